// Round 17
// baseline (3478.955 us; speedup 1.0000x reference)
//
#include <hip/hip_runtime.h>
#include <hip/hip_cooperative_groups.h>

#define NTOK 22500
#define N1   22501
#define NPAD 22528
#define PADR 27
#define DIM  512
#define NH   8
#define DHD  64
#define MM   256
#define LLM  88
#define HSZ  150
#define CSZ  256
#define NCH  88   // NPAD / CSZ

typedef short bf16x8 __attribute__((ext_vector_type(8)));
typedef float f32x4  __attribute__((ext_vector_type(4)));
typedef unsigned short us;

union U8 { bf16x8 v; unsigned short u[8]; };

__device__ __forceinline__ unsigned short f2b(float f){
  unsigned int u = __float_as_uint(f);
  unsigned int r = u + 0x7fffu + ((u>>16)&1u);
  return (unsigned short)(r>>16);
}
__device__ __forceinline__ float bf2f(unsigned short u){
  return __uint_as_float(((unsigned int)u)<<16);
}
__device__ __forceinline__ bf16x8 cvt8(float4 a, float4 b){
  U8 u;
  u.u[0]=f2b(a.x); u.u[1]=f2b(a.y); u.u[2]=f2b(a.z); u.u[3]=f2b(a.w);
  u.u[4]=f2b(b.x); u.u[5]=f2b(b.y); u.u[6]=f2b(b.z); u.u[7]=f2b(b.w);
  return u.v;
}
// async global->LDS, 16B per lane; lds dest = wave-uniform base + lane*16
__device__ __forceinline__ void gld16(const void* g, void* l){
  __builtin_amdgcn_global_load_lds(
      (const __attribute__((address_space(1))) void*)g,
      (__attribute__((address_space(3))) void*)l, 16, 0, 0);
}

// ---------------- reduction helpers ----------------
__device__ __forceinline__ float waveSum(float v){
#pragma unroll
  for (int o=32;o>0;o>>=1) v += __shfl_down(v,o);
  return v;
}
__device__ __forceinline__ float waveMax(float v){
#pragma unroll
  for (int o=32;o>0;o>>=1) v = fmaxf(v,__shfl_down(v,o));
  return v;
}
__device__ __forceinline__ float blockSum256(float v, float* sb){
  v = waveSum(v);
  __syncthreads();
  if ((threadIdx.x&63)==0) sb[threadIdx.x>>6]=v;
  __syncthreads();
  return sb[0]+sb[1]+sb[2]+sb[3];
}
__device__ __forceinline__ float blockMax256(float v, float* sb){
  v = waveMax(v);
  __syncthreads();
  if ((threadIdx.x&63)==0) sb[threadIdx.x>>6]=v;
  __syncthreads();
  return fmaxf(fmaxf(sb[0],sb[1]),fmaxf(sb[2],sb[3]));
}

// ---------------- fp32 -> bf16 convert ----------------
__global__ void k_cvt(const float* __restrict__ src, us* __restrict__ dst, size_t n4)
{
  size_t i = ((size_t)blockIdx.x*256 + threadIdx.x);
  if (i < n4){
    float4 v = *(const float4*)(src + i*4);
    ushort4 u; u.x=f2b(v.x); u.y=f2b(v.y); u.z=f2b(v.z); u.w=f2b(v.w);
    *(ushort4*)(dst + i*4) = u;
  }
}

// ---------------- weight transpose+cvt: W fp32 [K][N] -> Bt bf16 [N][K] ----------------
__global__ void k_wT(const float* __restrict__ W, us* __restrict__ Bt, int K, int N)
{
  __shared__ float tile[32][33];
  int tx = threadIdx.x&31, ty = threadIdx.x>>5;
  int k0 = blockIdx.x*32, n0 = blockIdx.y*32;
#pragma unroll
  for (int i=0;i<4;++i){
    int k = k0+ty+i*8;
    if (k<K && n0+tx<N) tile[ty+i*8][tx] = W[(size_t)k*N + n0+tx];
  }
  __syncthreads();
#pragma unroll
  for (int i=0;i<4;++i){
    int n = n0+ty+i*8, k = k0+tx;
    if (n<N && k<K) Bt[(size_t)n*K + k] = f2b(tile[tx][ty+i*8]);
  }
}

// ---------------- V transpose: Vb [h][p][d] -> Vtb [h][d][p] ----------------
__global__ void k_vT(const us* __restrict__ V, us* __restrict__ Vt)
{
  __shared__ us tile[32][33];
  int tx = threadIdx.x&31, ty = threadIdx.x>>5;
  int p0 = blockIdx.x*32;
  int h = blockIdx.y>>1, d0 = (blockIdx.y&1)*32;
#pragma unroll
  for (int i=0;i<4;++i){
    int p = p0+ty+i*8;
    tile[ty+i*8][tx] = V[((size_t)h*NPAD+p)*DHD + d0+tx];
  }
  __syncthreads();
#pragma unroll
  for (int i=0;i<4;++i){
    int d = d0+ty+i*8;
    Vt[((size_t)h*DHD+d)*NPAD + p0+tx] = tile[tx][ty+i*8];
  }
}

// ---------------- MFMA GEMM (64x128 tile), 3-buffer counted-vmcnt pipeline ----------------
// MODE 0: fc1 (A=hb bf16 -> X bf16 relu)   MODE 1: qkv (A=Yb bf16 -> Qb/Kb/Vb)
// MODE 2: wout (A=OHb bf16, X bf16 +=)     MODE 3: qk0 (A=Yb bf16 -> Q0/K0 fp32)
template<int MODE>
__global__ __launch_bounds__(256) void k_gemm(
    const us* __restrict__ Ab, const us* __restrict__ Bt, const float* __restrict__ bias,
    us* __restrict__ Xb, float* __restrict__ Cf, float* __restrict__ C2,
    us* __restrict__ Q_, us* __restrict__ K_, us* __restrict__ V_,
    const us* __restrict__ zpg, int Kd, int mtn)
{
  constexpr int BM = 64;
  constexpr int BUFE = BM*64 + 128*64;    // 12288 us per buffer
  __shared__ us SM[3*BUFE];               // 72 KB
  const int tid = threadIdx.x;
  const int bid = blockIdx.x;
  const int ntile = bid / mtn;            // m-fastest: consecutive blocks share B panel
  const int m0 = (bid % mtn)*BM, n0 = ntile*128;
  const int lane = tid & 63;
  const int wid = tid >> 6;
  const int wm = (wid>>1)*32, wn = (wid&1)*64;
  f32x4 acc[2][4] = {};
  const int NT = Kd >> 6;

  auto stage = [&](int t, int buf){
    us* As = SM + buf*BUFE;
    us* Bs = As + BM*64;
    int k0 = t*64;
#pragma unroll
    for (int i=0;i<2;++i){
      int c = wid*2+i;
      int row = c*8 + (lane>>3);
      int scol8 = ((lane&7) ^ (row&7))*8;
      int gm = m0+row;
      const us* ga;
      if (MODE==0)      ga = (gm<NTOK) ? Ab + (size_t)gm*Kd + k0 + scol8 : zpg + scol8;
      else if (MODE==2) ga = Ab + ((size_t)((gm<N1?gm:0)+PADR))*Kd + k0 + scol8;
      else              ga = (gm>=PADR) ? Ab + (size_t)(gm-PADR)*Kd + k0 + scol8 : zpg + scol8;
      gld16(ga, &As[c*512]);
    }
#pragma unroll
    for (int i=0;i<4;++i){
      int c = wid*4+i;
      int row = c*8 + (lane>>3);
      int scol8 = ((lane&7) ^ (row&7))*8;
      int vn = n0+row;
      if (MODE==3) vn = (vn<64)? vn : vn+448;
      gld16(Bt + (size_t)vn*Kd + k0 + scol8, &Bs[c*512]);
    }
  };

  stage(0, 0);
  stage(1, 1);
  for (int t=0; t<NT; ++t){
    asm volatile("s_waitcnt vmcnt(6)" ::: "memory");   // oldest stage (t) landed in LDS
    __builtin_amdgcn_s_barrier();                      // raw barrier: NO vmcnt drain
    asm volatile("" ::: "memory");
    if (t+2 < NT) stage(t+2, (t+2)%3);                 // buf (t+2)%3: last read at iter t-1
    us* As = SM + (t%3)*BUFE;
    us* Bs = As + BM*64;
#pragma unroll
    for (int ks=0; ks<2; ++ks){
      const int kk = ks*32 + (lane>>4)*8;
      bf16x8 af[2], bfm[4];
#pragma unroll
      for (int tt=0;tt<2;++tt){
        int r = wm + tt*16 + (lane&15);
        af[tt] = *(bf16x8*)(&As[r*64 + (kk ^ ((r&7)<<3))]);
      }
#pragma unroll
      for (int tt=0;tt<4;++tt){
        int c = wn + tt*16 + (lane&15);
        bfm[tt] = *(bf16x8*)(&Bs[c*64 + (kk ^ ((c&7)<<3))]);
      }
#pragma unroll
      for (int mt=0;mt<2;++mt)
#pragma unroll
        for (int nt=0;nt<4;++nt)
          acc[mt][nt] = __builtin_amdgcn_mfma_f32_16x16x32_bf16(af[mt], bfm[nt], acc[mt][nt], 0,0,0);
    }
  }
  __syncthreads();
  const int rbase = (lane>>4)*4;
  const int cl = lane&15;
  if (MODE==3){
#pragma unroll
    for (int mt=0;mt<2;++mt)
#pragma unroll
      for (int r=0;r<4;++r){
        int gm = m0 + wm + mt*16 + rbase + r;
#pragma unroll
        for (int nt=0;nt<4;++nt){
          int gn = n0 + wn + nt*16 + cl;
          float v = acc[mt][nt][r];
          if (gn < 64) Cf[(size_t)gm*DHD + gn] = v*0.125f;
          else         C2[(size_t)gm*DHD + (gn-64)] = v;
        }
      }
    return;
  }
  // LDS relayout epilogues (coalesced 16B bf16 stores)
  const float sc1 = (MODE==1 && (ntile>>2)==0) ? 0.125f : 1.f;
#pragma unroll
  for (int mt=0;mt<2;++mt)
#pragma unroll
    for (int r=0;r<4;++r){
      int row = wm + mt*16 + rbase + r;
#pragma unroll
      for (int nt=0;nt<4;++nt){
        int col = wn + nt*16 + cl;
        float v = acc[mt][nt][r];
        if (MODE==0){ v += bias[n0+col]; v = v>0.f?v:0.f; }
        else if (MODE==2){ v += bias[n0+col]; }
        else v *= sc1;
        SM[row*128 + col] = f2b(v);
      }
    }
  __syncthreads();
  if (MODE==1){
    const int sec = ntile>>2;
    us* dst = sec==0 ? Q_ : (sec==1 ? K_ : V_);
#pragma unroll
    for (int i=0;i<4;++i){
      int v8 = i*256 + tid;
      int row = v8>>4, c8 = (v8&15)*8;
      int gm = m0 + row, gn = n0 + c8;
      int hh = (gn>>6)&7, d = gn&63;
      *(bf16x8*)(dst + ((size_t)hh*NPAD+gm)*DHD + d) = *(bf16x8*)(&SM[row*128 + c8]);
    }
  } else if (MODE==0){
#pragma unroll
    for (int i=0;i<4;++i){
      int v8 = i*256 + tid;
      int row = v8>>4, c8 = (v8&15)*8;
      int gm = m0 + row;
      if (gm < NTOK)
        *(bf16x8*)(Xb + (size_t)(1+gm)*DIM + n0 + c8) = *(bf16x8*)(&SM[row*128 + c8]);
    }
  } else {  // MODE 2: bf16 RMW on X
#pragma unroll
    for (int i=0;i<4;++i){
      int v8 = i*256 + tid;
      int row = v8>>4, c8 = (v8&15)*8;
      int gm = m0 + row;
      if (gm < N1){
        us* p = Xb + (size_t)gm*DIM + n0 + c8;
        U8 xo, ad, o;
        xo.v = *(bf16x8*)p;
        ad.v = *(bf16x8*)(&SM[row*128 + c8]);
#pragma unroll
        for (int j=0;j<8;++j) o.u[j] = f2b(bf2f(xo.u[j]) + bf2f(ad.u[j]));
        *(bf16x8*)p = o.v;
      }
    }
  }
}

__global__ void k_setcls(us* __restrict__ X, const float* __restrict__ cls){
  int i = blockIdx.x*256 + threadIdx.x;
  if (i < DIM) X[i] = f2b(cls[i]);
}
__global__ void k_copyu(us* __restrict__ d, const us* __restrict__ s, size_t n){
  size_t i = (size_t)blockIdx.x*256 + threadIdx.x;
  if (i<n) d[i]=s[i];
}

// ---------------- layernorm: bf16 in -> bf16 out ----------------
__global__ void k_ln(const us* __restrict__ X, us* __restrict__ Y,
                     const float* __restrict__ w, const float* __restrict__ b)
{
  __shared__ float sb[4];
  const us* x = X + (size_t)blockIdx.x*DIM;
  us* y = Y + (size_t)blockIdx.x*DIM;
  int t = threadIdx.x;
  ushort2 xv = *(const ushort2*)(x + 2*t);
  float a0=bf2f(xv.x), a1=bf2f(xv.y);
  float s = blockSum256(a0+a1, sb);
  float q = blockSum256(a0*a0+a1*a1, sb);
  float mean = s*(1.f/512.f);
  float var = q*(1.f/512.f) - mean*mean;
  float rstd = rsqrtf(var+1e-5f);
  float2 wv = *(const float2*)(w + 2*t);
  float2 bv = *(const float2*)(b + 2*t);
  ushort2 o;
  o.x = f2b((a0-mean)*rstd*wv.x+bv.x);
  o.y = f2b((a1-mean)*rstd*wv.y+bv.y);
  *(ushort2*)(y + 2*t) = o;
}

// ---------------- landmarks (fused Q+K) ----------------
__global__ void k_landmark2(const us* __restrict__ Q, const us* __restrict__ K,
                            us* __restrict__ QL, us* __restrict__ KL)
{
  int hm = blockIdx.x;
  bool isK = hm >= NH*MM;
  if (isK) hm -= NH*MM;
  int h = hm>>8, m = hm&255; int d = threadIdx.x;
  const us* base = (isK?K:Q) + ((size_t)h*NPAD + (size_t)m*LLM)*DHD + d;
  float s = 0.f;
  for (int j=0;j<LLM;++j) s += bf2f(base[(size_t)j*DHD]);
  (isK?KL:QL)[((size_t)h*MM + m)*DHD + d] = f2b(s * (1.f/(float)LLM));
}
__global__ void k_landmark2f(const float* __restrict__ Q, const float* __restrict__ K,
                             float* __restrict__ QL, float* __restrict__ KL)
{
  int hm = blockIdx.x;
  bool isK = hm >= MM;
  int m = isK ? hm-MM : hm; int d = threadIdx.x;
  const float* base = (isK?K:Q) + (size_t)m*LLM*DHD + d;
  float s = 0.f;
  for (int j=0;j<LLM;++j) s += base[(size_t)j*DHD];
  (isK?KL:QL)[(size_t)m*DHD + d] = s * (1.f/(float)LLM);
}

// ---------------- MFMA NT gemm K=64, fp32 inputs ----------------
__global__ __launch_bounds__(64) void k_nt64(const float* __restrict__ A,
    const float* __restrict__ B, float* __restrict__ C,
    long sA, long sB, long sC, int Nr)
{
  int lane = threadIdx.x;
  int n0 = blockIdx.x*64, m0 = blockIdx.y*64;
  A += (size_t)blockIdx.z*sA; B += (size_t)blockIdx.z*sB; C += (size_t)blockIdx.z*sC;
  f32x4 acc[4][4] = {};
#pragma unroll
  for (int ks=0;ks<2;++ks){
    int kk = ks*32 + (lane>>4)*8;
    bf16x8 af[4], bfr[4];
#pragma unroll
    for (int mt=0;mt<4;++mt){
      const float* p = A + (size_t)(m0+mt*16+(lane&15))*64 + kk;
      af[mt] = cvt8(*(const float4*)p, *(const float4*)(p+4));
    }
#pragma unroll
    for (int nt=0;nt<4;++nt){
      const float* p = B + (size_t)(n0+nt*16+(lane&15))*64 + kk;
      bfr[nt] = cvt8(*(const float4*)p, *(const float4*)(p+4));
    }
#pragma unroll
    for (int mt=0;mt<4;++mt)
#pragma unroll
      for (int nt=0;nt<4;++nt)
        acc[mt][nt] = __builtin_amdgcn_mfma_f32_16x16x32_bf16(af[mt], bfr[nt], acc[mt][nt], 0,0,0);
  }
#pragma unroll
  for (int mt=0;mt<4;++mt)
#pragma unroll
    for (int r=0;r<4;++r){
      int row = m0+mt*16+(lane>>4)*4+r;
#pragma unroll
      for (int nt=0;nt<4;++nt){
        int col = n0+nt*16+(lane&15);
        C[(size_t)row*Nr + col] = acc[mt][nt][r];
      }
    }
}

// ---------------- MFMA NT gemm K=64, bf16 inputs (attn2 logits) ----------------
__global__ __launch_bounds__(64) void k_nt64b(const us* __restrict__ A,
    const us* __restrict__ B, float* __restrict__ C,
    long sA, long sB, long sC, int Nr)
{
  int lane = threadIdx.x;
  int n0 = blockIdx.x*64, m0 = blockIdx.y*64;
  A += (size_t)blockIdx.z*sA; B += (size_t)blockIdx.z*sB; C += (size_t)blockIdx.z*sC;
  f32x4 acc[4][4] = {};
#pragma unroll
  for (int ks=0;ks<2;++ks){
    int kk = ks*32 + (lane>>4)*8;
    bf16x8 af[4], bfr[4];
#pragma unroll
    for (int mt=0;mt<4;++mt)
      af[mt] = *(const bf16x8*)(A + (size_t)(m0+mt*16+(lane&15))*64 + kk);
#pragma unroll
    for (int nt=0;nt<4;++nt)
      bfr[nt] = *(const bf16x8*)(B + (size_t)(n0+nt*16+(lane&15))*64 + kk);
#pragma unroll
    for (int mt=0;mt<4;++mt)
#pragma unroll
      for (int nt=0;nt<4;++nt)
        acc[mt][nt] = __builtin_amdgcn_mfma_f32_16x16x32_bf16(af[mt], bfr[nt], acc[mt][nt], 0,0,0);
  }
#pragma unroll
  for (int mt=0;mt<4;++mt)
#pragma unroll
    for (int r=0;r<4;++r){
      int row = m0+mt*16+(lane>>4)*4+r;
#pragma unroll
      for (int nt=0;nt<4;++nt){
        int col = n0+nt*16+(lane&15);
        C[(size_t)row*Nr + col] = acc[mt][nt][r];
      }
    }
}

// ---------------- pinv gemm tile body (shared by cooperative k_pinv) ----------------
// PM 0: C=A@B (write C+Ct)   PM 1: C=alpha*(dc*A - A@B) (write Ct, C if writeC)
template<int PM>
__device__ __forceinline__ void pgemm_tile(const us* __restrict__ A,
    const us* __restrict__ Bt, us* __restrict__ C, us* __restrict__ Ct,
    float dc, float alpha, int writeC, us* As, us* Bs)
{
  const int tid = threadIdx.x, lane = tid&63, wid = tid>>6;
  const int n0 = blockIdx.x*64, m0 = blockIdx.y*64;
  const us* Ab = A + (size_t)blockIdx.z*65536;
  const us* Bb = Bt + (size_t)blockIdx.z*65536;
  for (int i=tid; i<4096; i+=256){
    int r = i>>6, c4 = (i&63)*4;
    *(ushort4*)(&As[r*256 + (c4 ^ ((r&7)<<3))]) = *(const ushort4*)(Ab + (size_t)(m0+r)*256 + c4);
    *(ushort4*)(&Bs[r*256 + (c4 ^ ((r&7)<<3))]) = *(const ushort4*)(Bb + (size_t)(n0+r)*256 + c4);
  }
  __syncthreads();
  const int wm = (wid>>1)*32, wn = (wid&1)*32;
  f32x4 acc[2][2] = {};
#pragma unroll
  for (int ks=0;ks<8;++ks){
    int kk = ks*32 + (lane>>4)*8;
    bf16x8 af[2], bfr[2];
#pragma unroll
    for (int t=0;t<2;++t){
      int rr = wm + t*16 + (lane&15);
      af[t] = *(const bf16x8*)(&As[rr*256 + (kk ^ ((rr&7)<<3))]);
      int cc = wn + t*16 + (lane&15);
      bfr[t] = *(const bf16x8*)(&Bs[cc*256 + (kk ^ ((cc&7)<<3))]);
    }
#pragma unroll
    for (int mt=0;mt<2;++mt)
#pragma unroll
      for (int nt=0;nt<2;++nt)
        acc[mt][nt] = __builtin_amdgcn_mfma_f32_16x16x32_bf16(af[mt], bfr[nt], acc[mt][nt], 0,0,0);
  }
  // fold PM1 diag term (A read from LDS), keep in regs
  float vv[2][4][2];
#pragma unroll
  for (int mt=0;mt<2;++mt)
#pragma unroll
    for (int q=0;q<4;++q){
      int rl = wm + mt*16 + (lane>>4)*4 + q;
#pragma unroll
      for (int nt=0;nt<2;++nt){
        int clx = wn + nt*16 + (lane&15);
        float v = acc[mt][nt][q];
        if (PM==1) v = alpha*(dc*bf2f(As[rl*256 + (clx ^ ((rl&7)<<3))]) - v);
        vv[mt][q][nt] = v;
      }
    }
  __syncthreads();
  // write 64x64 tile into LDS (swizzled), reuse As
  us* TT = As;
#pragma unroll
  for (int mt=0;mt<2;++mt)
#pragma unroll
    for (int q=0;q<4;++q){
      int rl = wm + mt*16 + (lane>>4)*4 + q;
      int sw = (rl&7)<<3;
#pragma unroll
      for (int nt=0;nt<2;++nt){
        int clx = wn + nt*16 + (lane&15);
        TT[rl*64 + (clx ^ sw)] = f2b(vv[mt][q][nt]);
      }
    }
  __syncthreads();
  // coalesced transposed store
  {
    int c = tid>>2, r0 = (tid&3)*16;
    U8 b0, b1;
#pragma unroll
    for (int i=0;i<8;++i){
      int r = r0+i;       b0.u[i] = TT[r*64 + (c ^ ((r&7)<<3))];
      int r2 = r0+8+i;    b1.u[i] = TT[r2*64 + (c ^ ((r2&7)<<3))];
    }
    us* dst = Ct + (size_t)blockIdx.z*65536 + (size_t)(n0+c)*256 + m0 + r0;
    *(bf16x8*)dst = b0.v;
    *(bf16x8*)(dst+8) = b1.v;
  }
  if (PM==0 || writeC){
    int rr = tid>>2, c0 = (tid&3)*16;
    int sw = (rr&7)<<3;
    bf16x8 x0 = *(const bf16x8*)(&TT[rr*64 + (c0 ^ sw)]);
    bf16x8 x1 = *(const bf16x8*)(&TT[rr*64 + ((c0+8) ^ sw)]);
    us* dc2 = C + (size_t)blockIdx.z*65536 + (size_t)(m0+rr)*256 + n0 + c0;
    *(bf16x8*)dc2 = x0;
    *(bf16x8*)(dc2+8) = x1;
  }
}

// ---------------- cooperative pinv: 6 iters x 4 gemm phases, 1 launch ----------------
__global__ __launch_bounds__(256) void k_pinv(const us* __restrict__ A2b,
    us* Z0, us* Z0t, us* Z1, us* Z1t,
    us* XZ, us* XZt, us* T1t, us* T2t)
{
  __shared__ us As[64*256];
  __shared__ us Bs[64*256];
  cooperative_groups::grid_group grid = cooperative_groups::this_grid();
  us *Zc=Z0, *Zct=Z0t, *Zn=Z1, *Znt=Z1t;
  for (int it=0; it<6; ++it){
    pgemm_tile<0>(A2b, Zct, XZ, XZt, 0.f, 1.f, 1, As, Bs);
    grid.sync();
    pgemm_tile<1>(XZ, XZt, nullptr, T1t, 7.f, 1.f, 0, As, Bs);
    grid.sync();
    pgemm_tile<1>(XZ, T1t, nullptr, T2t, 15.f, 1.f, 0, As, Bs);
    grid.sync();
    pgemm_tile<1>(Zc, T2t, Zn, Znt, 13.f, 0.25f, 1, As, Bs);
    grid.sync();
    us* s1=Zc; Zc=Zn; Zn=s1;
    us* s2=Zct; Zct=Znt; Znt=s2;
  }
  // 6 iterations = even number of swaps -> final Z in Z0/Z0t
}

// ---------------- WmT gemm (dispatch) ----------------
__global__ __launch_bounds__(256) void k_pgemm2(const us* __restrict__ A,
    const us* __restrict__ Bt, us* __restrict__ Ct)
{
  __shared__ us As[16384];
  __shared__ us Bs[16384];
  const int tid = threadIdx.x, lane = tid&63, wid = tid>>6;
  const int n0 = 0, m0 = blockIdx.y*64;
  const us* Ab = A + (size_t)blockIdx.z*65536;
  const us* Bb = Bt + (size_t)blockIdx.z*16384;
  for (int i=tid; i<4096; i+=256){
    int r = i>>6, c4 = (i&63)*4;
    *(ushort4*)(&As[r*256 + (c4 ^ ((r&7)<<3))]) = *(const ushort4*)(Ab + (size_t)(m0+r)*256 + c4);
    if (r < 64)
      *(ushort4*)(&Bs[r*256 + (c4 ^ ((r&7)<<3))]) = *(const ushort4*)(Bb + (size_t)(n0+r)*256 + c4);
  }
  __syncthreads();
  const int wm = (wid>>1)*32, wn = (wid&1)*32;
  f32x4 acc[2][2] = {};
#pragma unroll
  for (int ks=0;ks<8;++ks){
    int kk = ks*32 + (lane>>4)*8;
    bf16x8 af[2], bfr[2];
#pragma unroll
    for (int t=0;t<2;++t){
      int rr = wm + t*16 + (lane&15);
      af[t] = *(const bf16x8*)(&As[rr*256 + (kk ^ ((rr&7)<<3))]);
      int cc = wn + t*16 + (lane&15);
      bfr[t] = *(const bf16x8*)(&Bs[cc*256 + (kk ^ ((cc&7)<<3))]);
    }
#pragma unroll
    for (int mt=0;mt<2;++mt)
#pragma unroll
      for (int nt=0;nt<2;++nt)
        acc[mt][nt] = __builtin_amdgcn_mfma_f32_16x16x32_bf16(af[mt], bfr[nt], acc[mt][nt], 0,0,0);
  }
#pragma unroll
  for (int mt=0;mt<2;++mt)
#pragma unroll
    for (int r=0;r<4;++r){
      int row = m0 + wm + mt*16 + (lane>>4)*4 + r;
#pragma unroll
      for (int nt=0;nt<2;++nt){
        int col = n0 + wn + nt*16 + (lane&15);
        Ct[(size_t)blockIdx.z*16384 + (size_t)col*256 + row] = f2b(acc[mt][nt][r]);
      }
    }
}

// ---------------- small elementwise ----------------
__global__ void k_softmax256(float* __restrict__ S, us* __restrict__ Sb)
{
  __shared__ float sb[4];
  float* row = S + ((size_t)blockIdx.x<<8);
  float x = row[threadIdx.x];
  float m = blockMax256(x, sb);
  float e = __expf(x-m);
  float s = blockSum256(e, sb);
  float p = e/s;
  row[threadIdx.x] = p;
  Sb[((size_t)blockIdx.x<<8) + threadIdx.x] = f2b(p);
}
__global__ void k_csmax(const float* __restrict__ A2, float* __restrict__ sums)
{
  __shared__ float sb[4];
  int b = blockIdx.x, j = threadIdx.x;
  const float* Ab = A2 + ((size_t)b<<16);
  float s = 0.f;
  for (int i=0;i<256;++i) s += Ab[((size_t)i<<8)+j];
  float m = blockMax256(s, sb);
  if (j==0) sums[b] = m;
}
__global__ void k_scale2(const float* __restrict__ sums, float* __restrict__ scl, int nb)
{
  __shared__ float sb[4];
  float m=-1e30f;
  for (int i=threadIdx.x;i<nb;i+=256) m = fmaxf(m, sums[i]);
  m = blockMax256(m, sb);
  if (threadIdx.x==0) scl[0] = 1.f/m;
}
// tiled Z0: Zt = A2*s (row-major), Z = A2^T*s, both coalesced via LDS 32x32
__global__ void k_z0t(const float* __restrict__ A2, us* __restrict__ Z, us* __restrict__ Zt,
                      const float* __restrict__ scl)
{
  __shared__ us tile[32][33];
  int tx = threadIdx.x&31, ty = threadIdx.x>>5;
  int i0 = blockIdx.x*32;
  int head = blockIdx.y>>3, j0 = (blockIdx.y&7)*32;
  float s = scl[0];
  const float* Ab = A2 + (size_t)head*65536;
  us* Zh  = Z  + (size_t)head*65536;
  us* Zth = Zt + (size_t)head*65536;
#pragma unroll
  for (int ii=0;ii<4;++ii){
    int i = i0+ty+ii*8;
    us bv = f2b(Ab[(size_t)i*256 + j0+tx]*s);
    Zth[(size_t)i*256 + j0+tx] = bv;
    tile[ty+ii*8][tx] = bv;
  }
  __syncthreads();
#pragma unroll
  for (int ii=0;ii<4;++ii){
    int j = j0+ty+ii*8;
    Zh[(size_t)j*256 + i0+tx] = tile[tx][ty+ii*8];
  }
}

// ---------------- attn3: MFMA flash (8 waves x 32 query rows) ----------------
__global__ __launch_bounds__(512) void k_attn3(const us* __restrict__ QLb,
    const us* __restrict__ Kb, const us* __restrict__ Vt,
    float* __restrict__ Pmax, float* __restrict__ Psum, us* __restrict__ Pacc)
{
  __shared__ us Ks[64*64];       // 8 KB
  __shared__ us Vs[64*64];       // 8 KB
  __shared__ us Ps[8*32*64];     // 32 KB (per-wave 32x64 P tile)
  int h = blockIdx.y, cx = blockIdx.x;
  int tid = threadIdx.x, wid = tid>>6, lane = tid&63;   // wid 0..7
  bf16x8 aq[2][2];
#pragma unroll
  for (int mt=0;mt<2;++mt){
    const us* qp = QLb + ((size_t)h*MM + wid*32 + mt*16 + (lane&15))*DHD;
#pragma unroll
    for (int ks=0;ks<2;++ks)
      aq[mt][ks] = *(const bf16x8*)(qp + ks*32 + (lane>>4)*8);
  }
  float m_[2][4], l_[2][4];
  f32x4 acc[2][4] = {};
#pragma unroll
  for (int mt=0;mt<2;++mt)
#pragma unroll
    for (int r=0;r<4;++r){ m_[mt][r] = -1e30f; l_[mt][r] = 0.f; }

  us* Pw = &Ps[wid*2048];
  for (int t=0;t<4;++t){
    int kb0 = cx*CSZ + t*64;
    __syncthreads();
    for (int i=tid;i<1024;i+=512){
      int rr = i>>4, c4 = (i&15)*4;
      ushort4 ku = *(const ushort4*)(Kb + ((size_t)h*NPAD + kb0 + rr)*DHD + c4);
      *(ushort4*)(&Ks[rr*64 + (c4 ^ ((rr&7)<<3))]) = ku;
      ushort4 vu = *(const ushort4*)(Vt + ((size_t)h*DHD + rr)*NPAD + kb0 + c4);
      *(ushort4*)(&Vs[rr*64 + (c4 ^ ((rr&7)<<3))]) = vu;
    }
    __syncthreads();
    f32x4 s[2][4] = {};
    __builtin_amdgcn_s_setprio(1);
#pragma unroll
    for (int ks=0;ks<2;++ks){
      int kk = ks*32 + (lane>>4)*8;
      bf16x8 kbf[4];
#pragma unroll
      for (int nt=0;nt<4;++nt){
        int key = nt*16 + (lane&15);
        kbf[nt] = *(const bf16x8*)(&Ks[key*64 + (kk ^ ((key&7)<<3))]);
      }
#pragma unroll
      for (int mt=0;mt<2;++mt)
#pragma unroll
        for (int nt=0;nt<4;++nt)
          s[mt][nt] = __builtin_amdgcn_mfma_f32_16x16x32_bf16(aq[mt][ks], kbf[nt], s[mt][nt], 0,0,0);
    }
    __builtin_amdgcn_s_setprio(0);
#pragma unroll
    for (int mt=0;mt<2;++mt){
#pragma unroll
      for (int r=0;r<4;++r){
        float mx = fmaxf(fmaxf(s[mt][0][r], s[mt][1][r]), fmaxf(s[mt][2][r], s[mt][3][r]));
#pragma unroll
        for (int off=8;off>=1;off>>=1) mx = fmaxf(mx, __shfl_xor(mx, off));
        float mn = fmaxf(m_[mt][r], mx);
        float f = __expf(m_[mt][r]-mn);
        float la = 0.f;
#pragma unroll
        for (int nt=0;nt<4;++nt){ float p=__expf(s[mt][nt][r]-mn); s[mt][nt][r]=p; la+=p; }
#pragma unroll
        for (int off=8;off>=1;off>>=1) la += __shfl_xor(la, off);
        l_[mt][r] = l_[mt][r]*f + la;
        m_[mt][r] = mn;
#pragma unroll
        for (int dt=0;dt<4;++dt) acc[mt][dt][r] *= f;
      }
    }
#pragma unroll
    for (int mt=0;mt<2;++mt)
#pragma unroll
      for (int r=0;r<4;++r){
        int row = mt*16 + (lane>>4)*4 + r;      // 0..31 within wave
        int sw = (row&7)<<3;
#pragma unroll
        for (int nt=0;nt<4;++nt){
          int col = nt*16 + (lane&15);
          Pw[row*64 + (col ^ sw)] = f2b(s[mt][nt][r]);
        }
      }
    __builtin_amdgcn_s_setprio(1);
#pragma unroll
    for (int ks=0;ks<2;++ks){
      int kk = ks*32 + (lane>>4)*8;
      bf16x8 pa[2], vb[4];
#pragma unroll
      for (int mt=0;mt<2;++mt){
        int arow = mt*16 + (lane&15);
        pa[mt] = *(const bf16x8*)(&Pw[arow*64 + (kk ^ ((arow&7)<<3))]);
      }
#pragma unroll
      for (int dt=0;dt<4;++dt){
        int d = dt*16 + (lane&15);
        vb[dt] = *(const bf16x8*)(&Vs[d*64 + (kk ^ ((d&7)<<3))]);
      }
#pragma unroll
      for (int mt=0;mt<2;++mt)
#pragma unroll
        for (int dt=0;dt<4;++dt)
          acc[mt][dt] = __builtin_amdgcn_mfma_f32_16x16x32_bf16(pa[mt], vb[dt], acc[mt][dt], 0,0,0);
    }
    __builtin_amdgcn_s_setprio(0);
  }
  size_t pbase = ((size_t)h*NCH + cx)*MM;
#pragma unroll
  for (int mt=0;mt<2;++mt)
#pragma unroll
    for (int r=0;r<4;++r){
      int row = wid*32 + mt*16 + (lane>>4)*4 + r;
      if ((lane&15)==0){ Pmax[pbase+row]=m_[mt][r]; Psum[pbase+row]=l_[mt][r]; }
#pragma unroll
      for (int dt=0;dt<4;++dt)
        Pacc[(pbase+row)*DHD + dt*16+(lane&15)] = f2b(acc[mt][dt][r]);
    }
}

__global__ void k_attn3_merge(const float* __restrict__ Pmax, const float* __restrict__ Psum,
    const us* __restrict__ Pacc, us* __restrict__ A3Vtb)
{
  int hm = blockIdx.x; int h = hm>>8, m = hm&255; int d = threadIdx.x;
  float gm = -1e30f;
  for (int c=0;c<NCH;++c) gm = fmaxf(gm, Pmax[((size_t)h*NCH+c)*MM+m]);
  float tot=0.f, acc=0.f;
  for (int c=0;c<NCH;++c){
    size_t pi = ((size_t)h*NCH+c)*MM+m;
    float w = __expf(Pmax[pi]-gm);
    tot += Psum[pi]*w;
    acc += bf2f(Pacc[pi*DHD+d])*w;
  }
  A3Vtb[((size_t)h*DHD + d)*MM + m] = f2b(acc/tot);
}

// ---------------- attn1 ----------------
__global__ __launch_bounds__(256) void k_attn1(const us* __restrict__ Qb,
    const us* __restrict__ KLb, const us* __restrict__ WmT,
    us* __restrict__ OH)
{
  __shared__ us KWs[64*256];
  __shared__ us Ps[64*256];
  int h = blockIdx.y, tid = threadIdx.x;
  int wid = tid>>6, lane = tid&63;
  int q0 = blockIdx.x*64;
  for (int i=tid; i<4096; i+=256){
    int lm = i>>4, k4 = (i&15)*4;
    *(ushort4*)(&KWs[lm*64 + (k4 ^ ((lm&7)<<3))]) =
        *(const ushort4*)(KLb + ((size_t)h*MM + lm)*DHD + k4);
  }
  bf16x8 aq[2];
  const us* qp = Qb + ((size_t)h*NPAD + q0 + wid*16 + (lane&15))*DHD;
#pragma unroll
  for (int ks=0;ks<2;++ks)
    aq[ks] = *(const bf16x8*)(qp + ks*32 + (lane>>4)*8);
  __syncthreads();
  f32x4 s[16];
#pragma unroll
  for (int nt=0;nt<16;++nt) s[nt] = (f32x4){0.f,0.f,0.f,0.f};
  __builtin_amdgcn_s_setprio(1);
#pragma unroll
  for (int ks=0;ks<2;++ks){
    int kk = ks*32 + (lane>>4)*8;
#pragma unroll
    for (int nt=0;nt<16;++nt){
      int col = nt*16 + (lane&15);
      bf16x8 b = *(const bf16x8*)(&KWs[col*64 + (kk ^ ((col&7)<<3))]);
      s[nt] = __builtin_amdgcn_mfma_f32_16x16x32_bf16(aq[ks], b, s[nt], 0,0,0);
    }
  }
  __builtin_amdgcn_s_setprio(0);
  float rcp[4];
#pragma unroll
  for (int r=0;r<4;++r){
    float m = -1e30f;
#pragma unroll
    for (int nt=0;nt<16;++nt) m = fmaxf(m, s[nt][r]);
#pragma unroll
    for (int off=8;off>=1;off>>=1) m = fmaxf(m, __shfl_xor(m, off));
    float l = 0.f;
#pragma unroll
    for (int nt=0;nt<16;++nt){ float p=__expf(s[nt][r]-m); s[nt][r]=p; l+=p; }
#pragma unroll
    for (int off=8;off>=1;off>>=1) l += __shfl_xor(l, off);
    rcp[r] = 1.f/l;
  }
  int prow_base = wid*16 + (lane>>4)*4;
#pragma unroll
  for (int nt=0;nt<16;++nt){
    int col = nt*16 + (lane&15);
#pragma unroll
    for (int r=0;r<4;++r){
      int row = prow_base + r;
      Ps[row*256 + (col ^ ((row&7)<<3))] = f2b(s[nt][r]);
    }
  }
  __syncthreads();
  for (int i=tid; i<4096; i+=256){
    int d = i>>6, k4 = (i&63)*4;
    ushort4 u = *(const ushort4*)(WmT + ((size_t)h*DHD + d)*MM + k4);
    *(ushort4*)(&KWs[d*256 + (k4 ^ ((d&7)<<3))]) = u;
  }
  __syncthreads();
  f32x4 acc[4] = {};
  int arow = wid*16 + (lane&15);
  __builtin_amdgcn_s_setprio(1);
#pragma unroll
  for (int ks=0;ks<8;++ks){
    int kk = ks*32 + (lane>>4)*8;
    bf16x8 a = *(const bf16x8*)(&Ps[arow*256 + (kk ^ ((arow&7)<<3))]);
#pragma unroll
    for (int dt=0;dt<4;++dt){
      int d = dt*16 + (lane&15);
      bf16x8 b = *(const bf16x8*)(&KWs[d*256 + (kk ^ ((d&7)<<3))]);
      acc[dt] = __builtin_amdgcn_mfma_f32_16x16x32_bf16(a, b, acc[dt], 0,0,0);
    }
  }
  __builtin_amdgcn_s_setprio(0);
#pragma unroll
  for (int r=0;r<4;++r){
    int row = q0 + prow_base + r;
    us* op = OH + (size_t)row*DIM + h*DHD;
#pragma unroll
    for (int dt=0;dt<4;++dt)
      op[dt*16 + (lane&15)] = f2b(acc[dt][r]*rcp[r]);
  }
}

// ---------------- depthwise conv along seq, bf16 RMW ----------------
#define SCBLK 32
__global__ __launch_bounds__(256) void k_seqconv(const us* __restrict__ Vb,
    const float* __restrict__ resk, us* __restrict__ OH)
{
  __shared__ us Vs[64*512];
  int tid = threadIdx.x;
  int p0 = blockIdx.x*SCBLK;
  for (int i=tid; i<16384; i+=256){
    int pl = i>>8, c2 = i&255;
    int gp = p0 - 16 + pl;
    int hh = c2>>5, d2 = (c2&31)*2;
    ushort2 v = make_ushort2(0,0);
    if (gp>=0 && gp<NPAD) v = *(const ushort2*)(Vb + ((size_t)hh*NPAD+gp)*DHD + d2);
    *(ushort2*)(&Vs[pl*512 + c2*2]) = v;
  }
  __syncthreads();
  int h = tid>>5;
  float kr[33];
#pragma unroll
  for (int r=0;r<33;++r) kr[r] = resk[h*33+r];
  for (int pl=0; pl<SCBLK; ++pl){
    float s0=0.f, s1=0.f;
#pragma unroll
    for (int r=0;r<33;++r){
      ushort2 v = *(const ushort2*)(&Vs[(pl+r)*512 + tid*2]);
      s0 += bf2f(v.x)*kr[r];
      s1 += bf2f(v.y)*kr[r];
    }
    size_t o = (size_t)(p0+pl)*DIM + tid*2;
    ushort2 cur = *(ushort2*)(OH + o);
    *(ushort2*)(OH + o) = make_ushort2(f2b(bf2f(cur.x)+s0), f2b(bf2f(cur.y)+s1));
  }
}

// ---------------- leff (bf16 planes, bf16 X) ----------------
__global__ void k_tfwd(const us* __restrict__ X, us* __restrict__ T)
{
  __shared__ us tile[32][33];
  int tx = threadIdx.x & 31, ty = threadIdx.x >> 5;
  int s0 = blockIdx.x*32, c0 = blockIdx.y*32;
  for (int yy=0; yy<4; ++yy){
    int s = s0 + ty + yy*8;
    if (s < NTOK) tile[ty+yy*8][tx] = X[(size_t)(1+s)*DIM + c0+tx];
  }
  __syncthreads();
  for (int yy=0; yy<4; ++yy){
    int c = c0 + ty + yy*8;
    int s = s0 + tx;
    if (s < NTOK) T[(size_t)c*NTOK + s] = tile[tx][ty+yy*8];
  }
}
__global__ void k_tbwd(const us* __restrict__ T, us* __restrict__ X)
{
  __shared__ us tile[32][33];
  int tx = threadIdx.x & 31, ty = threadIdx.x >> 5;
  int s0 = blockIdx.x*32, c0 = blockIdx.y*32;
  for (int yy=0; yy<4; ++yy){
    int c = c0 + ty + yy*8, s = s0 + tx;
    if (s < NTOK) tile[ty+yy*8][tx] = T[(size_t)c*NTOK + s];
  }
  __syncthreads();
  for (int yy=0; yy<4; ++yy){
    int s = s0 + ty + yy*8, c = c0 + tx;
    if (s < NTOK) X[(size_t)(1+s)*DIM + c] = tile[tx][ty+yy*8];
  }
}
// scalar depthwise 7/5/3 conv (round-13 variant: high occupancy)
__global__ __launch_bounds__(256) void k_leff(const us* __restrict__ T,
    const float* __restrict__ k7, const float* __restrict__ b7,
    const float* __restrict__ k5, const float* __restrict__ b5,
    const float* __restrict__ k3, const float* __restrict__ b3,
    us* __restrict__ T2)
{
  __shared__ float tile[21*21];
  int c = blockIdx.y;
  int ti = blockIdx.x/10, tj = blockIdx.x%10;
  int i0 = ti*15-3, j0 = tj*15-3;
  const us* img = T + (size_t)c*NTOK;
  for (int idx=threadIdx.x; idx<441; idx+=256){
    int ii = idx/21, jj = idx%21;
    int gi = i0+ii, gj = j0+jj;
    tile[idx] = (gi>=0 && gi<HSZ && gj>=0 && gj<HSZ) ? bf2f(img[gi*HSZ+gj]) : 0.f;
  }
  __syncthreads();
  if (threadIdx.x < 225){
    int li = threadIdx.x/15, lj = threadIdx.x%15;
    int gi = ti*15+li, gj = tj*15+lj;
    float acc = tile[(li+3)*21 + (lj+3)] + b7[c]+b5[c]+b3[c];
    const float* w7 = k7 + c*49;
#pragma unroll
    for (int a=0;a<7;++a)
#pragma unroll
      for (int bb=0;bb<7;++bb) acc += tile[(li+a)*21 + (lj+bb)]*w7[a*7+bb];
    const float* w5 = k5 + c*25;
#pragma unroll
    for (int a=0;a<5;++a)
#pragma unroll
      for (int bb=0;bb<5;++bb) acc += tile[(li+1+a)*21 + (lj+1+bb)]*w5[a*5+bb];
    const float* w3 = k3 + c*9;
#pragma unroll
    for (int a=0;a<3;++a)
#pragma unroll
      for (int bb=0;bb<3;++bb) acc += tile[(li+2+a)*21 + (lj+2+bb)]*w3[a*3+bb];
    T2[(size_t)c*NTOK + gi*HSZ+gj] = f2b(acc);
  }
}

// ---------------- cls-row pieces ----------------
__global__ void k_row1(const float* __restrict__ Q0, const float* __restrict__ KL0,
                       float* __restrict__ row1)
{
  __shared__ float sb[4];
  __shared__ float qv[64];
  int t = threadIdx.x;
  if (t<64) qv[t] = Q0[PADR*DHD + t];
  __syncthreads();
  float l = 0.f;
#pragma unroll
  for (int d=0;d<64;++d) l += qv[d]*KL0[(size_t)t*DHD+d];
  float m = blockMax256(l, sb);
  float e = __expf(l-m);
  float s = blockSum256(e, sb);
  row1[t] = e/s;
}
__global__ void k_rz(const float* __restrict__ row1, const us* __restrict__ Zt,
                     float* __restrict__ rz)
{
  __shared__ float r1[256];
  int t = threadIdx.x;
  r1[t] = row1[t];
  __syncthreads();
  float s = 0.f;
  for (int k2=0;k2<256;++k2) s += r1[k2]*bf2f(Zt[(size_t)t*MM + k2]);
  rz[t] = s;
}
__global__ void k_rowstat(const float* __restrict__ L0, float* __restrict__ mx, float* __restrict__ se)
{
  __shared__ float sb[4];
  const float* row = L0 + (size_t)blockIdx.x*NPAD;
  float m = -1e30f;
  for (int i=threadIdx.x;i<NPAD;i+=256) m = fmaxf(m, row[i]);
  m = blockMax256(m, sb);
  float s = 0.f;
  for (int i=threadIdx.x;i<NPAD;i+=256) s += __expf(row[i]-m);
  s = blockSum256(s, sb);
  if (threadIdx.x==0){ mx[blockIdx.x]=m; se[blockIdx.x]=s; }
}
__global__ void k_aout(const float* __restrict__ L0, const float* __restrict__ rz,
    const float* __restrict__ mx, const float* __restrict__ se, float* __restrict__ out)
{
  __shared__ float wk[256], mk[256];
  int t = threadIdx.x;
  wk[t] = rz[t]/se[t];
  mk[t] = mx[t];
  __syncthreads();
  int p = blockIdx.x*256 + t;
  if (p >= NTOK) return;
  size_t pp = (size_t)(PADR+1+p);
  float a = 0.f;
  for (int k2=0;k2<256;++k2) a += wk[k2]*__expf(L0[(size_t)k2*NPAD+pp]-mk[k2]);
  out[4+p] = a;
}
__global__ void k_final(const us* __restrict__ H2r, const float* __restrict__ nw,
    const float* __restrict__ nbb, const float* __restrict__ w2, const float* __restrict__ b2,
    float* __restrict__ out)
{
  __shared__ float sb[4];
  __shared__ float hf[512];
  int t = threadIdx.x;
  float x0 = bf2f(H2r[t]), x1 = bf2f(H2r[256+t]);
  float s = blockSum256(x0+x1, sb);
  float q = blockSum256(x0*x0+x1*x1, sb);
  float mean = s*(1.f/512.f);
  float var = q*(1.f/512.f) - mean*mean;
  float rstd = rsqrtf(var+1e-5f);
  hf[t]     = (x0-mean)*rstd*nw[t]+nbb[t];
  hf[256+t] = (x1-mean)*rstd*nw[256+t]+nbb[256+t];
  __syncthreads();
  float p0 = hf[t]*w2[t*2]   + hf[256+t]*w2[(256+t)*2];
  float p1 = hf[t]*w2[t*2+1] + hf[256+t]*w2[(256+t)*2+1];
  p0 = blockSum256(p0, sb);
  p1 = blockSum256(p1, sb);
  if (t==0){
    float l0 = p0+b2[0], l1 = p1+b2[1];
    float m = fmaxf(l0,l1);
    float e0 = __expf(l0-m), e1 = __expf(l1-m), si = 1.f/(e0+e1);
    out[0]=l0; out[1]=l1; out[2]=e0*si; out[3]=e1*si;
  }
}

// ---------------- host orchestration ----------------
struct Bufs {
  float *A2,*sums,*scl,*Pmax,*Psum;
  us *Xb,*Yb,*OHb,*Qb,*Kb,*Vb,*Vtb,*QLb,*KLb,*A2b;
  us *Z0b,*Z0tb,*Z1b,*Z1tb,*XZb,*XZtb,*T1tb,*T2tb;
  us *A3Vtb,*WmT,*Pacc,*zpg;
};

static void run_pinv(const us* A2b, Bufs& b, int NB, hipStream_t st)
{
  dim3 g(4,4,NB), blk(256,1,1);
  const us* a = A2b;
  us *z0=b.Z0b, *z0t=b.Z0tb, *z1=b.Z1b, *z1t=b.Z1tb;
  us *xz=b.XZb, *xzt=b.XZtb, *t1=b.T1tb, *t2=b.T2tb;
  void* args[] = {&a,&z0,&z0t,&z1,&z1t,&xz,&xzt,&t1,&t2};
  hipLaunchCooperativeKernel((void*)k_pinv, g, blk, args, 0, st);
  // 6 iterations = even number of swaps -> final Z in Z0b/Z0tb
}

static void nystrom_layer(Bufs& b, const float* lnw, const float* lnb,
    const us* wqkvT, const us* woutT,
    const float* bout, const float* resk, hipStream_t st)
{
  k_ln<<<N1,256,0,st>>>(b.Xb, b.Yb, lnw, lnb);
  k_gemm<1><<<352*12,256,0,st>>>(b.Yb, wqkvT, nullptr,
      nullptr, nullptr, nullptr, b.Qb, b.Kb, b.Vb, b.zpg, DIM, 352);
  k_vT<<<dim3(NPAD/32,16),256,0,st>>>(b.Vb, b.Vtb);
  k_landmark2<<<2*NH*MM,64,0,st>>>(b.Qb, b.Kb, b.QLb, b.KLb);
  k_nt64b<<<dim3(4,4,NH),64,0,st>>>(b.QLb, b.KLb, b.A2,
      (long)MM*DHD,(long)MM*DHD,(long)MM*MM, MM);
  k_softmax256<<<NH*MM,256,0,st>>>(b.A2, b.A2b);
  k_csmax<<<NH,256,0,st>>>(b.A2, b.sums);
  k_scale2<<<1,256,0,st>>>(b.sums, b.scl, NH);
  k_z0t<<<dim3(8,8*NH),256,0,st>>>(b.A2, b.Z0b, b.Z0tb, b.scl);
  run_pinv(b.A2b, b, NH, st);
  k_attn3<<<dim3(NCH,NH),512,0,st>>>(b.QLb, b.Kb, b.Vtb, b.Pmax, b.Psum, b.Pacc);
  k_attn3_merge<<<NH*MM,64,0,st>>>(b.Pmax, b.Psum, b.Pacc, b.A3Vtb);
  k_pgemm2<<<dim3(1,4,NH),256,0,st>>>(b.Z0b, b.A3Vtb, b.WmT);
  k_attn1<<<dim3(NPAD/64,NH),256,0,st>>>(b.Qb, b.KLb, b.WmT, b.OHb);
  k_seqconv<<<NPAD/SCBLK,256,0,st>>>(b.Vb, resk, b.OHb);
  k_gemm<2><<<352*4,256,0,st>>>(b.OHb, woutT, bout,
      b.Xb, nullptr, nullptr, nullptr, nullptr, nullptr, b.zpg, DIM, 352);
}

extern "C" void kernel_launch(void* const* d_in, const int* in_sizes, int n_in,
                              void* d_out, int out_size, void* d_ws, size_t ws_size,
                              hipStream_t stream)
{
  (void)n_in; (void)out_size;
  bool sig_order = (in_sizes[10] == 25088);
  int iL2 = sig_order ? 16 : 10;
  int iLf = sig_order ? 10 : 16;

  const float* h       = (const float*)d_in[0];
  const float* fc1_w   = (const float*)d_in[1];
  const float* fc1_b   = (const float*)d_in[2];
  const float* cls_tok = (const float*)d_in[3];
  const float* l1_lnw  = (const float*)d_in[4];
  const float* l1_lnb  = (const float*)d_in[5];
  const float* l1_wqkv = (const float*)d_in[6];
  const float* l1_wout = (const float*)d_in[7];
  const float* l1_bout = (const float*)d_in[8];
  const float* l1_resk = (const float*)d_in[9];
  const float* l2_lnw  = (const float*)d_in[iL2+0];
  const float* l2_lnb  = (const float*)d_in[iL2+1];
  const float* l2_wqkv = (const float*)d_in[iL2+2];
  const float* l2_wout = (const float*)d_in[iL2+3];
  const float* l2_bout = (const float*)d_in[iL2+4];
  const float* l2_resk = (const float*)d_in[iL2+5];
  const float* k7 = (const float*)d_in[iLf+0];
  const float* b7 = (const float*)d_in[iLf+1];
  const float* k5 = (const float*)d_in[iLf+2];
  const float* b5 = (const float*)d_in[iLf+3];
  const float* k3 = (const float*)d_in[iLf+4];
  const float* b3 = (const float*)d_in[iLf+5];
  const float* nw = (const float*)d_in[22];
  const float* nbb= (const float*)d_in[23];
  const float* w2 = (const float*)d_in[24];
  const float* b2 = (const float*)d_in[25];
  float* out = (float*)d_out;

  char* base = (char*)d_ws;
  auto allocF = [&](size_t n)->float*{
    float* p=(float*)base; base += ((n*sizeof(float)+255)&~(size_t)255); return p; };
  auto allocU = [&](size_t n)->us*{
    us* p=(us*)base; base += ((n*sizeof(us)+255)&~(size_t)255); return p; };

  const size_t S = (size_t)NPAD*DIM;
  const size_t SQ = (size_t)MM*MM;
  Bufs b;
  b.Xb  = allocU(S);
  b.Yb  = allocU(S);
  b.OHb = allocU(S);
  b.Qb  = allocU(S);
  b.Kb  = allocU(S);
  b.Vb  = allocU(S);
  b.Vtb = allocU(S);
  b.QLb = allocU((size_t)NH*MM*DHD);
  b.KLb = allocU((size_t)NH*MM*DHD);
  b.A2  = allocF((size_t)NH*SQ);
  b.A2b = allocU((size_t)NH*SQ);
  b.Z0b = allocU((size_t)NH*SQ);  b.Z0tb = allocU((size_t)NH*SQ);
  b.Z1b = allocU((size_t)NH*SQ);  b.Z1tb = allocU((size_t)NH*SQ);
  b.XZb = allocU((size_t)NH*SQ);  b.XZtb = allocU((size_t)NH*SQ);
  b.T1tb= allocU((size_t)NH*SQ);
  b.T2tb= allocU((size_t)NH*SQ);
  b.A3Vtb = allocU((size_t)NH*MM*DHD);
  b.WmT   = allocU((size_t)NH*MM*DHD);
  b.sums  = allocF(2*(size_t)NH*MM);
  b.scl   = allocF(16);
  b.Pmax  = allocF((size_t)NH*NCH*MM);
  b.Psum  = allocF((size_t)NH*NCH*MM);
  b.Pacc  = allocU((size_t)NH*NCH*MM*DHD);
  b.zpg   = allocU(512);
  us* hb     = allocU((size_t)NTOK*1024);
  us* fc1T   = allocU((size_t)DIM*1024);
  us* wqkvT1 = allocU((size_t)1536*DIM);
  us* wqkvT2 = allocU((size_t)1536*DIM);
  us* woutT1 = allocU((size_t)DIM*DIM);
  us* woutT2 = allocU((size_t)DIM*DIM);
  float* Q0   = allocF((size_t)NPAD*DHD);
  float* K0   = allocF((size_t)NPAD*DHD);
  float* QL0f = allocF((size_t)MM*DHD);
  float* KL0f = allocF((size_t)MM*DHD);
  float* row1 = allocF(256);
  float* rzv  = allocF(256);
  float* mxv  = allocF(256);
  float* sev  = allocF(256);
  us* h2row = allocU(512);
  if ((size_t)(base - (char*)d_ws) > ws_size) return;

  hipMemsetAsync((void*)b.zpg, 0, 1024, stream);

  // input + weight conversions (fp32 -> bf16)
  k_cvt<<<((size_t)NTOK*1024/4 + 255)/256,256,0,stream>>>(h, hb, (size_t)NTOK*1024/4);
  k_wT<<<dim3(32,16),256,0,stream>>>(fc1_w, fc1T, 1024, DIM);
  k_wT<<<dim3(16,48),256,0,stream>>>(l1_wqkv, wqkvT1, DIM, 1536);
  k_wT<<<dim3(16,48),256,0,stream>>>(l2_wqkv, wqkvT2, DIM, 1536);
  k_wT<<<dim3(16,16),256,0,stream>>>(l1_wout, woutT1, DIM, DIM);
  k_wT<<<dim3(16,16),256,0,stream>>>(l2_wout, woutT2, DIM, DIM);

  // stage 0: fc1 + cls token
  k_gemm<0><<<352*4,256,0,stream>>>(hb, fc1T, fc1_b,
      b.Xb, nullptr, nullptr, nullptr, nullptr, nullptr, b.zpg, 1024, 352);
  k_setcls<<<2,256,0,stream>>>(b.Xb, cls_tok);

  // layer 1 + LeFF
  nystrom_layer(b, l1_lnw, l1_lnb, wqkvT1, woutT1, l1_bout, l1_resk, stream);
  k_tfwd<<<dim3(704,16),256,0,stream>>>(b.Xb, b.OHb);
  k_leff<<<dim3(100,512),256,0,stream>>>(b.OHb, k7,b7,k5,b5,k3,b3, b.Qb);
  k_tbwd<<<dim3(704,16),256,0,stream>>>(b.Qb, b.Xb);

  // layer 2 (save h2 row 0)
  nystrom_layer(b, l2_lnw, l2_lnb, wqkvT2, woutT2, l2_bout, l2_resk, stream);
  k_copyu<<<2,256,0,stream>>>(h2row, b.Xb, 512);

  // layer 3 -> h3
  nystrom_layer(b, l2_lnw, l2_lnb, wqkvT2, woutT2, l2_bout, l2_resk, stream);

  // cls-row stage (head 0, l2 weights, LN(h3))
  k_ln<<<N1,256,0,stream>>>(b.Xb, b.Yb, l2_lnw, l2_lnb);
  k_gemm<3><<<352,256,0,stream>>>(b.Yb, wqkvT2, nullptr,
      nullptr, Q0, K0, nullptr, nullptr, nullptr, b.zpg, DIM, 352);
  k_landmark2f<<<2*MM,64,0,stream>>>(Q0, K0, QL0f, KL0f);
  k_nt64<<<dim3(4,4,1),64,0,stream>>>(QL0f, KL0f, b.A2, 0,0,0, MM);
  k_softmax256<<<MM,256,0,stream>>>(b.A2, b.A2b);
  k_csmax<<<1,256,0,stream>>>(b.A2, b.sums);
  k_scale2<<<1,256,0,stream>>>(b.sums, b.scl, 1);
  k_z0t<<<dim3(8,8),256,0,stream>>>(b.A2, b.Z0b, b.Z0tb, b.scl);
  run_pinv(b.A2b, b, 1, stream);
  k_row1<<<1,256,0,stream>>>(Q0, KL0f, row1);
  k_rz<<<1,256,0,stream>>>(row1, b.Z0tb, rzv);
  // L0 = QL0 @ K0^T (256 x NPAD), into Yb's storage (NPAD*256 floats)
  float* L0 = (float*)b.Yb;
  k_nt64<<<dim3(NPAD/64,4,1),64,0,stream>>>(QL0f, K0, L0, 0,0,0, NPAD);
  k_rowstat<<<MM,256,0,stream>>>(L0, mxv, sev);
  k_aout<<<88,256,0,stream>>>(L0, rzv, mxv, sev, out);
  k_final<<<1,256,0,stream>>>(h2row, nw, nbb, w2, b2, out);
}

// Round 18
// 2865.795 us; speedup vs baseline: 1.2140x; 1.2140x over previous
//
#include <hip/hip_runtime.h>

#define NTOK 22500
#define N1   22501
#define NPAD 22528
#define PADR 27
#define DIM  512
#define NH   8
#define DHD  64
#define MM   256
#define LLM  88
#define HSZ  150
#define CSZ  256
#define NCH  88   // NPAD / CSZ

typedef short bf16x8 __attribute__((ext_vector_type(8)));
typedef float f32x4  __attribute__((ext_vector_type(4)));
typedef unsigned short us;

union U8 { bf16x8 v; unsigned short u[8]; };

__device__ __forceinline__ unsigned short f2b(float f){
  unsigned int u = __float_as_uint(f);
  unsigned int r = u + 0x7fffu + ((u>>16)&1u);
  return (unsigned short)(r>>16);
}
__device__ __forceinline__ float bf2f(unsigned short u){
  return __uint_as_float(((unsigned int)u)<<16);
}
__device__ __forceinline__ bf16x8 cvt8(float4 a, float4 b){
  U8 u;
  u.u[0]=f2b(a.x); u.u[1]=f2b(a.y); u.u[2]=f2b(a.z); u.u[3]=f2b(a.w);
  u.u[4]=f2b(b.x); u.u[5]=f2b(b.y); u.u[6]=f2b(b.z); u.u[7]=f2b(b.w);
  return u.v;
}
// async global->LDS, 16B per lane; lds dest = wave-uniform base + lane*16
__device__ __forceinline__ void gld16(const void* g, void* l){
  __builtin_amdgcn_global_load_lds(
      (const __attribute__((address_space(1))) void*)g,
      (__attribute__((address_space(3))) void*)l, 16, 0, 0);
}

// ---------------- reduction helpers ----------------
__device__ __forceinline__ float waveSum(float v){
#pragma unroll
  for (int o=32;o>0;o>>=1) v += __shfl_down(v,o);
  return v;
}
__device__ __forceinline__ float waveMax(float v){
#pragma unroll
  for (int o=32;o>0;o>>=1) v = fmaxf(v,__shfl_down(v,o));
  return v;
}
__device__ __forceinline__ float blockSum256(float v, float* sb){
  v = waveSum(v);
  __syncthreads();
  if ((threadIdx.x&63)==0) sb[threadIdx.x>>6]=v;
  __syncthreads();
  return sb[0]+sb[1]+sb[2]+sb[3];
}
__device__ __forceinline__ float blockMax256(float v, float* sb){
  v = waveMax(v);
  __syncthreads();
  if ((threadIdx.x&63)==0) sb[threadIdx.x>>6]=v;
  __syncthreads();
  return fmaxf(fmaxf(sb[0],sb[1]),fmaxf(sb[2],sb[3]));
}

// ---------------- manual device-scope barrier (all blocks co-resident) ----------------
__device__ __forceinline__ void gbar(unsigned* cnt, unsigned gen, unsigned nb){
  __syncthreads();                    // all block threads done (vmcnt0 drain before s_barrier)
  if (threadIdx.x==0){
    __threadfence();                  // agent-scope release: writeback local L2
    __hip_atomic_fetch_add(cnt, 1u, __ATOMIC_RELAXED, __HIP_MEMORY_SCOPE_AGENT);
    while (__hip_atomic_load(cnt, __ATOMIC_RELAXED, __HIP_MEMORY_SCOPE_AGENT) < gen*nb)
      __builtin_amdgcn_s_sleep(2);
    __threadfence();                  // agent-scope acquire: invalidate local caches
  }
  __syncthreads();
}

// ---------------- fp32 -> bf16 convert ----------------
__global__ void k_cvt(const float* __restrict__ src, us* __restrict__ dst, size_t n4)
{
  size_t i = ((size_t)blockIdx.x*256 + threadIdx.x);
  if (i < n4){
    float4 v = *(const float4*)(src + i*4);
    ushort4 u; u.x=f2b(v.x); u.y=f2b(v.y); u.z=f2b(v.z); u.w=f2b(v.w);
    *(ushort4*)(dst + i*4) = u;
  }
}

// ---------------- weight transpose+cvt: W fp32 [K][N] -> Bt bf16 [N][K] ----------------
__global__ void k_wT(const float* __restrict__ W, us* __restrict__ Bt, int K, int N)
{
  __shared__ float tile[32][33];
  int tx = threadIdx.x&31, ty = threadIdx.x>>5;
  int k0 = blockIdx.x*32, n0 = blockIdx.y*32;
#pragma unroll
  for (int i=0;i<4;++i){
    int k = k0+ty+i*8;
    if (k<K && n0+tx<N) tile[ty+i*8][tx] = W[(size_t)k*N + n0+tx];
  }
  __syncthreads();
#pragma unroll
  for (int i=0;i<4;++i){
    int n = n0+ty+i*8, k = k0+tx;
    if (n<N && k<K) Bt[(size_t)n*K + k] = f2b(tile[tx][ty+i*8]);
  }
}

// ---------------- V transpose: Vb [h][p][d] -> Vtb [h][d][p] ----------------
__global__ void k_vT(const us* __restrict__ V, us* __restrict__ Vt)
{
  __shared__ us tile[32][33];
  int tx = threadIdx.x&31, ty = threadIdx.x>>5;
  int p0 = blockIdx.x*32;
  int h = blockIdx.y>>1, d0 = (blockIdx.y&1)*32;
#pragma unroll
  for (int i=0;i<4;++i){
    int p = p0+ty+i*8;
    tile[ty+i*8][tx] = V[((size_t)h*NPAD+p)*DHD + d0+tx];
  }
  __syncthreads();
#pragma unroll
  for (int i=0;i<4;++i){
    int d = d0+ty+i*8;
    Vt[((size_t)h*DHD+d)*NPAD + p0+tx] = tile[tx][ty+i*8];
  }
}

// ---------------- MFMA GEMM (64x128 tile), 3-buffer counted-vmcnt pipeline ----------------
// MODE 0: fc1 (A=hb bf16 -> X bf16 relu)   MODE 1: qkv (A=Yb bf16 -> Qb/Kb/Vb)
// MODE 2: wout (A=OHb bf16, X bf16 +=)     MODE 3: qk0 (A=Yb bf16 -> Q0/K0 fp32)
template<int MODE>
__global__ __launch_bounds__(256) void k_gemm(
    const us* __restrict__ Ab, const us* __restrict__ Bt, const float* __restrict__ bias,
    us* __restrict__ Xb, float* __restrict__ Cf, float* __restrict__ C2,
    us* __restrict__ Q_, us* __restrict__ K_, us* __restrict__ V_,
    const us* __restrict__ zpg, int Kd, int mtn)
{
  constexpr int BM = 64;
  constexpr int BUFE = BM*64 + 128*64;    // 12288 us per buffer
  __shared__ us SM[3*BUFE];               // 72 KB
  const int tid = threadIdx.x;
  const int bid = blockIdx.x;
  const int ntile = bid / mtn;            // m-fastest: consecutive blocks share B panel
  const int m0 = (bid % mtn)*BM, n0 = ntile*128;
  const int lane = tid & 63;
  const int wid = tid >> 6;
  const int wm = (wid>>1)*32, wn = (wid&1)*64;
  f32x4 acc[2][4] = {};
  const int NT = Kd >> 6;

  auto stage = [&](int t, int buf){
    us* As = SM + buf*BUFE;
    us* Bs = As + BM*64;
    int k0 = t*64;
#pragma unroll
    for (int i=0;i<2;++i){
      int c = wid*2+i;
      int row = c*8 + (lane>>3);
      int scol8 = ((lane&7) ^ (row&7))*8;
      int gm = m0+row;
      const us* ga;
      if (MODE==0)      ga = (gm<NTOK) ? Ab + (size_t)gm*Kd + k0 + scol8 : zpg + scol8;
      else if (MODE==2) ga = Ab + ((size_t)((gm<N1?gm:0)+PADR))*Kd + k0 + scol8;
      else              ga = (gm>=PADR) ? Ab + (size_t)(gm-PADR)*Kd + k0 + scol8 : zpg + scol8;
      gld16(ga, &As[c*512]);
    }
#pragma unroll
    for (int i=0;i<4;++i){
      int c = wid*4+i;
      int row = c*8 + (lane>>3);
      int scol8 = ((lane&7) ^ (row&7))*8;
      int vn = n0+row;
      if (MODE==3) vn = (vn<64)? vn : vn+448;
      gld16(Bt + (size_t)vn*Kd + k0 + scol8, &Bs[c*512]);
    }
  };

  stage(0, 0);
  stage(1, 1);
  for (int t=0; t<NT; ++t){
    asm volatile("s_waitcnt vmcnt(6)" ::: "memory");   // oldest stage (t) landed in LDS
    __builtin_amdgcn_s_barrier();                      // raw barrier: NO vmcnt drain
    asm volatile("" ::: "memory");
    if (t+2 < NT) stage(t+2, (t+2)%3);                 // buf (t+2)%3: last read at iter t-1
    us* As = SM + (t%3)*BUFE;
    us* Bs = As + BM*64;
#pragma unroll
    for (int ks=0; ks<2; ++ks){
      const int kk = ks*32 + (lane>>4)*8;
      bf16x8 af[2], bfm[4];
#pragma unroll
      for (int tt=0;tt<2;++tt){
        int r = wm + tt*16 + (lane&15);
        af[tt] = *(bf16x8*)(&As[r*64 + (kk ^ ((r&7)<<3))]);
      }
#pragma unroll
      for (int tt=0;tt<4;++tt){
        int c = wn + tt*16 + (lane&15);
        bfm[tt] = *(bf16x8*)(&Bs[c*64 + (kk ^ ((c&7)<<3))]);
      }
#pragma unroll
      for (int mt=0;mt<2;++mt)
#pragma unroll
        for (int nt=0;nt<4;++nt)
          acc[mt][nt] = __builtin_amdgcn_mfma_f32_16x16x32_bf16(af[mt], bfm[nt], acc[mt][nt], 0,0,0);
    }
  }
  __syncthreads();
  const int rbase = (lane>>4)*4;
  const int cl = lane&15;
  if (MODE==3){
#pragma unroll
    for (int mt=0;mt<2;++mt)
#pragma unroll
      for (int r=0;r<4;++r){
        int gm = m0 + wm + mt*16 + rbase + r;
#pragma unroll
        for (int nt=0;nt<4;++nt){
          int gn = n0 + wn + nt*16 + cl;
          float v = acc[mt][nt][r];
          if (gn < 64) Cf[(size_t)gm*DHD + gn] = v*0.125f;
          else         C2[(size_t)gm*DHD + (gn-64)] = v;
        }
      }
    return;
  }
  // LDS relayout epilogues (coalesced 16B bf16 stores)
  const float sc1 = (MODE==1 && (ntile>>2)==0) ? 0.125f : 1.f;
#pragma unroll
  for (int mt=0;mt<2;++mt)
#pragma unroll
    for (int r=0;r<4;++r){
      int row = wm + mt*16 + rbase + r;
#pragma unroll
      for (int nt=0;nt<4;++nt){
        int col = wn + nt*16 + cl;
        float v = acc[mt][nt][r];
        if (MODE==0){ v += bias[n0+col]; v = v>0.f?v:0.f; }
        else if (MODE==2){ v += bias[n0+col]; }
        else v *= sc1;
        SM[row*128 + col] = f2b(v);
      }
    }
  __syncthreads();
  if (MODE==1){
    const int sec = ntile>>2;
    us* dst = sec==0 ? Q_ : (sec==1 ? K_ : V_);
#pragma unroll
    for (int i=0;i<4;++i){
      int v8 = i*256 + tid;
      int row = v8>>4, c8 = (v8&15)*8;
      int gm = m0 + row, gn = n0 + c8;
      int hh = (gn>>6)&7, d = gn&63;
      *(bf16x8*)(dst + ((size_t)hh*NPAD+gm)*DHD + d) = *(bf16x8*)(&SM[row*128 + c8]);
    }
  } else if (MODE==0){
#pragma unroll
    for (int i=0;i<4;++i){
      int v8 = i*256 + tid;
      int row = v8>>4, c8 = (v8&15)*8;
      int gm = m0 + row;
      if (gm < NTOK)
        *(bf16x8*)(Xb + (size_t)(1+gm)*DIM + n0 + c8) = *(bf16x8*)(&SM[row*128 + c8]);
    }
  } else {  // MODE 2: bf16 RMW on X
#pragma unroll
    for (int i=0;i<4;++i){
      int v8 = i*256 + tid;
      int row = v8>>4, c8 = (v8&15)*8;
      int gm = m0 + row;
      if (gm < N1){
        us* p = Xb + (size_t)gm*DIM + n0 + c8;
        U8 xo, ad, o;
        xo.v = *(bf16x8*)p;
        ad.v = *(bf16x8*)(&SM[row*128 + c8]);
#pragma unroll
        for (int j=0;j<8;++j) o.u[j] = f2b(bf2f(xo.u[j]) + bf2f(ad.u[j]));
        *(bf16x8*)p = o.v;
      }
    }
  }
}

__global__ void k_setcls(us* __restrict__ X, const float* __restrict__ cls){
  int i = blockIdx.x*256 + threadIdx.x;
  if (i < DIM) X[i] = f2b(cls[i]);
}
__global__ void k_copyu(us* __restrict__ d, const us* __restrict__ s, size_t n){
  size_t i = (size_t)blockIdx.x*256 + threadIdx.x;
  if (i<n) d[i]=s[i];
}

// ---------------- layernorm: bf16 in -> bf16 out ----------------
__global__ void k_ln(const us* __restrict__ X, us* __restrict__ Y,
                     const float* __restrict__ w, const float* __restrict__ b)
{
  __shared__ float sb[4];
  const us* x = X + (size_t)blockIdx.x*DIM;
  us* y = Y + (size_t)blockIdx.x*DIM;
  int t = threadIdx.x;
  ushort2 xv = *(const ushort2*)(x + 2*t);
  float a0=bf2f(xv.x), a1=bf2f(xv.y);
  float s = blockSum256(a0+a1, sb);
  float q = blockSum256(a0*a0+a1*a1, sb);
  float mean = s*(1.f/512.f);
  float var = q*(1.f/512.f) - mean*mean;
  float rstd = rsqrtf(var+1e-5f);
  float2 wv = *(const float2*)(w + 2*t);
  float2 bv = *(const float2*)(b + 2*t);
  ushort2 o;
  o.x = f2b((a0-mean)*rstd*wv.x+bv.x);
  o.y = f2b((a1-mean)*rstd*wv.y+bv.y);
  *(ushort2*)(y + 2*t) = o;
}

// ---------------- landmarks (fused Q+K) ----------------
__global__ void k_landmark2(const us* __restrict__ Q, const us* __restrict__ K,
                            us* __restrict__ QL, us* __restrict__ KL)
{
  int hm = blockIdx.x;
  bool isK = hm >= NH*MM;
  if (isK) hm -= NH*MM;
  int h = hm>>8, m = hm&255; int d = threadIdx.x;
  const us* base = (isK?K:Q) + ((size_t)h*NPAD + (size_t)m*LLM)*DHD + d;
  float s = 0.f;
  for (int j=0;j<LLM;++j) s += bf2f(base[(size_t)j*DHD]);
  (isK?KL:QL)[((size_t)h*MM + m)*DHD + d] = f2b(s * (1.f/(float)LLM));
}
__global__ void k_landmark2f(const float* __restrict__ Q, const float* __restrict__ K,
                             float* __restrict__ QL, float* __restrict__ KL)
{
  int hm = blockIdx.x;
  bool isK = hm >= MM;
  int m = isK ? hm-MM : hm; int d = threadIdx.x;
  const float* base = (isK?K:Q) + (size_t)m*LLM*DHD + d;
  float s = 0.f;
  for (int j=0;j<LLM;++j) s += base[(size_t)j*DHD];
  (isK?KL:QL)[(size_t)m*DHD + d] = s * (1.f/(float)LLM);
}

// ---------------- MFMA NT gemm K=64, fp32 inputs ----------------
__global__ __launch_bounds__(64) void k_nt64(const float* __restrict__ A,
    const float* __restrict__ B, float* __restrict__ C,
    long sA, long sB, long sC, int Nr)
{
  int lane = threadIdx.x;
  int n0 = blockIdx.x*64, m0 = blockIdx.y*64;
  A += (size_t)blockIdx.z*sA; B += (size_t)blockIdx.z*sB; C += (size_t)blockIdx.z*sC;
  f32x4 acc[4][4] = {};
#pragma unroll
  for (int ks=0;ks<2;++ks){
    int kk = ks*32 + (lane>>4)*8;
    bf16x8 af[4], bfr[4];
#pragma unroll
    for (int mt=0;mt<4;++mt){
      const float* p = A + (size_t)(m0+mt*16+(lane&15))*64 + kk;
      af[mt] = cvt8(*(const float4*)p, *(const float4*)(p+4));
    }
#pragma unroll
    for (int nt=0;nt<4;++nt){
      const float* p = B + (size_t)(n0+nt*16+(lane&15))*64 + kk;
      bfr[nt] = cvt8(*(const float4*)p, *(const float4*)(p+4));
    }
#pragma unroll
    for (int mt=0;mt<4;++mt)
#pragma unroll
      for (int nt=0;nt<4;++nt)
        acc[mt][nt] = __builtin_amdgcn_mfma_f32_16x16x32_bf16(af[mt], bfr[nt], acc[mt][nt], 0,0,0);
  }
#pragma unroll
  for (int mt=0;mt<4;++mt)
#pragma unroll
    for (int r=0;r<4;++r){
      int row = m0+mt*16+(lane>>4)*4+r;
#pragma unroll
      for (int nt=0;nt<4;++nt){
        int col = n0+nt*16+(lane&15);
        C[(size_t)row*Nr + col] = acc[mt][nt][r];
      }
    }
}

// ---------------- MFMA NT gemm K=64, bf16 inputs (attn2 logits) ----------------
__global__ __launch_bounds__(64) void k_nt64b(const us* __restrict__ A,
    const us* __restrict__ B, float* __restrict__ C,
    long sA, long sB, long sC, int Nr)
{
  int lane = threadIdx.x;
  int n0 = blockIdx.x*64, m0 = blockIdx.y*64;
  A += (size_t)blockIdx.z*sA; B += (size_t)blockIdx.z*sB; C += (size_t)blockIdx.z*sC;
  f32x4 acc[4][4] = {};
#pragma unroll
  for (int ks=0;ks<2;++ks){
    int kk = ks*32 + (lane>>4)*8;
    bf16x8 af[4], bfr[4];
#pragma unroll
    for (int mt=0;mt<4;++mt)
      af[mt] = *(const bf16x8*)(A + (size_t)(m0+mt*16+(lane&15))*64 + kk);
#pragma unroll
    for (int nt=0;nt<4;++nt)
      bfr[nt] = *(const bf16x8*)(B + (size_t)(n0+nt*16+(lane&15))*64 + kk);
#pragma unroll
    for (int mt=0;mt<4;++mt)
#pragma unroll
      for (int nt=0;nt<4;++nt)
        acc[mt][nt] = __builtin_amdgcn_mfma_f32_16x16x32_bf16(af[mt], bfr[nt], acc[mt][nt], 0,0,0);
  }
#pragma unroll
  for (int mt=0;mt<4;++mt)
#pragma unroll
    for (int r=0;r<4;++r){
      int row = m0+mt*16+(lane>>4)*4+r;
#pragma unroll
      for (int nt=0;nt<4;++nt){
        int col = n0+nt*16+(lane&15);
        C[(size_t)row*Nr + col] = acc[mt][nt][r];
      }
    }
}

// ---------------- pinv gemm tile body (shared by fused k_pinv) ----------------
// PM 0: C=A@B (write C+Ct)   PM 1: C=alpha*(dc*A - A@B) (write Ct, C if writeC)
template<int PM>
__device__ __forceinline__ void pgemm_tile(const us* __restrict__ A,
    const us* __restrict__ Bt, us* __restrict__ C, us* __restrict__ Ct,
    float dc, float alpha, int writeC, us* As, us* Bs)
{
  const int tid = threadIdx.x, lane = tid&63, wid = tid>>6;
  const int n0 = blockIdx.x*64, m0 = blockIdx.y*64;
  const us* Ab = A + (size_t)blockIdx.z*65536;
  const us* Bb = Bt + (size_t)blockIdx.z*65536;
  for (int i=tid; i<4096; i+=256){
    int r = i>>6, c4 = (i&63)*4;
    *(ushort4*)(&As[r*256 + (c4 ^ ((r&7)<<3))]) = *(const ushort4*)(Ab + (size_t)(m0+r)*256 + c4);
    *(ushort4*)(&Bs[r*256 + (c4 ^ ((r&7)<<3))]) = *(const ushort4*)(Bb + (size_t)(n0+r)*256 + c4);
  }
  __syncthreads();
  const int wm = (wid>>1)*32, wn = (wid&1)*32;
  f32x4 acc[2][2] = {};
#pragma unroll
  for (int ks=0;ks<8;++ks){
    int kk = ks*32 + (lane>>4)*8;
    bf16x8 af[2], bfr[2];
#pragma unroll
    for (int t=0;t<2;++t){
      int rr = wm + t*16 + (lane&15);
      af[t] = *(const bf16x8*)(&As[rr*256 + (kk ^ ((rr&7)<<3))]);
      int cc = wn + t*16 + (lane&15);
      bfr[t] = *(const bf16x8*)(&Bs[cc*256 + (kk ^ ((cc&7)<<3))]);
    }
#pragma unroll
    for (int mt=0;mt<2;++mt)
#pragma unroll
      for (int nt=0;nt<2;++nt)
        acc[mt][nt] = __builtin_amdgcn_mfma_f32_16x16x32_bf16(af[mt], bfr[nt], acc[mt][nt], 0,0,0);
  }
  // fold PM1 diag term (A read from LDS), keep in regs
  float vv[2][4][2];
#pragma unroll
  for (int mt=0;mt<2;++mt)
#pragma unroll
    for (int q=0;q<4;++q){
      int rl = wm + mt*16 + (lane>>4)*4 + q;
#pragma unroll
      for (int nt=0;nt<2;++nt){
        int clx = wn + nt*16 + (lane&15);
        float v = acc[mt][nt][q];
        if (PM==1) v = alpha*(dc*bf2f(As[rl*256 + (clx ^ ((rl&7)<<3))]) - v);
        vv[mt][q][nt] = v;
      }
    }
  __syncthreads();
  // write 64x64 tile into LDS (swizzled), reuse As
  us* TT = As;
#pragma unroll
  for (int mt=0;mt<2;++mt)
#pragma unroll
    for (int q=0;q<4;++q){
      int rl = wm + mt*16 + (lane>>4)*4 + q;
      int sw = (rl&7)<<3;
#pragma unroll
      for (int nt=0;nt<2;++nt){
        int clx = wn + nt*16 + (lane&15);
        TT[rl*64 + (clx ^ sw)] = f2b(vv[mt][q][nt]);
      }
    }
  __syncthreads();
  // coalesced transposed store
  {
    int c = tid>>2, r0 = (tid&3)*16;
    U8 b0, b1;
#pragma unroll
    for (int i=0;i<8;++i){
      int r = r0+i;       b0.u[i] = TT[r*64 + (c ^ ((r&7)<<3))];
      int r2 = r0+8+i;    b1.u[i] = TT[r2*64 + (c ^ ((r2&7)<<3))];
    }
    us* dst = Ct + (size_t)blockIdx.z*65536 + (size_t)(n0+c)*256 + m0 + r0;
    *(bf16x8*)dst = b0.v;
    *(bf16x8*)(dst+8) = b1.v;
  }
  if (PM==0 || writeC){
    int rr = tid>>2, c0 = (tid&3)*16;
    int sw = (rr&7)<<3;
    bf16x8 x0 = *(const bf16x8*)(&TT[rr*64 + (c0 ^ sw)]);
    bf16x8 x1 = *(const bf16x8*)(&TT[rr*64 + ((c0+8) ^ sw)]);
    us* dc2 = C + (size_t)blockIdx.z*65536 + (size_t)(m0+rr)*256 + n0 + c0;
    *(bf16x8*)dc2 = x0;
    *(bf16x8*)(dc2+8) = x1;
  }
}

// ---------------- fused pinv: 6 iters x 4 gemm phases, 1 launch, manual barrier ----------------
__global__ __launch_bounds__(256) void k_pinv(const us* __restrict__ A2b,
    us* Z0, us* Z0t, us* Z1, us* Z1t,
    us* XZ, us* XZt, us* T1t, us* T2t,
    unsigned* cnt, unsigned nb)
{
  __shared__ us As[64*256];
  __shared__ us Bs[64*256];
  us *Zc=Z0, *Zct=Z0t, *Zn=Z1, *Znt=Z1t;
  unsigned gen = 0;
  for (int it=0; it<6; ++it){
    pgemm_tile<0>(A2b, Zct, XZ, XZt, 0.f, 1.f, 1, As, Bs);
    gbar(cnt, ++gen, nb);
    pgemm_tile<1>(XZ, XZt, nullptr, T1t, 7.f, 1.f, 0, As, Bs);
    gbar(cnt, ++gen, nb);
    pgemm_tile<1>(XZ, T1t, nullptr, T2t, 15.f, 1.f, 0, As, Bs);
    gbar(cnt, ++gen, nb);
    pgemm_tile<1>(Zc, T2t, Zn, Znt, 13.f, 0.25f, 1, As, Bs);
    if (it < 5) gbar(cnt, ++gen, nb);
    us* s1=Zc; Zc=Zn; Zn=s1;
    us* s2=Zct; Zct=Znt; Znt=s2;
  }
  // 6 iterations = even number of swaps -> final Z in Z0/Z0t
}

// ---------------- WmT gemm (dispatch) ----------------
__global__ __launch_bounds__(256) void k_pgemm2(const us* __restrict__ A,
    const us* __restrict__ Bt, us* __restrict__ Ct)
{
  __shared__ us As[16384];
  __shared__ us Bs[16384];
  const int tid = threadIdx.x, lane = tid&63, wid = tid>>6;
  const int n0 = 0, m0 = blockIdx.y*64;
  const us* Ab = A + (size_t)blockIdx.z*65536;
  const us* Bb = Bt + (size_t)blockIdx.z*16384;
  for (int i=tid; i<4096; i+=256){
    int r = i>>6, c4 = (i&63)*4;
    *(ushort4*)(&As[r*256 + (c4 ^ ((r&7)<<3))]) = *(const ushort4*)(Ab + (size_t)(m0+r)*256 + c4);
    if (r < 64)
      *(ushort4*)(&Bs[r*256 + (c4 ^ ((r&7)<<3))]) = *(const ushort4*)(Bb + (size_t)(n0+r)*256 + c4);
  }
  __syncthreads();
  const int wm = (wid>>1)*32, wn = (wid&1)*32;
  f32x4 acc[2][2] = {};
#pragma unroll
  for (int ks=0;ks<8;++ks){
    int kk = ks*32 + (lane>>4)*8;
    bf16x8 af[2], bfr[2];
#pragma unroll
    for (int t=0;t<2;++t){
      int rr = wm + t*16 + (lane&15);
      af[t] = *(const bf16x8*)(&As[rr*256 + (kk ^ ((rr&7)<<3))]);
      int cc = wn + t*16 + (lane&15);
      bfr[t] = *(const bf16x8*)(&Bs[cc*256 + (kk ^ ((cc&7)<<3))]);
    }
#pragma unroll
    for (int mt=0;mt<2;++mt)
#pragma unroll
      for (int nt=0;nt<2;++nt)
        acc[mt][nt] = __builtin_amdgcn_mfma_f32_16x16x32_bf16(af[mt], bfr[nt], acc[mt][nt], 0,0,0);
  }
#pragma unroll
  for (int mt=0;mt<2;++mt)
#pragma unroll
    for (int r=0;r<4;++r){
      int row = m0 + wm + mt*16 + (lane>>4)*4 + r;
#pragma unroll
      for (int nt=0;nt<2;++nt){
        int col = n0 + wn + nt*16 + (lane&15);
        Ct[(size_t)blockIdx.z*16384 + (size_t)col*256 + row] = f2b(acc[mt][nt][r]);
      }
    }
}

// ---------------- small elementwise ----------------
__global__ void k_softmax256(float* __restrict__ S, us* __restrict__ Sb)
{
  __shared__ float sb[4];
  float* row = S + ((size_t)blockIdx.x<<8);
  float x = row[threadIdx.x];
  float m = blockMax256(x, sb);
  float e = __expf(x-m);
  float s = blockSum256(e, sb);
  float p = e/s;
  row[threadIdx.x] = p;
  Sb[((size_t)blockIdx.x<<8) + threadIdx.x] = f2b(p);
}
__global__ void k_csmax(const float* __restrict__ A2, float* __restrict__ sums)
{
  __shared__ float sb[4];
  int b = blockIdx.x, j = threadIdx.x;
  const float* Ab = A2 + ((size_t)b<<16);
  float s = 0.f;
  for (int i=0;i<256;++i) s += Ab[((size_t)i<<8)+j];
  float m = blockMax256(s, sb);
  if (j==0) sums[b] = m;
}
__global__ void k_scale2(const float* __restrict__ sums, float* __restrict__ scl, int nb)
{
  __shared__ float sb[4];
  float m=-1e30f;
  for (int i=threadIdx.x;i<nb;i+=256) m = fmaxf(m, sums[i]);
  m = blockMax256(m, sb);
  if (threadIdx.x==0) scl[0] = 1.f/m;
}
// tiled Z0: Zt = A2*s (row-major), Z = A2^T*s, both coalesced via LDS 32x32
__global__ void k_z0t(const float* __restrict__ A2, us* __restrict__ Z, us* __restrict__ Zt,
                      const float* __restrict__ scl)
{
  __shared__ us tile[32][33];
  int tx = threadIdx.x&31, ty = threadIdx.x>>5;
  int i0 = blockIdx.x*32;
  int head = blockIdx.y>>3, j0 = (blockIdx.y&7)*32;
  float s = scl[0];
  const float* Ab = A2 + (size_t)head*65536;
  us* Zh  = Z  + (size_t)head*65536;
  us* Zth = Zt + (size_t)head*65536;
#pragma unroll
  for (int ii=0;ii<4;++ii){
    int i = i0+ty+ii*8;
    us bv = f2b(Ab[(size_t)i*256 + j0+tx]*s);
    Zth[(size_t)i*256 + j0+tx] = bv;
    tile[ty+ii*8][tx] = bv;
  }
  __syncthreads();
#pragma unroll
  for (int ii=0;ii<4;++ii){
    int j = j0+ty+ii*8;
    Zh[(size_t)j*256 + i0+tx] = tile[tx][ty+ii*8];
  }
}

// ---------------- attn3: MFMA flash (8 waves x 32 query rows) ----------------
__global__ __launch_bounds__(512) void k_attn3(const us* __restrict__ QLb,
    const us* __restrict__ Kb, const us* __restrict__ Vt,
    float* __restrict__ Pmax, float* __restrict__ Psum, us* __restrict__ Pacc)
{
  __shared__ us Ks[64*64];       // 8 KB
  __shared__ us Vs[64*64];       // 8 KB
  __shared__ us Ps[8*32*64];     // 32 KB (per-wave 32x64 P tile)
  int h = blockIdx.y, cx = blockIdx.x;
  int tid = threadIdx.x, wid = tid>>6, lane = tid&63;   // wid 0..7
  bf16x8 aq[2][2];
#pragma unroll
  for (int mt=0;mt<2;++mt){
    const us* qp = QLb + ((size_t)h*MM + wid*32 + mt*16 + (lane&15))*DHD;
#pragma unroll
    for (int ks=0;ks<2;++ks)
      aq[mt][ks] = *(const bf16x8*)(qp + ks*32 + (lane>>4)*8);
  }
  float m_[2][4], l_[2][4];
  f32x4 acc[2][4] = {};
#pragma unroll
  for (int mt=0;mt<2;++mt)
#pragma unroll
    for (int r=0;r<4;++r){ m_[mt][r] = -1e30f; l_[mt][r] = 0.f; }

  us* Pw = &Ps[wid*2048];
  for (int t=0;t<4;++t){
    int kb0 = cx*CSZ + t*64;
    __syncthreads();
    for (int i=tid;i<1024;i+=512){
      int rr = i>>4, c4 = (i&15)*4;
      ushort4 ku = *(const ushort4*)(Kb + ((size_t)h*NPAD + kb0 + rr)*DHD + c4);
      *(ushort4*)(&Ks[rr*64 + (c4 ^ ((rr&7)<<3))]) = ku;
      ushort4 vu = *(const ushort4*)(Vt + ((size_t)h*DHD + rr)*NPAD + kb0 + c4);
      *(ushort4*)(&Vs[rr*64 + (c4 ^ ((rr&7)<<3))]) = vu;
    }
    __syncthreads();
    f32x4 s[2][4] = {};
    __builtin_amdgcn_s_setprio(1);
#pragma unroll
    for (int ks=0;ks<2;++ks){
      int kk = ks*32 + (lane>>4)*8;
      bf16x8 kbf[4];
#pragma unroll
      for (int nt=0;nt<4;++nt){
        int key = nt*16 + (lane&15);
        kbf[nt] = *(const bf16x8*)(&Ks[key*64 + (kk ^ ((key&7)<<3))]);
      }
#pragma unroll
      for (int mt=0;mt<2;++mt)
#pragma unroll
        for (int nt=0;nt<4;++nt)
          s[mt][nt] = __builtin_amdgcn_mfma_f32_16x16x32_bf16(aq[mt][ks], kbf[nt], s[mt][nt], 0,0,0);
    }
    __builtin_amdgcn_s_setprio(0);
#pragma unroll
    for (int mt=0;mt<2;++mt){
#pragma unroll
      for (int r=0;r<4;++r){
        float mx = fmaxf(fmaxf(s[mt][0][r], s[mt][1][r]), fmaxf(s[mt][2][r], s[mt][3][r]));
#pragma unroll
        for (int off=8;off>=1;off>>=1) mx = fmaxf(mx, __shfl_xor(mx, off));
        float mn = fmaxf(m_[mt][r], mx);
        float f = __expf(m_[mt][r]-mn);
        float la = 0.f;
#pragma unroll
        for (int nt=0;nt<4;++nt){ float p=__expf(s[mt][nt][r]-mn); s[mt][nt][r]=p; la+=p; }
#pragma unroll
        for (int off=8;off>=1;off>>=1) la += __shfl_xor(la, off);
        l_[mt][r] = l_[mt][r]*f + la;
        m_[mt][r] = mn;
#pragma unroll
        for (int dt=0;dt<4;++dt) acc[mt][dt][r] *= f;
      }
    }
#pragma unroll
    for (int mt=0;mt<2;++mt)
#pragma unroll
      for (int r=0;r<4;++r){
        int row = mt*16 + (lane>>4)*4 + r;      // 0..31 within wave
        int sw = (row&7)<<3;
#pragma unroll
        for (int nt=0;nt<4;++nt){
          int col = nt*16 + (lane&15);
          Pw[row*64 + (col ^ sw)] = f2b(s[mt][nt][r]);
        }
      }
    __builtin_amdgcn_s_setprio(1);
#pragma unroll
    for (int ks=0;ks<2;++ks){
      int kk = ks*32 + (lane>>4)*8;
      bf16x8 pa[2], vb[4];
#pragma unroll
      for (int mt=0;mt<2;++mt){
        int arow = mt*16 + (lane&15);
        pa[mt] = *(const bf16x8*)(&Pw[arow*64 + (kk ^ ((arow&7)<<3))]);
      }
#pragma unroll
      for (int dt=0;dt<4;++dt){
        int d = dt*16 + (lane&15);
        vb[dt] = *(const bf16x8*)(&Vs[d*64 + (kk ^ ((d&7)<<3))]);
      }
#pragma unroll
      for (int mt=0;mt<2;++mt)
#pragma unroll
        for (int dt=0;dt<4;++dt)
          acc[mt][dt] = __builtin_amdgcn_mfma_f32_16x16x32_bf16(pa[mt], vb[dt], acc[mt][dt], 0,0,0);
    }
    __builtin_amdgcn_s_setprio(0);
  }
  size_t pbase = ((size_t)h*NCH + cx)*MM;
#pragma unroll
  for (int mt=0;mt<2;++mt)
#pragma unroll
    for (int r=0;r<4;++r){
      int row = wid*32 + mt*16 + (lane>>4)*4 + r;
      if ((lane&15)==0){ Pmax[pbase+row]=m_[mt][r]; Psum[pbase+row]=l_[mt][r]; }
#pragma unroll
      for (int dt=0;dt<4;++dt)
        Pacc[(pbase+row)*DHD + dt*16+(lane&15)] = f2b(acc[mt][dt][r]);
    }
}

__global__ void k_attn3_merge(const float* __restrict__ Pmax, const float* __restrict__ Psum,
    const us* __restrict__ Pacc, us* __restrict__ A3Vtb)
{
  int hm = blockIdx.x; int h = hm>>8, m = hm&255; int d = threadIdx.x;
  float gm = -1e30f;
  for (int c=0;c<NCH;++c) gm = fmaxf(gm, Pmax[((size_t)h*NCH+c)*MM+m]);
  float tot=0.f, acc=0.f;
  for (int c=0;c<NCH;++c){
    size_t pi = ((size_t)h*NCH+c)*MM+m;
    float w = __expf(Pmax[pi]-gm);
    tot += Psum[pi]*w;
    acc += bf2f(Pacc[pi*DHD+d])*w;
  }
  A3Vtb[((size_t)h*DHD + d)*MM + m] = f2b(acc/tot);
}

// ---------------- attn1 ----------------
__global__ __launch_bounds__(256) void k_attn1(const us* __restrict__ Qb,
    const us* __restrict__ KLb, const us* __restrict__ WmT,
    us* __restrict__ OH)
{
  __shared__ us KWs[64*256];
  __shared__ us Ps[64*256];
  int h = blockIdx.y, tid = threadIdx.x;
  int wid = tid>>6, lane = tid&63;
  int q0 = blockIdx.x*64;
  for (int i=tid; i<4096; i+=256){
    int lm = i>>4, k4 = (i&15)*4;
    *(ushort4*)(&KWs[lm*64 + (k4 ^ ((lm&7)<<3))]) =
        *(const ushort4*)(KLb + ((size_t)h*MM + lm)*DHD + k4);
  }
  bf16x8 aq[2];
  const us* qp = Qb + ((size_t)h*NPAD + q0 + wid*16 + (lane&15))*DHD;
#pragma unroll
  for (int ks=0;ks<2;++ks)
    aq[ks] = *(const bf16x8*)(qp + ks*32 + (lane>>4)*8);
  __syncthreads();
  f32x4 s[16];
#pragma unroll
  for (int nt=0;nt<16;++nt) s[nt] = (f32x4){0.f,0.f,0.f,0.f};
  __builtin_amdgcn_s_setprio(1);
#pragma unroll
  for (int ks=0;ks<2;++ks){
    int kk = ks*32 + (lane>>4)*8;
#pragma unroll
    for (int nt=0;nt<16;++nt){
      int col = nt*16 + (lane&15);
      bf16x8 b = *(const bf16x8*)(&KWs[col*64 + (kk ^ ((col&7)<<3))]);
      s[nt] = __builtin_amdgcn_mfma_f32_16x16x32_bf16(aq[ks], b, s[nt], 0,0,0);
    }
  }
  __builtin_amdgcn_s_setprio(0);
  float rcp[4];
#pragma unroll
  for (int r=0;r<4;++r){
    float m = -1e30f;
#pragma unroll
    for (int nt=0;nt<16;++nt) m = fmaxf(m, s[nt][r]);
#pragma unroll
    for (int off=8;off>=1;off>>=1) m = fmaxf(m, __shfl_xor(m, off));
    float l = 0.f;
#pragma unroll
    for (int nt=0;nt<16;++nt){ float p=__expf(s[nt][r]-m); s[nt][r]=p; l+=p; }
#pragma unroll
    for (int off=8;off>=1;off>>=1) l += __shfl_xor(l, off);
    rcp[r] = 1.f/l;
  }
  int prow_base = wid*16 + (lane>>4)*4;
#pragma unroll
  for (int nt=0;nt<16;++nt){
    int col = nt*16 + (lane&15);
#pragma unroll
    for (int r=0;r<4;++r){
      int row = prow_base + r;
      Ps[row*256 + (col ^ ((row&7)<<3))] = f2b(s[nt][r]);
    }
  }
  __syncthreads();
  for (int i=tid; i<4096; i+=256){
    int d = i>>6, k4 = (i&63)*4;
    ushort4 u = *(const ushort4*)(WmT + ((size_t)h*DHD + d)*MM + k4);
    *(ushort4*)(&KWs[d*256 + (k4 ^ ((d&7)<<3))]) = u;
  }
  __syncthreads();
  f32x4 acc[4] = {};
  int arow = wid*16 + (lane&15);
  __builtin_amdgcn_s_setprio(1);
#pragma unroll
  for (int ks=0;ks<8;++ks){
    int kk = ks*32 + (lane>>4)*8;
    bf16x8 a = *(const bf16x8*)(&Ps[arow*256 + (kk ^ ((arow&7)<<3))]);
#pragma unroll
    for (int dt=0;dt<4;++dt){
      int d = dt*16 + (lane&15);
      bf16x8 b = *(const bf16x8*)(&KWs[d*256 + (kk ^ ((d&7)<<3))]);
      acc[dt] = __builtin_amdgcn_mfma_f32_16x16x32_bf16(a, b, acc[dt], 0,0,0);
    }
  }
  __builtin_amdgcn_s_setprio(0);
#pragma unroll
  for (int r=0;r<4;++r){
    int row = q0 + prow_base + r;
    us* op = OH + (size_t)row*DIM + h*DHD;
#pragma unroll
    for (int dt=0;dt<4;++dt)
      op[dt*16 + (lane&15)] = f2b(acc[dt][r]*rcp[r]);
  }
}

// ---------------- depthwise conv along seq, bf16 RMW ----------------
#define SCBLK 32
__global__ __launch_bounds__(256) void k_seqconv(const us* __restrict__ Vb,
    const float* __restrict__ resk, us* __restrict__ OH)
{
  __shared__ us Vs[64*512];
  int tid = threadIdx.x;
  int p0 = blockIdx.x*SCBLK;
  for (int i=tid; i<16384; i+=256){
    int pl = i>>8, c2 = i&255;
    int gp = p0 - 16 + pl;
    int hh = c2>>5, d2 = (c2&31)*2;
    ushort2 v = make_ushort2(0,0);
    if (gp>=0 && gp<NPAD) v = *(const ushort2*)(Vb + ((size_t)hh*NPAD+gp)*DHD + d2);
    *(ushort2*)(&Vs[pl*512 + c2*2]) = v;
  }
  __syncthreads();
  int h = tid>>5;
  float kr[33];
#pragma unroll
  for (int r=0;r<33;++r) kr[r] = resk[h*33+r];
  for (int pl=0; pl<SCBLK; ++pl){
    float s0=0.f, s1=0.f;
#pragma unroll
    for (int r=0;r<33;++r){
      ushort2 v = *(const ushort2*)(&Vs[(pl+r)*512 + tid*2]);
      s0 += bf2f(v.x)*kr[r];
      s1 += bf2f(v.y)*kr[r];
    }
    size_t o = (size_t)(p0+pl)*DIM + tid*2;
    ushort2 cur = *(ushort2*)(OH + o);
    *(ushort2*)(OH + o) = make_ushort2(f2b(bf2f(cur.x)+s0), f2b(bf2f(cur.y)+s1));
  }
}

// ---------------- leff (bf16 planes, bf16 X) ----------------
__global__ void k_tfwd(const us* __restrict__ X, us* __restrict__ T)
{
  __shared__ us tile[32][33];
  int tx = threadIdx.x & 31, ty = threadIdx.x >> 5;
  int s0 = blockIdx.x*32, c0 = blockIdx.y*32;
  for (int yy=0; yy<4; ++yy){
    int s = s0 + ty + yy*8;
    if (s < NTOK) tile[ty+yy*8][tx] = X[(size_t)(1+s)*DIM + c0+tx];
  }
  __syncthreads();
  for (int yy=0; yy<4; ++yy){
    int c = c0 + ty + yy*8;
    int s = s0 + tx;
    if (s < NTOK) T[(size_t)c*NTOK + s] = tile[tx][ty+yy*8];
  }
}
__global__ void k_tbwd(const us* __restrict__ T, us* __restrict__ X)
{
  __shared__ us tile[32][33];
  int tx = threadIdx.x & 31, ty = threadIdx.x >> 5;
  int s0 = blockIdx.x*32, c0 = blockIdx.y*32;
  for (int yy=0; yy<4; ++yy){
    int c = c0 + ty + yy*8, s = s0 + tx;
    if (s < NTOK) tile[ty+yy*8][tx] = T[(size_t)c*NTOK + s];
  }
  __syncthreads();
  for (int yy=0; yy<4; ++yy){
    int s = s0 + ty + yy*8, c = c0 + tx;
    if (s < NTOK) X[(size_t)(1+s)*DIM + c] = tile[tx][ty+yy*8];
  }
}
// scalar depthwise 7/5/3 conv (round-13 variant: high occupancy)
__global__ __launch_bounds__(256) void k_leff(const us* __restrict__ T,
    const float* __restrict__ k7, const float* __restrict__ b7,
    const float* __restrict__ k5, const float* __restrict__ b5,
    const float* __restrict__ k3, const float* __restrict__ b3,
    us* __restrict__ T2)
{
  __shared__ float tile[21*21];
  int c = blockIdx.y;
  int ti = blockIdx.x/10, tj = blockIdx.x%10;
  int i0 = ti*15-3, j0 = tj*15-3;
  const us* img = T + (size_t)c*NTOK;
  for (int idx=threadIdx.x; idx<441; idx+=256){
    int ii = idx/21, jj = idx%21;
    int gi = i0+ii, gj = j0+jj;
    tile[idx] = (gi>=0 && gi<HSZ && gj>=0 && gj<HSZ) ? bf2f(img[gi*HSZ+gj]) : 0.f;
  }
  __syncthreads();
  if (threadIdx.x < 225){
    int li = threadIdx.x/15, lj = threadIdx.x%15;
    int gi = ti*15+li, gj = tj*15+lj;
    float acc = tile[(li+3)*21 + (lj+3)] + b7[c]+b5[c]+b3[c];
    const float* w7 = k7 + c*49;
#pragma unroll
    for (int a=0;a<7;++a)
#pragma unroll
      for (int bb=0;bb<7;++bb) acc += tile[(li+a)*21 + (lj+bb)]*w7[a*7+bb];
    const float* w5 = k5 + c*25;
#pragma unroll
    for (int a=0;a<5;++a)
#pragma unroll
      for (int bb=0;bb<5;++bb) acc += tile[(li+1+a)*21 + (lj+1+bb)]*w5[a*5+bb];
    const float* w3 = k3 + c*9;
#pragma unroll
    for (int a=0;a<3;++a)
#pragma unroll
      for (int bb=0;bb<3;++bb) acc += tile[(li+2+a)*21 + (lj+2+bb)]*w3[a*3+bb];
    T2[(size_t)c*NTOK + gi*HSZ+gj] = f2b(acc);
  }
}

// ---------------- cls-row pieces ----------------
__global__ void k_row1(const float* __restrict__ Q0, const float* __restrict__ KL0,
                       float* __restrict__ row1)
{
  __shared__ float sb[4];
  __shared__ float qv[64];
  int t = threadIdx.x;
  if (t<64) qv[t] = Q0[PADR*DHD + t];
  __syncthreads();
  float l = 0.f;
#pragma unroll
  for (int d=0;d<64;++d) l += qv[d]*KL0[(size_t)t*DHD+d];
  float m = blockMax256(l, sb);
  float e = __expf(l-m);
  float s = blockSum256(e, sb);
  row1[t] = e/s;
}
__global__ void k_rz(const float* __restrict__ row1, const us* __restrict__ Zt,
                     float* __restrict__ rz)
{
  __shared__ float r1[256];
  int t = threadIdx.x;
  r1[t] = row1[t];
  __syncthreads();
  float s = 0.f;
  for (int k2=0;k2<256;++k2) s += r1[k2]*bf2f(Zt[(size_t)t*MM + k2]);
  rz[t] = s;
}
__global__ void k_rowstat(const float* __restrict__ L0, float* __restrict__ mx, float* __restrict__ se)
{
  __shared__ float sb[4];
  const float* row = L0 + (size_t)blockIdx.x*NPAD;
  float m = -1e30f;
  for (int i=threadIdx.x;i<NPAD;i+=256) m = fmaxf(m, row[i]);
  m = blockMax256(m, sb);
  float s = 0.f;
  for (int i=threadIdx.x;i<NPAD;i+=256) s += __expf(row[i]-m);
  s = blockSum256(s, sb);
  if (threadIdx.x==0){ mx[blockIdx.x]=m; se[blockIdx.x]=s; }
}
__global__ void k_aout(const float* __restrict__ L0, const float* __restrict__ rz,
    const float* __restrict__ mx, const float* __restrict__ se, float* __restrict__ out)
{
  __shared__ float wk[256], mk[256];
  int t = threadIdx.x;
  wk[t] = rz[t]/se[t];
  mk[t] = mx[t];
  __syncthreads();
  int p = blockIdx.x*256 + t;
  if (p >= NTOK) return;
  size_t pp = (size_t)(PADR+1+p);
  float a = 0.f;
  for (int k2=0;k2<256;++k2) a += wk[k2]*__expf(L0[(size_t)k2*NPAD+pp]-mk[k2]);
  out[4+p] = a;
}
__global__ void k_final(const us* __restrict__ H2r, const float* __restrict__ nw,
    const float* __restrict__ nbb, const float* __restrict__ w2, const float* __restrict__ b2,
    float* __restrict__ out)
{
  __shared__ float sb[4];
  __shared__ float hf[512];
  int t = threadIdx.x;
  float x0 = bf2f(H2r[t]), x1 = bf2f(H2r[256+t]);
  float s = blockSum256(x0+x1, sb);
  float q = blockSum256(x0*x0+x1*x1, sb);
  float mean = s*(1.f/512.f);
  float var = q*(1.f/512.f) - mean*mean;
  float rstd = rsqrtf(var+1e-5f);
  hf[t]     = (x0-mean)*rstd*nw[t]+nbb[t];
  hf[256+t] = (x1-mean)*rstd*nw[256+t]+nbb[256+t];
  __syncthreads();
  float p0 = hf[t]*w2[t*2]   + hf[256+t]*w2[(256+t)*2];
  float p1 = hf[t]*w2[t*2+1] + hf[256+t]*w2[(256+t)*2+1];
  p0 = blockSum256(p0, sb);
  p1 = blockSum256(p1, sb);
  if (t==0){
    float l0 = p0+b2[0], l1 = p1+b2[1];
    float m = fmaxf(l0,l1);
    float e0 = __expf(l0-m), e1 = __expf(l1-m), si = 1.f/(e0+e1);
    out[0]=l0; out[1]=l1; out[2]=e0*si; out[3]=e1*si;
  }
}

// ---------------- host orchestration ----------------
struct Bufs {
  float *A2,*sums,*scl,*Pmax,*Psum;
  us *Xb,*Yb,*OHb,*Qb,*Kb,*Vb,*Vtb,*QLb,*KLb,*A2b;
  us *Z0b,*Z0tb,*Z1b,*Z1tb,*XZb,*XZtb,*T1tb,*T2tb;
  us *A3Vtb,*WmT,*Pacc,*zpg;
};

static void run_pinv(const us* A2b, Bufs& b, int NB, int callidx, hipStream_t st)
{
  dim3 g(4,4,NB);
  unsigned* cnt = (unsigned*)(b.zpg + 256) + callidx;   // zpg bytes 512.. are zeroed, unused by gemm
  unsigned nb = 16u * (unsigned)NB;
  k_pinv<<<g,256,0,st>>>(A2b, b.Z0b, b.Z0tb, b.Z1b, b.Z1tb,
                         b.XZb, b.XZtb, b.T1tb, b.T2tb, cnt, nb);
  // 6 iterations = even number of swaps -> final Z in Z0b/Z0tb
}

static void nystrom_layer(Bufs& b, const float* lnw, const float* lnb,
    const us* wqkvT, const us* woutT,
    const float* bout, const float* resk, int callidx, hipStream_t st)
{
  k_ln<<<N1,256,0,st>>>(b.Xb, b.Yb, lnw, lnb);
  k_gemm<1><<<352*12,256,0,st>>>(b.Yb, wqkvT, nullptr,
      nullptr, nullptr, nullptr, b.Qb, b.Kb, b.Vb, b.zpg, DIM, 352);
  k_vT<<<dim3(NPAD/32,16),256,0,st>>>(b.Vb, b.Vtb);
  k_landmark2<<<2*NH*MM,64,0,st>>>(b.Qb, b.Kb, b.QLb, b.KLb);
  k_nt64b<<<dim3(4,4,NH),64,0,st>>>(b.QLb, b.KLb, b.A2,
      (long)MM*DHD,(long)MM*DHD,(long)MM*MM, MM);
  k_softmax256<<<NH*MM,256,0,st>>>(b.A2, b.A2b);
  k_csmax<<<NH,256,0,st>>>(b.A2, b.sums);
  k_scale2<<<1,256,0,st>>>(b.sums, b.scl, NH);
  k_z0t<<<dim3(8,8*NH),256,0,st>>>(b.A2, b.Z0b, b.Z0tb, b.scl);
  run_pinv(b.A2b, b, NH, callidx, st);
  k_attn3<<<dim3(NCH,NH),512,0,st>>>(b.QLb, b.Kb, b.Vtb, b.Pmax, b.Psum, b.Pacc);
  k_attn3_merge<<<NH*MM,64,0,st>>>(b.Pmax, b.Psum, b.Pacc, b.A3Vtb);
  k_pgemm2<<<dim3(1,4,NH),256,0,st>>>(b.Z0b, b.A3Vtb, b.WmT);
  k_attn1<<<dim3(NPAD/64,NH),256,0,st>>>(b.Qb, b.KLb, b.WmT, b.OHb);
  k_seqconv<<<NPAD/SCBLK,256,0,st>>>(b.Vb, resk, b.OHb);
  k_gemm<2><<<352*4,256,0,st>>>(b.OHb, woutT, bout,
      b.Xb, nullptr, nullptr, nullptr, nullptr, nullptr, b.zpg, DIM, 352);
}

extern "C" void kernel_launch(void* const* d_in, const int* in_sizes, int n_in,
                              void* d_out, int out_size, void* d_ws, size_t ws_size,
                              hipStream_t stream)
{
  (void)n_in; (void)out_size;
  bool sig_order = (in_sizes[10] == 25088);
  int iL2 = sig_order ? 16 : 10;
  int iLf = sig_order ? 10 : 16;

  const float* h       = (const float*)d_in[0];
  const float* fc1_w   = (const float*)d_in[1];
  const float* fc1_b   = (const float*)d_in[2];
  const float* cls_tok = (const float*)d_in[3];
  const float* l1_lnw  = (const float*)d_in[4];
  const float* l1_lnb  = (const float*)d_in[5];
  const float* l1_wqkv = (const float*)d_in[6];
  const float* l1_wout = (const float*)d_in[7];
  const float* l1_bout = (const float*)d_in[8];
  const float* l1_resk = (const float*)d_in[9];
  const float* l2_lnw  = (const float*)d_in[iL2+0];
  const float* l2_lnb  = (const float*)d_in[iL2+1];
  const float* l2_wqkv = (const float*)d_in[iL2+2];
  const float* l2_wout = (const float*)d_in[iL2+3];
  const float* l2_bout = (const float*)d_in[iL2+4];
  const float* l2_resk = (const float*)d_in[iL2+5];
  const float* k7 = (const float*)d_in[iLf+0];
  const float* b7 = (const float*)d_in[iLf+1];
  const float* k5 = (const float*)d_in[iLf+2];
  const float* b5 = (const float*)d_in[iLf+3];
  const float* k3 = (const float*)d_in[iLf+4];
  const float* b3 = (const float*)d_in[iLf+5];
  const float* nw = (const float*)d_in[22];
  const float* nbb= (const float*)d_in[23];
  const float* w2 = (const float*)d_in[24];
  const float* b2 = (const float*)d_in[25];
  float* out = (float*)d_out;

  char* base = (char*)d_ws;
  auto allocF = [&](size_t n)->float*{
    float* p=(float*)base; base += ((n*sizeof(float)+255)&~(size_t)255); return p; };
  auto allocU = [&](size_t n)->us*{
    us* p=(us*)base; base += ((n*sizeof(us)+255)&~(size_t)255); return p; };

  const size_t S = (size_t)NPAD*DIM;
  const size_t SQ = (size_t)MM*MM;
  Bufs b;
  b.Xb  = allocU(S);
  b.Yb  = allocU(S);
  b.OHb = allocU(S);
  b.Qb  = allocU(S);
  b.Kb  = allocU(S);
  b.Vb  = allocU(S);
  b.Vtb = allocU(S);
  b.QLb = allocU((size_t)NH*MM*DHD);
  b.KLb = allocU((size_t)NH*MM*DHD);
  b.A2  = allocF((size_t)NH*SQ);
  b.A2b = allocU((size_t)NH*SQ);
  b.Z0b = allocU((size_t)NH*SQ);  b.Z0tb = allocU((size_t)NH*SQ);
  b.Z1b = allocU((size_t)NH*SQ);  b.Z1tb = allocU((size_t)NH*SQ);
  b.XZb = allocU((size_t)NH*SQ);  b.XZtb = allocU((size_t)NH*SQ);
  b.T1tb= allocU((size_t)NH*SQ);
  b.T2tb= allocU((size_t)NH*SQ);
  b.A3Vtb = allocU((size_t)NH*MM*DHD);
  b.WmT   = allocU((size_t)NH*MM*DHD);
  b.sums  = allocF(2*(size_t)NH*MM);
  b.scl   = allocF(16);
  b.Pmax  = allocF((size_t)NH*NCH*MM);
  b.Psum  = allocF((size_t)NH*NCH*MM);
  b.Pacc  = allocU((size_t)NH*NCH*MM*DHD);
  b.zpg   = allocU(512);
  us* hb     = allocU((size_t)NTOK*1024);
  us* fc1T   = allocU((size_t)DIM*1024);
  us* wqkvT1 = allocU((size_t)1536*DIM);
  us* wqkvT2 = allocU((size_t)1536*DIM);
  us* woutT1 = allocU((size_t)DIM*DIM);
  us* woutT2 = allocU((size_t)DIM*DIM);
  float* Q0   = allocF((size_t)NPAD*DHD);
  float* K0   = allocF((size_t)NPAD*DHD);
  float* QL0f = allocF((size_t)MM*DHD);
  float* KL0f = allocF((size_t)MM*DHD);
  float* row1 = allocF(256);
  float* rzv  = allocF(256);
  float* mxv  = allocF(256);
  float* sev  = allocF(256);
  us* h2row = allocU(512);
  if ((size_t)(base - (char*)d_ws) > ws_size) return;

  hipMemsetAsync((void*)b.zpg, 0, 1024, stream);

  // input + weight conversions (fp32 -> bf16)
  k_cvt<<<((size_t)NTOK*1024/4 + 255)/256,256,0,stream>>>(h, hb, (size_t)NTOK*1024/4);
  k_wT<<<dim3(32,16),256,0,stream>>>(fc1_w, fc1T, 1024, DIM);
  k_wT<<<dim3(16,48),256,0,stream>>>(l1_wqkv, wqkvT1, DIM, 1536);
  k_wT<<<dim3(16,48),256,0,stream>>>(l2_wqkv, wqkvT2, DIM, 1536);
  k_wT<<<dim3(16,16),256,0,stream>>>(l1_wout, woutT1, DIM, DIM);
  k_wT<<<dim3(16,16),256,0,stream>>>(l2_wout, woutT2, DIM, DIM);

  // stage 0: fc1 + cls token
  k_gemm<0><<<352*4,256,0,stream>>>(hb, fc1T, fc1_b,
      b.Xb, nullptr, nullptr, nullptr, nullptr, nullptr, b.zpg, 1024, 352);
  k_setcls<<<2,256,0,stream>>>(b.Xb, cls_tok);

  // layer 1 + LeFF
  nystrom_layer(b, l1_lnw, l1_lnb, wqkvT1, woutT1, l1_bout, l1_resk, 0, stream);
  k_tfwd<<<dim3(704,16),256,0,stream>>>(b.Xb, b.OHb);
  k_leff<<<dim3(100,512),256,0,stream>>>(b.OHb, k7,b7,k5,b5,k3,b3, b.Qb);
  k_tbwd<<<dim3(704,16),256,0,stream>>>(b.Qb, b.Xb);

  // layer 2 (save h2 row 0)
  nystrom_layer(b, l2_lnw, l2_lnb, wqkvT2, woutT2, l2_bout, l2_resk, 1, stream);
  k_copyu<<<2,256,0,stream>>>(h2row, b.Xb, 512);

  // layer 3 -> h3
  nystrom_layer(b, l2_lnw, l2_lnb, wqkvT2, woutT2, l2_bout, l2_resk, 2, stream);

  // cls-row stage (head 0, l2 weights, LN(h3))
  k_ln<<<N1,256,0,stream>>>(b.Xb, b.Yb, l2_lnw, l2_lnb);
  k_gemm<3><<<352,256,0,stream>>>(b.Yb, wqkvT2, nullptr,
      nullptr, Q0, K0, nullptr, nullptr, nullptr, b.zpg, DIM, 352);
  k_landmark2f<<<2*MM,64,0,stream>>>(Q0, K0, QL0f, KL0f);
  k_nt64<<<dim3(4,4,1),64,0,stream>>>(QL0f, KL0f, b.A2, 0,0,0, MM);
  k_softmax256<<<MM,256,0,stream>>>(b.A2, b.A2b);
  k_csmax<<<1,256,0,stream>>>(b.A2, b.sums);
  k_scale2<<<1,256,0,stream>>>(b.sums, b.scl, 1);
  k_z0t<<<dim3(8,8),256,0,stream>>>(b.A2, b.Z0b, b.Z0tb, b.scl);
  run_pinv(b.A2b, b, 1, 3, stream);
  k_row1<<<1,256,0,stream>>>(Q0, KL0f, row1);
  k_rz<<<1,256,0,stream>>>(row1, b.Z0tb, rzv);
  // L0 = QL0 @ K0^T (256 x NPAD), into Yb's storage (NPAD*256 floats)
  float* L0 = (float*)b.Yb;
  k_nt64<<<dim3(NPAD/64,4,1),64,0,stream>>>(QL0f, K0, L0, 0,0,0, NPAD);
  k_rowstat<<<MM,256,0,stream>>>(L0, mxv, sev);
  k_aout<<<88,256,0,stream>>>(L0, rzv, mxv, sev, out);
  k_final<<<1,256,0,stream>>>(h2row, nw, nbb, w2, b2, out);
}

// Round 19
// 2244.990 us; speedup vs baseline: 1.5497x; 1.2765x over previous
//
#include <hip/hip_runtime.h>

#define NTOK 22500
#define N1   22501
#define NPAD 22528
#define PADR 27
#define DIM  512
#define NH   8
#define DHD  64
#define MM   256
#define LLM  88
#define HSZ  150
#define CSZ  256
#define NCH  88   // NPAD / CSZ

typedef short bf16x8 __attribute__((ext_vector_type(8)));
typedef float f32x4  __attribute__((ext_vector_type(4)));
typedef unsigned short us;

union U8 { bf16x8 v; unsigned short u[8]; };

__device__ __forceinline__ unsigned short f2b(float f){
  unsigned int u = __float_as_uint(f);
  unsigned int r = u + 0x7fffu + ((u>>16)&1u);
  return (unsigned short)(r>>16);
}
__device__ __forceinline__ float bf2f(unsigned short u){
  return __uint_as_float(((unsigned int)u)<<16);
}
__device__ __forceinline__ bf16x8 cvt8(float4 a, float4 b){
  U8 u;
  u.u[0]=f2b(a.x); u.u[1]=f2b(a.y); u.u[2]=f2b(a.z); u.u[3]=f2b(a.w);
  u.u[4]=f2b(b.x); u.u[5]=f2b(b.y); u.u[6]=f2b(b.z); u.u[7]=f2b(b.w);
  return u.v;
}
// async global->LDS, 16B per lane; lds dest = wave-uniform base + lane*16
__device__ __forceinline__ void gld16(const void* g, void* l){
  __builtin_amdgcn_global_load_lds(
      (const __attribute__((address_space(1))) void*)g,
      (__attribute__((address_space(3))) void*)l, 16, 0, 0);
}

// ---------------- reduction helpers ----------------
__device__ __forceinline__ float waveSum(float v){
#pragma unroll
  for (int o=32;o>0;o>>=1) v += __shfl_down(v,o);
  return v;
}
__device__ __forceinline__ float waveMax(float v){
#pragma unroll
  for (int o=32;o>0;o>>=1) v = fmaxf(v,__shfl_down(v,o));
  return v;
}
__device__ __forceinline__ float blockSum256(float v, float* sb){
  v = waveSum(v);
  __syncthreads();
  if ((threadIdx.x&63)==0) sb[threadIdx.x>>6]=v;
  __syncthreads();
  return sb[0]+sb[1]+sb[2]+sb[3];
}
__device__ __forceinline__ float blockMax256(float v, float* sb){
  v = waveMax(v);
  __syncthreads();
  if ((threadIdx.x&63)==0) sb[threadIdx.x>>6]=v;
  __syncthreads();
  return fmaxf(fmaxf(sb[0],sb[1]),fmaxf(sb[2],sb[3]));
}

// ---------------- fp32 -> bf16 convert ----------------
__global__ void k_cvt(const float* __restrict__ src, us* __restrict__ dst, size_t n4)
{
  size_t i = ((size_t)blockIdx.x*256 + threadIdx.x);
  if (i < n4){
    float4 v = *(const float4*)(src + i*4);
    ushort4 u; u.x=f2b(v.x); u.y=f2b(v.y); u.z=f2b(v.z); u.w=f2b(v.w);
    *(ushort4*)(dst + i*4) = u;
  }
}

// ---------------- weight transpose+cvt: W fp32 [K][N] -> Bt bf16 [N][K] ----------------
__global__ void k_wT(const float* __restrict__ W, us* __restrict__ Bt, int K, int N)
{
  __shared__ float tile[32][33];
  int tx = threadIdx.x&31, ty = threadIdx.x>>5;
  int k0 = blockIdx.x*32, n0 = blockIdx.y*32;
#pragma unroll
  for (int i=0;i<4;++i){
    int k = k0+ty+i*8;
    if (k<K && n0+tx<N) tile[ty+i*8][tx] = W[(size_t)k*N + n0+tx];
  }
  __syncthreads();
#pragma unroll
  for (int i=0;i<4;++i){
    int n = n0+ty+i*8, k = k0+tx;
    if (n<N && k<K) Bt[(size_t)n*K + k] = f2b(tile[tx][ty+i*8]);
  }
}

// ---------------- V transpose: Vb [h][p][d] -> Vtb [h][d][p] ----------------
__global__ void k_vT(const us* __restrict__ V, us* __restrict__ Vt)
{
  __shared__ us tile[32][33];
  int tx = threadIdx.x&31, ty = threadIdx.x>>5;
  int p0 = blockIdx.x*32;
  int h = blockIdx.y>>1, d0 = (blockIdx.y&1)*32;
#pragma unroll
  for (int i=0;i<4;++i){
    int p = p0+ty+i*8;
    tile[ty+i*8][tx] = V[((size_t)h*NPAD+p)*DHD + d0+tx];
  }
  __syncthreads();
#pragma unroll
  for (int i=0;i<4;++i){
    int d = d0+ty+i*8;
    Vt[((size_t)h*DHD+d)*NPAD + p0+tx] = tile[tx][ty+i*8];
  }
}

// ---------------- MFMA GEMM (64x128 tile), 3-buffer counted-vmcnt pipeline ----------------
// MODE 0: fc1 (A=hb bf16 -> X bf16 relu)   MODE 1: qkv (A=Yb bf16 -> Qb/Kb/Vb)
// MODE 2: wout (A=OHb bf16, X bf16 +=)     MODE 3: qk0 (A=Yb bf16 -> Q0/K0 fp32)
template<int MODE>
__global__ __launch_bounds__(256) void k_gemm(
    const us* __restrict__ Ab, const us* __restrict__ Bt, const float* __restrict__ bias,
    us* __restrict__ Xb, float* __restrict__ Cf, float* __restrict__ C2,
    us* __restrict__ Q_, us* __restrict__ K_, us* __restrict__ V_,
    const us* __restrict__ zpg, int Kd, int mtn)
{
  constexpr int BM = 64;
  constexpr int BUFE = BM*64 + 128*64;    // 12288 us per buffer
  __shared__ us SM[3*BUFE];               // 72 KB
  const int tid = threadIdx.x;
  const int bid = blockIdx.x;
  const int ntile = bid / mtn;            // m-fastest: consecutive blocks share B panel
  const int m0 = (bid % mtn)*BM, n0 = ntile*128;
  const int lane = tid & 63;
  const int wid = tid >> 6;
  const int wm = (wid>>1)*32, wn = (wid&1)*64;
  f32x4 acc[2][4] = {};
  const int NT = Kd >> 6;

  auto stage = [&](int t, int buf){
    us* As = SM + buf*BUFE;
    us* Bs = As + BM*64;
    int k0 = t*64;
#pragma unroll
    for (int i=0;i<2;++i){
      int c = wid*2+i;
      int row = c*8 + (lane>>3);
      int scol8 = ((lane&7) ^ (row&7))*8;
      int gm = m0+row;
      const us* ga;
      if (MODE==0)      ga = (gm<NTOK) ? Ab + (size_t)gm*Kd + k0 + scol8 : zpg + scol8;
      else if (MODE==2) ga = Ab + ((size_t)((gm<N1?gm:0)+PADR))*Kd + k0 + scol8;
      else              ga = (gm>=PADR) ? Ab + (size_t)(gm-PADR)*Kd + k0 + scol8 : zpg + scol8;
      gld16(ga, &As[c*512]);
    }
#pragma unroll
    for (int i=0;i<4;++i){
      int c = wid*4+i;
      int row = c*8 + (lane>>3);
      int scol8 = ((lane&7) ^ (row&7))*8;
      int vn = n0+row;
      if (MODE==3) vn = (vn<64)? vn : vn+448;
      gld16(Bt + (size_t)vn*Kd + k0 + scol8, &Bs[c*512]);
    }
  };

  stage(0, 0);
  stage(1, 1);
  for (int t=0; t<NT; ++t){
    asm volatile("s_waitcnt vmcnt(6)" ::: "memory");   // oldest stage (t) landed in LDS
    __builtin_amdgcn_s_barrier();                      // raw barrier: NO vmcnt drain
    asm volatile("" ::: "memory");
    if (t+2 < NT) stage(t+2, (t+2)%3);                 // buf (t+2)%3: last read at iter t-1
    us* As = SM + (t%3)*BUFE;
    us* Bs = As + BM*64;
#pragma unroll
    for (int ks=0; ks<2; ++ks){
      const int kk = ks*32 + (lane>>4)*8;
      bf16x8 af[2], bfm[4];
#pragma unroll
      for (int tt=0;tt<2;++tt){
        int r = wm + tt*16 + (lane&15);
        af[tt] = *(bf16x8*)(&As[r*64 + (kk ^ ((r&7)<<3))]);
      }
#pragma unroll
      for (int tt=0;tt<4;++tt){
        int c = wn + tt*16 + (lane&15);
        bfm[tt] = *(bf16x8*)(&Bs[c*64 + (kk ^ ((c&7)<<3))]);
      }
#pragma unroll
      for (int mt=0;mt<2;++mt)
#pragma unroll
        for (int nt=0;nt<4;++nt)
          acc[mt][nt] = __builtin_amdgcn_mfma_f32_16x16x32_bf16(af[mt], bfm[nt], acc[mt][nt], 0,0,0);
    }
  }
  __syncthreads();
  const int rbase = (lane>>4)*4;
  const int cl = lane&15;
  if (MODE==3){
#pragma unroll
    for (int mt=0;mt<2;++mt)
#pragma unroll
      for (int r=0;r<4;++r){
        int gm = m0 + wm + mt*16 + rbase + r;
#pragma unroll
        for (int nt=0;nt<4;++nt){
          int gn = n0 + wn + nt*16 + cl;
          float v = acc[mt][nt][r];
          if (gn < 64) Cf[(size_t)gm*DHD + gn] = v*0.125f;
          else         C2[(size_t)gm*DHD + (gn-64)] = v;
        }
      }
    return;
  }
  // LDS relayout epilogues (coalesced 16B bf16 stores)
  const float sc1 = (MODE==1 && (ntile>>2)==0) ? 0.125f : 1.f;
#pragma unroll
  for (int mt=0;mt<2;++mt)
#pragma unroll
    for (int r=0;r<4;++r){
      int row = wm + mt*16 + rbase + r;
#pragma unroll
      for (int nt=0;nt<4;++nt){
        int col = wn + nt*16 + cl;
        float v = acc[mt][nt][r];
        if (MODE==0){ v += bias[n0+col]; v = v>0.f?v:0.f; }
        else if (MODE==2){ v += bias[n0+col]; }
        else v *= sc1;
        SM[row*128 + col] = f2b(v);
      }
    }
  __syncthreads();
  if (MODE==1){
    const int sec = ntile>>2;
    us* dst = sec==0 ? Q_ : (sec==1 ? K_ : V_);
#pragma unroll
    for (int i=0;i<4;++i){
      int v8 = i*256 + tid;
      int row = v8>>4, c8 = (v8&15)*8;
      int gm = m0 + row, gn = n0 + c8;
      int hh = (gn>>6)&7, d = gn&63;
      *(bf16x8*)(dst + ((size_t)hh*NPAD+gm)*DHD + d) = *(bf16x8*)(&SM[row*128 + c8]);
    }
  } else if (MODE==0){
#pragma unroll
    for (int i=0;i<4;++i){
      int v8 = i*256 + tid;
      int row = v8>>4, c8 = (v8&15)*8;
      int gm = m0 + row;
      if (gm < NTOK)
        *(bf16x8*)(Xb + (size_t)(1+gm)*DIM + n0 + c8) = *(bf16x8*)(&SM[row*128 + c8]);
    }
  } else {  // MODE 2: bf16 RMW on X
#pragma unroll
    for (int i=0;i<4;++i){
      int v8 = i*256 + tid;
      int row = v8>>4, c8 = (v8&15)*8;
      int gm = m0 + row;
      if (gm < N1){
        us* p = Xb + (size_t)gm*DIM + n0 + c8;
        U8 xo, ad, o;
        xo.v = *(bf16x8*)p;
        ad.v = *(bf16x8*)(&SM[row*128 + c8]);
#pragma unroll
        for (int j=0;j<8;++j) o.u[j] = f2b(bf2f(xo.u[j]) + bf2f(ad.u[j]));
        *(bf16x8*)p = o.v;
      }
    }
  }
}

__global__ void k_setcls(us* __restrict__ X, const float* __restrict__ cls){
  int i = blockIdx.x*256 + threadIdx.x;
  if (i < DIM) X[i] = f2b(cls[i]);
}
__global__ void k_copyu(us* __restrict__ d, const us* __restrict__ s, size_t n){
  size_t i = (size_t)blockIdx.x*256 + threadIdx.x;
  if (i<n) d[i]=s[i];
}

// ---------------- layernorm: bf16 in -> bf16 out ----------------
__global__ void k_ln(const us* __restrict__ X, us* __restrict__ Y,
                     const float* __restrict__ w, const float* __restrict__ b)
{
  __shared__ float sb[4];
  const us* x = X + (size_t)blockIdx.x*DIM;
  us* y = Y + (size_t)blockIdx.x*DIM;
  int t = threadIdx.x;
  ushort2 xv = *(const ushort2*)(x + 2*t);
  float a0=bf2f(xv.x), a1=bf2f(xv.y);
  float s = blockSum256(a0+a1, sb);
  float q = blockSum256(a0*a0+a1*a1, sb);
  float mean = s*(1.f/512.f);
  float var = q*(1.f/512.f) - mean*mean;
  float rstd = rsqrtf(var+1e-5f);
  float2 wv = *(const float2*)(w + 2*t);
  float2 bv = *(const float2*)(b + 2*t);
  ushort2 o;
  o.x = f2b((a0-mean)*rstd*wv.x+bv.x);
  o.y = f2b((a1-mean)*rstd*wv.y+bv.y);
  *(ushort2*)(y + 2*t) = o;
}

// ---------------- landmarks (fused Q+K) ----------------
__global__ void k_landmark2(const us* __restrict__ Q, const us* __restrict__ K,
                            us* __restrict__ QL, us* __restrict__ KL)
{
  int hm = blockIdx.x;
  bool isK = hm >= NH*MM;
  if (isK) hm -= NH*MM;
  int h = hm>>8, m = hm&255; int d = threadIdx.x;
  const us* base = (isK?K:Q) + ((size_t)h*NPAD + (size_t)m*LLM)*DHD + d;
  float s = 0.f;
  for (int j=0;j<LLM;++j) s += bf2f(base[(size_t)j*DHD]);
  (isK?KL:QL)[((size_t)h*MM + m)*DHD + d] = f2b(s * (1.f/(float)LLM));
}
__global__ void k_landmark2f(const float* __restrict__ Q, const float* __restrict__ K,
                             float* __restrict__ QL, float* __restrict__ KL)
{
  int hm = blockIdx.x;
  bool isK = hm >= MM;
  int m = isK ? hm-MM : hm; int d = threadIdx.x;
  const float* base = (isK?K:Q) + (size_t)m*LLM*DHD + d;
  float s = 0.f;
  for (int j=0;j<LLM;++j) s += base[(size_t)j*DHD];
  (isK?KL:QL)[(size_t)m*DHD + d] = s * (1.f/(float)LLM);
}

// ---------------- MFMA NT gemm K=64, fp32 inputs ----------------
__global__ __launch_bounds__(64) void k_nt64(const float* __restrict__ A,
    const float* __restrict__ B, float* __restrict__ C,
    long sA, long sB, long sC, int Nr)
{
  int lane = threadIdx.x;
  int n0 = blockIdx.x*64, m0 = blockIdx.y*64;
  A += (size_t)blockIdx.z*sA; B += (size_t)blockIdx.z*sB; C += (size_t)blockIdx.z*sC;
  f32x4 acc[4][4] = {};
#pragma unroll
  for (int ks=0;ks<2;++ks){
    int kk = ks*32 + (lane>>4)*8;
    bf16x8 af[4], bfr[4];
#pragma unroll
    for (int mt=0;mt<4;++mt){
      const float* p = A + (size_t)(m0+mt*16+(lane&15))*64 + kk;
      af[mt] = cvt8(*(const float4*)p, *(const float4*)(p+4));
    }
#pragma unroll
    for (int nt=0;nt<4;++nt){
      const float* p = B + (size_t)(n0+nt*16+(lane&15))*64 + kk;
      bfr[nt] = cvt8(*(const float4*)p, *(const float4*)(p+4));
    }
#pragma unroll
    for (int mt=0;mt<4;++mt)
#pragma unroll
      for (int nt=0;nt<4;++nt)
        acc[mt][nt] = __builtin_amdgcn_mfma_f32_16x16x32_bf16(af[mt], bfr[nt], acc[mt][nt], 0,0,0);
  }
#pragma unroll
  for (int mt=0;mt<4;++mt)
#pragma unroll
    for (int r=0;r<4;++r){
      int row = m0+mt*16+(lane>>4)*4+r;
#pragma unroll
      for (int nt=0;nt<4;++nt){
        int col = n0+nt*16+(lane&15);
        C[(size_t)row*Nr + col] = acc[mt][nt][r];
      }
    }
}

// ---------------- MFMA NT gemm K=64, bf16 inputs (attn2 logits) ----------------
__global__ __launch_bounds__(64) void k_nt64b(const us* __restrict__ A,
    const us* __restrict__ B, float* __restrict__ C,
    long sA, long sB, long sC, int Nr)
{
  int lane = threadIdx.x;
  int n0 = blockIdx.x*64, m0 = blockIdx.y*64;
  A += (size_t)blockIdx.z*sA; B += (size_t)blockIdx.z*sB; C += (size_t)blockIdx.z*sC;
  f32x4 acc[4][4] = {};
#pragma unroll
  for (int ks=0;ks<2;++ks){
    int kk = ks*32 + (lane>>4)*8;
    bf16x8 af[4], bfr[4];
#pragma unroll
    for (int mt=0;mt<4;++mt)
      af[mt] = *(const bf16x8*)(A + (size_t)(m0+mt*16+(lane&15))*64 + kk);
#pragma unroll
    for (int nt=0;nt<4;++nt)
      bfr[nt] = *(const bf16x8*)(B + (size_t)(n0+nt*16+(lane&15))*64 + kk);
#pragma unroll
    for (int mt=0;mt<4;++mt)
#pragma unroll
      for (int nt=0;nt<4;++nt)
        acc[mt][nt] = __builtin_amdgcn_mfma_f32_16x16x32_bf16(af[mt], bfr[nt], acc[mt][nt], 0,0,0);
  }
#pragma unroll
  for (int mt=0;mt<4;++mt)
#pragma unroll
    for (int r=0;r<4;++r){
      int row = m0+mt*16+(lane>>4)*4+r;
#pragma unroll
      for (int nt=0;nt<4;++nt){
        int col = n0+nt*16+(lane&15);
        C[(size_t)row*Nr + col] = acc[mt][nt][r];
      }
    }
}

// ---------------- pinv MFMA gemm (dispatched, all-bf16, 64x64 tile, coalesced epilogue) ----------------
// PM 0: C=A@B (write C+Ct)   PM 1: C=alpha*(dc*A - A@B) (write Ct, C if writeC)
template<int PM>
__global__ __launch_bounds__(256) void k_pgemm(const us* __restrict__ A,
    const us* __restrict__ Bt, us* __restrict__ C, us* __restrict__ Ct,
    float dc, float alpha, int writeC)
{
  __shared__ us As[64*256];
  __shared__ us Bs[64*256];
  const int tid = threadIdx.x, lane = tid&63, wid = tid>>6;
  const int n0 = blockIdx.x*64, m0 = blockIdx.y*64;
  const us* Ab = A + (size_t)blockIdx.z*65536;
  const us* Bb = Bt + (size_t)blockIdx.z*65536;
  for (int i=tid; i<4096; i+=256){
    int r = i>>6, c4 = (i&63)*4;
    *(ushort4*)(&As[r*256 + (c4 ^ ((r&7)<<3))]) = *(const ushort4*)(Ab + (size_t)(m0+r)*256 + c4);
    *(ushort4*)(&Bs[r*256 + (c4 ^ ((r&7)<<3))]) = *(const ushort4*)(Bb + (size_t)(n0+r)*256 + c4);
  }
  __syncthreads();
  const int wm = (wid>>1)*32, wn = (wid&1)*32;
  f32x4 acc[2][2] = {};
#pragma unroll
  for (int ks=0;ks<8;++ks){
    int kk = ks*32 + (lane>>4)*8;
    bf16x8 af[2], bfr[2];
#pragma unroll
    for (int t=0;t<2;++t){
      int rr = wm + t*16 + (lane&15);
      af[t] = *(const bf16x8*)(&As[rr*256 + (kk ^ ((rr&7)<<3))]);
      int cc = wn + t*16 + (lane&15);
      bfr[t] = *(const bf16x8*)(&Bs[cc*256 + (kk ^ ((cc&7)<<3))]);
    }
#pragma unroll
    for (int mt=0;mt<2;++mt)
#pragma unroll
      for (int nt=0;nt<2;++nt)
        acc[mt][nt] = __builtin_amdgcn_mfma_f32_16x16x32_bf16(af[mt], bfr[nt], acc[mt][nt], 0,0,0);
  }
  // fold PM1 diag term (A read from LDS), keep in regs
  float vv[2][4][2];
#pragma unroll
  for (int mt=0;mt<2;++mt)
#pragma unroll
    for (int q=0;q<4;++q){
      int rl = wm + mt*16 + (lane>>4)*4 + q;
#pragma unroll
      for (int nt=0;nt<2;++nt){
        int clx = wn + nt*16 + (lane&15);
        float v = acc[mt][nt][q];
        if (PM==1) v = alpha*(dc*bf2f(As[rl*256 + (clx ^ ((rl&7)<<3))]) - v);
        vv[mt][q][nt] = v;
      }
    }
  __syncthreads();
  // write 64x64 tile into LDS (swizzled), reuse As
  us* TT = As;
#pragma unroll
  for (int mt=0;mt<2;++mt)
#pragma unroll
    for (int q=0;q<4;++q){
      int rl = wm + mt*16 + (lane>>4)*4 + q;
      int sw = (rl&7)<<3;
#pragma unroll
      for (int nt=0;nt<2;++nt){
        int clx = wn + nt*16 + (lane&15);
        TT[rl*64 + (clx ^ sw)] = f2b(vv[mt][q][nt]);
      }
    }
  __syncthreads();
  // coalesced transposed store
  {
    int c = tid>>2, r0 = (tid&3)*16;
    U8 b0, b1;
#pragma unroll
    for (int i=0;i<8;++i){
      int r = r0+i;       b0.u[i] = TT[r*64 + (c ^ ((r&7)<<3))];
      int r2 = r0+8+i;    b1.u[i] = TT[r2*64 + (c ^ ((r2&7)<<3))];
    }
    us* dst = Ct + (size_t)blockIdx.z*65536 + (size_t)(n0+c)*256 + m0 + r0;
    *(bf16x8*)dst = b0.v;
    *(bf16x8*)(dst+8) = b1.v;
  }
  if (PM==0 || writeC){
    int rr = tid>>2, c0 = (tid&3)*16;
    int sw = (rr&7)<<3;
    bf16x8 x0 = *(const bf16x8*)(&TT[rr*64 + (c0 ^ sw)]);
    bf16x8 x1 = *(const bf16x8*)(&TT[rr*64 + ((c0+8) ^ sw)]);
    us* dc2 = C + (size_t)blockIdx.z*65536 + (size_t)(m0+rr)*256 + n0 + c0;
    *(bf16x8*)dc2 = x0;
    *(bf16x8*)(dc2+8) = x1;
  }
}

// ---------------- WmT gemm (dispatch) ----------------
__global__ __launch_bounds__(256) void k_pgemm2(const us* __restrict__ A,
    const us* __restrict__ Bt, us* __restrict__ Ct)
{
  __shared__ us As[16384];
  __shared__ us Bs[16384];
  const int tid = threadIdx.x, lane = tid&63, wid = tid>>6;
  const int n0 = 0, m0 = blockIdx.y*64;
  const us* Ab = A + (size_t)blockIdx.z*65536;
  const us* Bb = Bt + (size_t)blockIdx.z*16384;
  for (int i=tid; i<4096; i+=256){
    int r = i>>6, c4 = (i&63)*4;
    *(ushort4*)(&As[r*256 + (c4 ^ ((r&7)<<3))]) = *(const ushort4*)(Ab + (size_t)(m0+r)*256 + c4);
    if (r < 64)
      *(ushort4*)(&Bs[r*256 + (c4 ^ ((r&7)<<3))]) = *(const ushort4*)(Bb + (size_t)(n0+r)*256 + c4);
  }
  __syncthreads();
  const int wm = (wid>>1)*32, wn = (wid&1)*32;
  f32x4 acc[2][2] = {};
#pragma unroll
  for (int ks=0;ks<8;++ks){
    int kk = ks*32 + (lane>>4)*8;
    bf16x8 af[2], bfr[2];
#pragma unroll
    for (int t=0;t<2;++t){
      int rr = wm + t*16 + (lane&15);
      af[t] = *(const bf16x8*)(&As[rr*256 + (kk ^ ((rr&7)<<3))]);
      int cc = wn + t*16 + (lane&15);
      bfr[t] = *(const bf16x8*)(&Bs[cc*256 + (kk ^ ((cc&7)<<3))]);
    }
#pragma unroll
    for (int mt=0;mt<2;++mt)
#pragma unroll
      for (int nt=0;nt<2;++nt)
        acc[mt][nt] = __builtin_amdgcn_mfma_f32_16x16x32_bf16(af[mt], bfr[nt], acc[mt][nt], 0,0,0);
  }
#pragma unroll
  for (int mt=0;mt<2;++mt)
#pragma unroll
    for (int r=0;r<4;++r){
      int row = m0 + wm + mt*16 + (lane>>4)*4 + r;
#pragma unroll
      for (int nt=0;nt<2;++nt){
        int col = n0 + wn + nt*16 + (lane&15);
        Ct[(size_t)blockIdx.z*16384 + (size_t)col*256 + row] = f2b(acc[mt][nt][r]);
      }
    }
}

// ---------------- small elementwise ----------------
__global__ void k_softmax256(float* __restrict__ S, us* __restrict__ Sb)
{
  __shared__ float sb[4];
  float* row = S + ((size_t)blockIdx.x<<8);
  float x = row[threadIdx.x];
  float m = blockMax256(x, sb);
  float e = __expf(x-m);
  float s = blockSum256(e, sb);
  float p = e/s;
  row[threadIdx.x] = p;
  Sb[((size_t)blockIdx.x<<8) + threadIdx.x] = f2b(p);
}
// col-sum max per head, then device atomic-max into mslot (positive floats: uint order == float order)
__global__ void k_csmax(const float* __restrict__ A2, unsigned* __restrict__ mslot)
{
  __shared__ float sb[4];
  int b = blockIdx.x, j = threadIdx.x;
  const float* Ab = A2 + ((size_t)b<<16);
  float s = 0.f;
  for (int i=0;i<256;++i) s += Ab[((size_t)i<<8)+j];
  float m = blockMax256(s, sb);
  if (j==0) atomicMax(mslot, __float_as_uint(m));
}
// tiled Z0: Zt = A2*s (row-major), Z = A2^T*s, both coalesced via LDS 32x32
__global__ void k_z0t(const float* __restrict__ A2, us* __restrict__ Z, us* __restrict__ Zt,
                      const unsigned* __restrict__ mslot)
{
  __shared__ us tile[32][33];
  int tx = threadIdx.x&31, ty = threadIdx.x>>5;
  int i0 = blockIdx.x*32;
  int head = blockIdx.y>>3, j0 = (blockIdx.y&7)*32;
  float s = 1.f/__uint_as_float(mslot[0]);
  const float* Ab = A2 + (size_t)head*65536;
  us* Zh  = Z  + (size_t)head*65536;
  us* Zth = Zt + (size_t)head*65536;
#pragma unroll
  for (int ii=0;ii<4;++ii){
    int i = i0+ty+ii*8;
    us bv = f2b(Ab[(size_t)i*256 + j0+tx]*s);
    Zth[(size_t)i*256 + j0+tx] = bv;
    tile[ty+ii*8][tx] = bv;
  }
  __syncthreads();
#pragma unroll
  for (int ii=0;ii<4;++ii){
    int j = j0+ty+ii*8;
    Zh[(size_t)j*256 + i0+tx] = tile[tx][ty+ii*8];
  }
}

// ---------------- attn3: MFMA flash (8 waves x 32 query rows) ----------------
__global__ __launch_bounds__(512) void k_attn3(const us* __restrict__ QLb,
    const us* __restrict__ Kb, const us* __restrict__ Vt,
    float* __restrict__ Pmax, float* __restrict__ Psum, us* __restrict__ Pacc)
{
  __shared__ us Ks[64*64];       // 8 KB
  __shared__ us Vs[64*64];       // 8 KB
  __shared__ us Ps[8*32*64];     // 32 KB (per-wave 32x64 P tile)
  int h = blockIdx.y, cx = blockIdx.x;
  int tid = threadIdx.x, wid = tid>>6, lane = tid&63;   // wid 0..7
  bf16x8 aq[2][2];
#pragma unroll
  for (int mt=0;mt<2;++mt){
    const us* qp = QLb + ((size_t)h*MM + wid*32 + mt*16 + (lane&15))*DHD;
#pragma unroll
    for (int ks=0;ks<2;++ks)
      aq[mt][ks] = *(const bf16x8*)(qp + ks*32 + (lane>>4)*8);
  }
  float m_[2][4], l_[2][4];
  f32x4 acc[2][4] = {};
#pragma unroll
  for (int mt=0;mt<2;++mt)
#pragma unroll
    for (int r=0;r<4;++r){ m_[mt][r] = -1e30f; l_[mt][r] = 0.f; }

  us* Pw = &Ps[wid*2048];
  for (int t=0;t<4;++t){
    int kb0 = cx*CSZ + t*64;
    __syncthreads();
    for (int i=tid;i<1024;i+=512){
      int rr = i>>4, c4 = (i&15)*4;
      ushort4 ku = *(const ushort4*)(Kb + ((size_t)h*NPAD + kb0 + rr)*DHD + c4);
      *(ushort4*)(&Ks[rr*64 + (c4 ^ ((rr&7)<<3))]) = ku;
      ushort4 vu = *(const ushort4*)(Vt + ((size_t)h*DHD + rr)*NPAD + kb0 + c4);
      *(ushort4*)(&Vs[rr*64 + (c4 ^ ((rr&7)<<3))]) = vu;
    }
    __syncthreads();
    f32x4 s[2][4] = {};
    __builtin_amdgcn_s_setprio(1);
#pragma unroll
    for (int ks=0;ks<2;++ks){
      int kk = ks*32 + (lane>>4)*8;
      bf16x8 kbf[4];
#pragma unroll
      for (int nt=0;nt<4;++nt){
        int key = nt*16 + (lane&15);
        kbf[nt] = *(const bf16x8*)(&Ks[key*64 + (kk ^ ((key&7)<<3))]);
      }
#pragma unroll
      for (int mt=0;mt<2;++mt)
#pragma unroll
        for (int nt=0;nt<4;++nt)
          s[mt][nt] = __builtin_amdgcn_mfma_f32_16x16x32_bf16(aq[mt][ks], kbf[nt], s[mt][nt], 0,0,0);
    }
    __builtin_amdgcn_s_setprio(0);
#pragma unroll
    for (int mt=0;mt<2;++mt){
#pragma unroll
      for (int r=0;r<4;++r){
        float mx = fmaxf(fmaxf(s[mt][0][r], s[mt][1][r]), fmaxf(s[mt][2][r], s[mt][3][r]));
#pragma unroll
        for (int off=8;off>=1;off>>=1) mx = fmaxf(mx, __shfl_xor(mx, off));
        float mn = fmaxf(m_[mt][r], mx);
        float f = __expf(m_[mt][r]-mn);
        float la = 0.f;
#pragma unroll
        for (int nt=0;nt<4;++nt){ float p=__expf(s[mt][nt][r]-mn); s[mt][nt][r]=p; la+=p; }
#pragma unroll
        for (int off=8;off>=1;off>>=1) la += __shfl_xor(la, off);
        l_[mt][r] = l_[mt][r]*f + la;
        m_[mt][r] = mn;
#pragma unroll
        for (int dt=0;dt<4;++dt) acc[mt][dt][r] *= f;
      }
    }
#pragma unroll
    for (int mt=0;mt<2;++mt)
#pragma unroll
      for (int r=0;r<4;++r){
        int row = mt*16 + (lane>>4)*4 + r;      // 0..31 within wave
        int sw = (row&7)<<3;
#pragma unroll
        for (int nt=0;nt<4;++nt){
          int col = nt*16 + (lane&15);
          Pw[row*64 + (col ^ sw)] = f2b(s[mt][nt][r]);
        }
      }
    __builtin_amdgcn_s_setprio(1);
#pragma unroll
    for (int ks=0;ks<2;++ks){
      int kk = ks*32 + (lane>>4)*8;
      bf16x8 pa[2], vb[4];
#pragma unroll
      for (int mt=0;mt<2;++mt){
        int arow = mt*16 + (lane&15);
        pa[mt] = *(const bf16x8*)(&Pw[arow*64 + (kk ^ ((arow&7)<<3))]);
      }
#pragma unroll
      for (int dt=0;dt<4;++dt){
        int d = dt*16 + (lane&15);
        vb[dt] = *(const bf16x8*)(&Vs[d*64 + (kk ^ ((d&7)<<3))]);
      }
#pragma unroll
      for (int mt=0;mt<2;++mt)
#pragma unroll
        for (int dt=0;dt<4;++dt)
          acc[mt][dt] = __builtin_amdgcn_mfma_f32_16x16x32_bf16(pa[mt], vb[dt], acc[mt][dt], 0,0,0);
    }
    __builtin_amdgcn_s_setprio(0);
  }
  size_t pbase = ((size_t)h*NCH + cx)*MM;
#pragma unroll
  for (int mt=0;mt<2;++mt)
#pragma unroll
    for (int r=0;r<4;++r){
      int row = wid*32 + mt*16 + (lane>>4)*4 + r;
      if ((lane&15)==0){ Pmax[pbase+row]=m_[mt][r]; Psum[pbase+row]=l_[mt][r]; }
#pragma unroll
      for (int dt=0;dt<4;++dt)
        Pacc[(pbase+row)*DHD + dt*16+(lane&15)] = f2b(acc[mt][dt][r]);
    }
}

__global__ void k_attn3_merge(const float* __restrict__ Pmax, const float* __restrict__ Psum,
    const us* __restrict__ Pacc, us* __restrict__ A3Vtb)
{
  int hm = blockIdx.x; int h = hm>>8, m = hm&255; int d = threadIdx.x;
  float gm = -1e30f;
  for (int c=0;c<NCH;++c) gm = fmaxf(gm, Pmax[((size_t)h*NCH+c)*MM+m]);
  float tot=0.f, acc=0.f;
  for (int c=0;c<NCH;++c){
    size_t pi = ((size_t)h*NCH+c)*MM+m;
    float w = __expf(Pmax[pi]-gm);
    tot += Psum[pi]*w;
    acc += bf2f(Pacc[pi*DHD+d])*w;
  }
  A3Vtb[((size_t)h*DHD + d)*MM + m] = f2b(acc/tot);
}

// ---------------- attn1 ----------------
__global__ __launch_bounds__(256) void k_attn1(const us* __restrict__ Qb,
    const us* __restrict__ KLb, const us* __restrict__ WmT,
    us* __restrict__ OH)
{
  __shared__ us KWs[64*256];
  __shared__ us Ps[64*256];
  int h = blockIdx.y, tid = threadIdx.x;
  int wid = tid>>6, lane = tid&63;
  int q0 = blockIdx.x*64;
  for (int i=tid; i<4096; i+=256){
    int lm = i>>4, k4 = (i&15)*4;
    *(ushort4*)(&KWs[lm*64 + (k4 ^ ((lm&7)<<3))]) =
        *(const ushort4*)(KLb + ((size_t)h*MM + lm)*DHD + k4);
  }
  bf16x8 aq[2];
  const us* qp = Qb + ((size_t)h*NPAD + q0 + wid*16 + (lane&15))*DHD;
#pragma unroll
  for (int ks=0;ks<2;++ks)
    aq[ks] = *(const bf16x8*)(qp + ks*32 + (lane>>4)*8);
  __syncthreads();
  f32x4 s[16];
#pragma unroll
  for (int nt=0;nt<16;++nt) s[nt] = (f32x4){0.f,0.f,0.f,0.f};
  __builtin_amdgcn_s_setprio(1);
#pragma unroll
  for (int ks=0;ks<2;++ks){
    int kk = ks*32 + (lane>>4)*8;
#pragma unroll
    for (int nt=0;nt<16;++nt){
      int col = nt*16 + (lane&15);
      bf16x8 b = *(const bf16x8*)(&KWs[col*64 + (kk ^ ((col&7)<<3))]);
      s[nt] = __builtin_amdgcn_mfma_f32_16x16x32_bf16(aq[ks], b, s[nt], 0,0,0);
    }
  }
  __builtin_amdgcn_s_setprio(0);
  float rcp[4];
#pragma unroll
  for (int r=0;r<4;++r){
    float m = -1e30f;
#pragma unroll
    for (int nt=0;nt<16;++nt) m = fmaxf(m, s[nt][r]);
#pragma unroll
    for (int off=8;off>=1;off>>=1) m = fmaxf(m, __shfl_xor(m, off));
    float l = 0.f;
#pragma unroll
    for (int nt=0;nt<16;++nt){ float p=__expf(s[nt][r]-m); s[nt][r]=p; l+=p; }
#pragma unroll
    for (int off=8;off>=1;off>>=1) l += __shfl_xor(l, off);
    rcp[r] = 1.f/l;
  }
  int prow_base = wid*16 + (lane>>4)*4;
#pragma unroll
  for (int nt=0;nt<16;++nt){
    int col = nt*16 + (lane&15);
#pragma unroll
    for (int r=0;r<4;++r){
      int row = prow_base + r;
      Ps[row*256 + (col ^ ((row&7)<<3))] = f2b(s[nt][r]);
    }
  }
  __syncthreads();
  for (int i=tid; i<4096; i+=256){
    int d = i>>6, k4 = (i&63)*4;
    ushort4 u = *(const ushort4*)(WmT + ((size_t)h*DHD + d)*MM + k4);
    *(ushort4*)(&KWs[d*256 + (k4 ^ ((d&7)<<3))]) = u;
  }
  __syncthreads();
  f32x4 acc[4] = {};
  int arow = wid*16 + (lane&15);
  __builtin_amdgcn_s_setprio(1);
#pragma unroll
  for (int ks=0;ks<8;++ks){
    int kk = ks*32 + (lane>>4)*8;
    bf16x8 a = *(const bf16x8*)(&Ps[arow*256 + (kk ^ ((arow&7)<<3))]);
#pragma unroll
    for (int dt=0;dt<4;++dt){
      int d = dt*16 + (lane&15);
      bf16x8 b = *(const bf16x8*)(&KWs[d*256 + (kk ^ ((d&7)<<3))]);
      acc[dt] = __builtin_amdgcn_mfma_f32_16x16x32_bf16(a, b, acc[dt], 0,0,0);
    }
  }
  __builtin_amdgcn_s_setprio(0);
#pragma unroll
  for (int r=0;r<4;++r){
    int row = q0 + prow_base + r;
    us* op = OH + (size_t)row*DIM + h*DHD;
#pragma unroll
    for (int dt=0;dt<4;++dt)
      op[dt*16 + (lane&15)] = f2b(acc[dt][r]*rcp[r]);
  }
}

// ---------------- depthwise conv along seq, bf16 RMW ----------------
#define SCBLK 32
__global__ __launch_bounds__(256) void k_seqconv(const us* __restrict__ Vb,
    const float* __restrict__ resk, us* __restrict__ OH)
{
  __shared__ us Vs[64*512];
  int tid = threadIdx.x;
  int p0 = blockIdx.x*SCBLK;
  for (int i=tid; i<16384; i+=256){
    int pl = i>>8, c2 = i&255;
    int gp = p0 - 16 + pl;
    int hh = c2>>5, d2 = (c2&31)*2;
    ushort2 v = make_ushort2(0,0);
    if (gp>=0 && gp<NPAD) v = *(const ushort2*)(Vb + ((size_t)hh*NPAD+gp)*DHD + d2);
    *(ushort2*)(&Vs[pl*512 + c2*2]) = v;
  }
  __syncthreads();
  int h = tid>>5;
  float kr[33];
#pragma unroll
  for (int r=0;r<33;++r) kr[r] = resk[h*33+r];
  for (int pl=0; pl<SCBLK; ++pl){
    float s0=0.f, s1=0.f;
#pragma unroll
    for (int r=0;r<33;++r){
      ushort2 v = *(const ushort2*)(&Vs[(pl+r)*512 + tid*2]);
      s0 += bf2f(v.x)*kr[r];
      s1 += bf2f(v.y)*kr[r];
    }
    size_t o = (size_t)(p0+pl)*DIM + tid*2;
    ushort2 cur = *(ushort2*)(OH + o);
    *(ushort2*)(OH + o) = make_ushort2(f2b(bf2f(cur.x)+s0), f2b(bf2f(cur.y)+s1));
  }
}

// ---------------- leff (bf16 planes, bf16 X) ----------------
__global__ void k_tfwd(const us* __restrict__ X, us* __restrict__ T)
{
  __shared__ us tile[32][33];
  int tx = threadIdx.x & 31, ty = threadIdx.x >> 5;
  int s0 = blockIdx.x*32, c0 = blockIdx.y*32;
  for (int yy=0; yy<4; ++yy){
    int s = s0 + ty + yy*8;
    if (s < NTOK) tile[ty+yy*8][tx] = X[(size_t)(1+s)*DIM + c0+tx];
  }
  __syncthreads();
  for (int yy=0; yy<4; ++yy){
    int c = c0 + ty + yy*8;
    int s = s0 + tx;
    if (s < NTOK) T[(size_t)c*NTOK + s] = tile[tx][ty+yy*8];
  }
}
__global__ void k_tbwd(const us* __restrict__ T, us* __restrict__ X)
{
  __shared__ us tile[32][33];
  int tx = threadIdx.x & 31, ty = threadIdx.x >> 5;
  int s0 = blockIdx.x*32, c0 = blockIdx.y*32;
  for (int yy=0; yy<4; ++yy){
    int c = c0 + ty + yy*8, s = s0 + tx;
    if (s < NTOK) tile[ty+yy*8][tx] = T[(size_t)c*NTOK + s];
  }
  __syncthreads();
  for (int yy=0; yy<4; ++yy){
    int s = s0 + ty + yy*8, c = c0 + tx;
    if (s < NTOK) X[(size_t)(1+s)*DIM + c] = tile[tx][ty+yy*8];
  }
}
// scalar depthwise 7/5/3 conv (round-13 variant: high occupancy)
__global__ __launch_bounds__(256) void k_leff(const us* __restrict__ T,
    const float* __restrict__ k7, const float* __restrict__ b7,
    const float* __restrict__ k5, const float* __restrict__ b5,
    const float* __restrict__ k3, const float* __restrict__ b3,
    us* __restrict__ T2)
{
  __shared__ float tile[21*21];
  int c = blockIdx.y;
  int ti = blockIdx.x/10, tj = blockIdx.x%10;
  int i0 = ti*15-3, j0 = tj*15-3;
  const us* img = T + (size_t)c*NTOK;
  for (int idx=threadIdx.x; idx<441; idx+=256){
    int ii = idx/21, jj = idx%21;
    int gi = i0+ii, gj = j0+jj;
    tile[idx] = (gi>=0 && gi<HSZ && gj>=0 && gj<HSZ) ? bf2f(img[gi*HSZ+gj]) : 0.f;
  }
  __syncthreads();
  if (threadIdx.x < 225){
    int li = threadIdx.x/15, lj = threadIdx.x%15;
    int gi = ti*15+li, gj = tj*15+lj;
    float acc = tile[(li+3)*21 + (lj+3)] + b7[c]+b5[c]+b3[c];
    const float* w7 = k7 + c*49;
#pragma unroll
    for (int a=0;a<7;++a)
#pragma unroll
      for (int bb=0;bb<7;++bb) acc += tile[(li+a)*21 + (lj+bb)]*w7[a*7+bb];
    const float* w5 = k5 + c*25;
#pragma unroll
    for (int a=0;a<5;++a)
#pragma unroll
      for (int bb=0;bb<5;++bb) acc += tile[(li+1+a)*21 + (lj+1+bb)]*w5[a*5+bb];
    const float* w3 = k3 + c*9;
#pragma unroll
    for (int a=0;a<3;++a)
#pragma unroll
      for (int bb=0;bb<3;++bb) acc += tile[(li+2+a)*21 + (lj+2+bb)]*w3[a*3+bb];
    T2[(size_t)c*NTOK + gi*HSZ+gj] = f2b(acc);
  }
}

// ---------------- cls-row pieces ----------------
__global__ void k_row1(const float* __restrict__ Q0, const float* __restrict__ KL0,
                       float* __restrict__ row1)
{
  __shared__ float sb[4];
  __shared__ float qv[64];
  int t = threadIdx.x;
  if (t<64) qv[t] = Q0[PADR*DHD + t];
  __syncthreads();
  float l = 0.f;
#pragma unroll
  for (int d=0;d<64;++d) l += qv[d]*KL0[(size_t)t*DHD+d];
  float m = blockMax256(l, sb);
  float e = __expf(l-m);
  float s = blockSum256(e, sb);
  row1[t] = e/s;
}
__global__ void k_rz(const float* __restrict__ row1, const us* __restrict__ Zt,
                     float* __restrict__ rz)
{
  __shared__ float r1[256];
  int t = threadIdx.x;
  r1[t] = row1[t];
  __syncthreads();
  float s = 0.f;
  for (int k2=0;k2<256;++k2) s += r1[k2]*bf2f(Zt[(size_t)t*MM + k2]);
  rz[t] = s;
}
__global__ void k_rowstat(const float* __restrict__ L0, float* __restrict__ mx, float* __restrict__ se)
{
  __shared__ float sb[4];
  const float* row = L0 + (size_t)blockIdx.x*NPAD;
  float m = -1e30f;
  for (int i=threadIdx.x;i<NPAD;i+=256) m = fmaxf(m, row[i]);
  m = blockMax256(m, sb);
  float s = 0.f;
  for (int i=threadIdx.x;i<NPAD;i+=256) s += __expf(row[i]-m);
  s = blockSum256(s, sb);
  if (threadIdx.x==0){ mx[blockIdx.x]=m; se[blockIdx.x]=s; }
}
__global__ void k_aout(const float* __restrict__ L0, const float* __restrict__ rz,
    const float* __restrict__ mx, const float* __restrict__ se, float* __restrict__ out)
{
  __shared__ float wk[256], mk[256];
  int t = threadIdx.x;
  wk[t] = rz[t]/se[t];
  mk[t] = mx[t];
  __syncthreads();
  int p = blockIdx.x*256 + t;
  if (p >= NTOK) return;
  size_t pp = (size_t)(PADR+1+p);
  float a = 0.f;
  for (int k2=0;k2<256;++k2) a += wk[k2]*__expf(L0[(size_t)k2*NPAD+pp]-mk[k2]);
  out[4+p] = a;
}
__global__ void k_final(const us* __restrict__ H2r, const float* __restrict__ nw,
    const float* __restrict__ nbb, const float* __restrict__ w2, const float* __restrict__ b2,
    float* __restrict__ out)
{
  __shared__ float sb[4];
  __shared__ float hf[512];
  int t = threadIdx.x;
  float x0 = bf2f(H2r[t]), x1 = bf2f(H2r[256+t]);
  float s = blockSum256(x0+x1, sb);
  float q = blockSum256(x0*x0+x1*x1, sb);
  float mean = s*(1.f/512.f);
  float var = q*(1.f/512.f) - mean*mean;
  float rstd = rsqrtf(var+1e-5f);
  hf[t]     = (x0-mean)*rstd*nw[t]+nbb[t];
  hf[256+t] = (x1-mean)*rstd*nw[256+t]+nbb[256+t];
  __syncthreads();
  float p0 = hf[t]*w2[t*2]   + hf[256+t]*w2[(256+t)*2];
  float p1 = hf[t]*w2[t*2+1] + hf[256+t]*w2[(256+t)*2+1];
  p0 = blockSum256(p0, sb);
  p1 = blockSum256(p1, sb);
  if (t==0){
    float l0 = p0+b2[0], l1 = p1+b2[1];
    float m = fmaxf(l0,l1);
    float e0 = __expf(l0-m), e1 = __expf(l1-m), si = 1.f/(e0+e1);
    out[0]=l0; out[1]=l1; out[2]=e0*si; out[3]=e1*si;
  }
}

// ---------------- host orchestration ----------------
struct Bufs {
  float *A2,*sums,*scl,*Pmax,*Psum;
  us *Xb,*Yb,*OHb,*Qb,*Kb,*Vb,*Vtb,*QLb,*KLb,*A2b;
  us *Z0b,*Z0tb,*Z1b,*Z1tb,*XZb,*XZtb,*T1tb,*T2tb;
  us *A3Vtb,*WmT,*Pacc,*zpg;
};

static void run_pinv(const us* A2b, Bufs& b, int NB, hipStream_t st)
{
  dim3 g(4,4,NB);
  us *Zc=b.Z0b, *Zct=b.Z0tb, *Zn=b.Z1b, *Znt=b.Z1tb;
  for (int it=0; it<6; ++it){
    k_pgemm<0><<<g,256,0,st>>>(A2b, Zct, b.XZb, b.XZtb, 0.f, 1.f, 1);
    k_pgemm<1><<<g,256,0,st>>>(b.XZb, b.XZtb, nullptr, b.T1tb, 7.f, 1.f, 0);
    k_pgemm<1><<<g,256,0,st>>>(b.XZb, b.T1tb, nullptr, b.T2tb, 15.f, 1.f, 0);
    k_pgemm<1><<<g,256,0,st>>>(Zc, b.T2tb, Zn, Znt, 13.f, 0.25f, 1);
    us* t1=Zc; Zc=Zn; Zn=t1;
    us* t2=Zct; Zct=Znt; Znt=t2;
  }
  // 6 iterations = even number of swaps -> final Z in Z0b/Z0tb
}

static void nystrom_layer(Bufs& b, const float* lnw, const float* lnb,
    const us* wqkvT, const us* woutT,
    const float* bout, const float* resk, int slot, hipStream_t st)
{
  unsigned* mslot = (unsigned*)(b.zpg + 256) + slot;   // zpg bytes 512.. zeroed each replay
  k_ln<<<N1,256,0,st>>>(b.Xb, b.Yb, lnw, lnb);
  k_gemm<1><<<352*12,256,0,st>>>(b.Yb, wqkvT, nullptr,
      nullptr, nullptr, nullptr, b.Qb, b.Kb, b.Vb, b.zpg, DIM, 352);
  k_vT<<<dim3(NPAD/32,16),256,0,st>>>(b.Vb, b.Vtb);
  k_landmark2<<<2*NH*MM,64,0,st>>>(b.Qb, b.Kb, b.QLb, b.KLb);
  k_nt64b<<<dim3(4,4,NH),64,0,st>>>(b.QLb, b.KLb, b.A2,
      (long)MM*DHD,(long)MM*DHD,(long)MM*MM, MM);
  k_softmax256<<<NH*MM,256,0,st>>>(b.A2, b.A2b);
  k_csmax<<<NH,256,0,st>>>(b.A2, mslot);
  k_z0t<<<dim3(8,8*NH),256,0,st>>>(b.A2, b.Z0b, b.Z0tb, mslot);
  run_pinv(b.A2b, b, NH, st);
  k_attn3<<<dim3(NCH,NH),512,0,st>>>(b.QLb, b.Kb, b.Vtb, b.Pmax, b.Psum, b.Pacc);
  k_attn3_merge<<<NH*MM,64,0,st>>>(b.Pmax, b.Psum, b.Pacc, b.A3Vtb);
  k_pgemm2<<<dim3(1,4,NH),256,0,st>>>(b.Z0b, b.A3Vtb, b.WmT);
  k_attn1<<<dim3(NPAD/64,NH),256,0,st>>>(b.Qb, b.KLb, b.WmT, b.OHb);
  k_seqconv<<<NPAD/SCBLK,256,0,st>>>(b.Vb, resk, b.OHb);
  k_gemm<2><<<352*4,256,0,st>>>(b.OHb, woutT, bout,
      b.Xb, nullptr, nullptr, nullptr, nullptr, nullptr, b.zpg, DIM, 352);
}

extern "C" void kernel_launch(void* const* d_in, const int* in_sizes, int n_in,
                              void* d_out, int out_size, void* d_ws, size_t ws_size,
                              hipStream_t stream)
{
  (void)n_in; (void)out_size;
  bool sig_order = (in_sizes[10] == 25088);
  int iL2 = sig_order ? 16 : 10;
  int iLf = sig_order ? 10 : 16;

  const float* h       = (const float*)d_in[0];
  const float* fc1_w   = (const float*)d_in[1];
  const float* fc1_b   = (const float*)d_in[2];
  const float* cls_tok = (const float*)d_in[3];
  const float* l1_lnw  = (const float*)d_in[4];
  const float* l1_lnb  = (const float*)d_in[5];
  const float* l1_wqkv = (const float*)d_in[6];
  const float* l1_wout = (const float*)d_in[7];
  const float* l1_bout = (const float*)d_in[8];
  const float* l1_resk = (const float*)d_in[9];
  const float* l2_lnw  = (const float*)d_in[iL2+0];
  const float* l2_lnb  = (const float*)d_in[iL2+1];
  const float* l2_wqkv = (const float*)d_in[iL2+2];
  const float* l2_wout = (const float*)d_in[iL2+3];
  const float* l2_bout = (const float*)d_in[iL2+4];
  const float* l2_resk = (const float*)d_in[iL2+5];
  const float* k7 = (const float*)d_in[iLf+0];
  const float* b7 = (const float*)d_in[iLf+1];
  const float* k5 = (const float*)d_in[iLf+2];
  const float* b5 = (const float*)d_in[iLf+3];
  const float* k3 = (const float*)d_in[iLf+4];
  const float* b3 = (const float*)d_in[iLf+5];
  const float* nw = (const float*)d_in[22];
  const float* nbb= (const float*)d_in[23];
  const float* w2 = (const float*)d_in[24];
  const float* b2 = (const float*)d_in[25];
  float* out = (float*)d_out;

  char* base = (char*)d_ws;
  auto allocF = [&](size_t n)->float*{
    float* p=(float*)base; base += ((n*sizeof(float)+255)&~(size_t)255); return p; };
  auto allocU = [&](size_t n)->us*{
    us* p=(us*)base; base += ((n*sizeof(us)+255)&~(size_t)255); return p; };

  const size_t S = (size_t)NPAD*DIM;
  const size_t SQ = (size_t)MM*MM;
  Bufs b;
  b.Xb  = allocU(S);
  b.Yb  = allocU(S);
  b.OHb = allocU(S);
  b.Qb  = allocU(S);
  b.Kb  = allocU(S);
  b.Vb  = allocU(S);
  b.Vtb = allocU(S);
  b.QLb = allocU((size_t)NH*MM*DHD);
  b.KLb = allocU((size_t)NH*MM*DHD);
  b.A2  = allocF((size_t)NH*SQ);
  b.A2b = allocU((size_t)NH*SQ);
  b.Z0b = allocU((size_t)NH*SQ);  b.Z0tb = allocU((size_t)NH*SQ);
  b.Z1b = allocU((size_t)NH*SQ);  b.Z1tb = allocU((size_t)NH*SQ);
  b.XZb = allocU((size_t)NH*SQ);  b.XZtb = allocU((size_t)NH*SQ);
  b.T1tb= allocU((size_t)NH*SQ);
  b.T2tb= allocU((size_t)NH*SQ);
  b.A3Vtb = allocU((size_t)NH*MM*DHD);
  b.WmT   = allocU((size_t)NH*MM*DHD);
  b.sums  = allocF(2*(size_t)NH*MM);
  b.scl   = allocF(16);
  b.Pmax  = allocF((size_t)NH*NCH*MM);
  b.Psum  = allocF((size_t)NH*NCH*MM);
  b.Pacc  = allocU((size_t)NH*NCH*MM*DHD);
  b.zpg   = allocU(512);
  us* hb     = allocU((size_t)NTOK*1024);
  us* fc1T   = allocU((size_t)DIM*1024);
  us* wqkvT1 = allocU((size_t)1536*DIM);
  us* wqkvT2 = allocU((size_t)1536*DIM);
  us* woutT1 = allocU((size_t)DIM*DIM);
  us* woutT2 = allocU((size_t)DIM*DIM);
  float* Q0   = allocF((size_t)NPAD*DHD);
  float* K0   = allocF((size_t)NPAD*DHD);
  float* QL0f = allocF((size_t)MM*DHD);
  float* KL0f = allocF((size_t)MM*DHD);
  float* row1 = allocF(256);
  float* rzv  = allocF(256);
  float* mxv  = allocF(256);
  float* sev  = allocF(256);
  us* h2row = allocU(512);
  if ((size_t)(base - (char*)d_ws) > ws_size) return;

  hipMemsetAsync((void*)b.zpg, 0, 1024, stream);

  // input + weight conversions (fp32 -> bf16)
  k_cvt<<<((size_t)NTOK*1024/4 + 255)/256,256,0,stream>>>(h, hb, (size_t)NTOK*1024/4);
  k_wT<<<dim3(32,16),256,0,stream>>>(fc1_w, fc1T, 1024, DIM);
  k_wT<<<dim3(16,48),256,0,stream>>>(l1_wqkv, wqkvT1, DIM, 1536);
  k_wT<<<dim3(16,48),256,0,stream>>>(l2_wqkv, wqkvT2, DIM, 1536);
  k_wT<<<dim3(16,16),256,0,stream>>>(l1_wout, woutT1, DIM, DIM);
  k_wT<<<dim3(16,16),256,0,stream>>>(l2_wout, woutT2, DIM, DIM);

  // stage 0: fc1 + cls token
  k_gemm<0><<<352*4,256,0,stream>>>(hb, fc1T, fc1_b,
      b.Xb, nullptr, nullptr, nullptr, nullptr, nullptr, b.zpg, 1024, 352);
  k_setcls<<<2,256,0,stream>>>(b.Xb, cls_tok);

  // layer 1 + LeFF
  nystrom_layer(b, l1_lnw, l1_lnb, wqkvT1, woutT1, l1_bout, l1_resk, 0, stream);
  k_tfwd<<<dim3(704,16),256,0,stream>>>(b.Xb, b.OHb);
  k_leff<<<dim3(100,512),256,0,stream>>>(b.OHb, k7,b7,k5,b5,k3,b3, b.Qb);
  k_tbwd<<<dim3(704,16),256,0,stream>>>(b.Qb, b.Xb);

  // layer 2 (save h2 row 0)
  nystrom_layer(b, l2_lnw, l2_lnb, wqkvT2, woutT2, l2_bout, l2_resk, 1, stream);
  k_copyu<<<2,256,0,stream>>>(h2row, b.Xb, 512);

  // layer 3 -> h3
  nystrom_layer(b, l2_lnw, l2_lnb, wqkvT2, woutT2, l2_bout, l2_resk, 2, stream);

  // cls-row stage (head 0, l2 weights, LN(h3))
  unsigned* mslot3 = (unsigned*)(b.zpg + 256) + 3;
  k_ln<<<N1,256,0,stream>>>(b.Xb, b.Yb, l2_lnw, l2_lnb);
  k_gemm<3><<<352,256,0,stream>>>(b.Yb, wqkvT2, nullptr,
      nullptr, Q0, K0, nullptr, nullptr, nullptr, b.zpg, DIM, 352);
  k_landmark2f<<<2*MM,64,0,stream>>>(Q0, K0, QL0f, KL0f);
  k_nt64<<<dim3(4,4,1),64,0,stream>>>(QL0f, KL0f, b.A2, 0,0,0, MM);
  k_softmax256<<<MM,256,0,stream>>>(b.A2, b.A2b);
  k_csmax<<<1,256,0,stream>>>(b.A2, mslot3);
  k_z0t<<<dim3(8,8),256,0,stream>>>(b.A2, b.Z0b, b.Z0tb, mslot3);
  run_pinv(b.A2b, b, 1, stream);
  k_row1<<<1,256,0,stream>>>(Q0, KL0f, row1);
  k_rz<<<1,256,0,stream>>>(row1, b.Z0tb, rzv);
  // L0 = QL0 @ K0^T (256 x NPAD), into Yb's storage (NPAD*256 floats)
  float* L0 = (float*)b.Yb;
  k_nt64<<<dim3(NPAD/64,4,1),64,0,stream>>>(QL0f, K0, L0, 0,0,0, NPAD);
  k_rowstat<<<MM,256,0,stream>>>(L0, mxv, sev);
  k_aout<<<88,256,0,stream>>>(L0, rzv, mxv, sev, out);
  k_final<<<1,256,0,stream>>>(h2row, nw, nbb, w2, b2, out);
}

// Round 20
// 2201.661 us; speedup vs baseline: 1.5801x; 1.0197x over previous
//
#include <hip/hip_runtime.h>

#define NTOK 22500
#define N1   22501
#define NPAD 22528
#define PADR 27
#define DIM  512
#define NH   8
#define DHD  64
#define MM   256
#define LLM  88
#define HSZ  150
#define CSZ  256
#define NCH  88   // NPAD / CSZ

typedef short bf16x8 __attribute__((ext_vector_type(8)));
typedef float f32x4  __attribute__((ext_vector_type(4)));
typedef unsigned short us;

union U8 { bf16x8 v; unsigned short u[8]; };

__device__ __forceinline__ unsigned short f2b(float f){
  unsigned int u = __float_as_uint(f);
  unsigned int r = u + 0x7fffu + ((u>>16)&1u);
  return (unsigned short)(r>>16);
}
__device__ __forceinline__ float bf2f(unsigned short u){
  return __uint_as_float(((unsigned int)u)<<16);
}
__device__ __forceinline__ bf16x8 cvt8(float4 a, float4 b){
  U8 u;
  u.u[0]=f2b(a.x); u.u[1]=f2b(a.y); u.u[2]=f2b(a.z); u.u[3]=f2b(a.w);
  u.u[4]=f2b(b.x); u.u[5]=f2b(b.y); u.u[6]=f2b(b.z); u.u[7]=f2b(b.w);
  return u.v;
}
// async global->LDS, 16B per lane; lds dest = wave-uniform base + lane*16
__device__ __forceinline__ void gld16(const void* g, void* l){
  __builtin_amdgcn_global_load_lds(
      (const __attribute__((address_space(1))) void*)g,
      (__attribute__((address_space(3))) void*)l, 16, 0, 0);
}

// ---------------- reduction helpers ----------------
__device__ __forceinline__ float waveSum(float v){
#pragma unroll
  for (int o=32;o>0;o>>=1) v += __shfl_down(v,o);
  return v;
}
__device__ __forceinline__ float waveMax(float v){
#pragma unroll
  for (int o=32;o>0;o>>=1) v = fmaxf(v,__shfl_down(v,o));
  return v;
}
__device__ __forceinline__ float waveSumX(float v){
#pragma unroll
  for (int o=32;o>0;o>>=1) v += __shfl_xor(v,o);
  return v;
}
__device__ __forceinline__ float waveMaxX(float v){
#pragma unroll
  for (int o=32;o>0;o>>=1) v = fmaxf(v,__shfl_xor(v,o));
  return v;
}
__device__ __forceinline__ float blockSum256(float v, float* sb){
  v = waveSum(v);
  __syncthreads();
  if ((threadIdx.x&63)==0) sb[threadIdx.x>>6]=v;
  __syncthreads();
  return sb[0]+sb[1]+sb[2]+sb[3];
}
__device__ __forceinline__ float blockMax256(float v, float* sb){
  v = waveMax(v);
  __syncthreads();
  if ((threadIdx.x&63)==0) sb[threadIdx.x>>6]=v;
  __syncthreads();
  return fmaxf(fmaxf(sb[0],sb[1]),fmaxf(sb[2],sb[3]));
}

// ---------------- fp32 -> bf16 convert ----------------
__global__ void k_cvt(const float* __restrict__ src, us* __restrict__ dst, size_t n4)
{
  size_t i = ((size_t)blockIdx.x*256 + threadIdx.x);
  if (i < n4){
    float4 v = *(const float4*)(src + i*4);
    ushort4 u; u.x=f2b(v.x); u.y=f2b(v.y); u.z=f2b(v.z); u.w=f2b(v.w);
    *(ushort4*)(dst + i*4) = u;
  }
}

// ---------------- weight transpose+cvt: W fp32 [K][N] -> Bt bf16 [N][K] ----------------
__global__ void k_wT(const float* __restrict__ W, us* __restrict__ Bt, int K, int N)
{
  __shared__ float tile[32][33];
  int tx = threadIdx.x&31, ty = threadIdx.x>>5;
  int k0 = blockIdx.x*32, n0 = blockIdx.y*32;
#pragma unroll
  for (int i=0;i<4;++i){
    int k = k0+ty+i*8;
    if (k<K && n0+tx<N) tile[ty+i*8][tx] = W[(size_t)k*N + n0+tx];
  }
  __syncthreads();
#pragma unroll
  for (int i=0;i<4;++i){
    int n = n0+ty+i*8, k = k0+tx;
    if (n<N && k<K) Bt[(size_t)n*K + k] = f2b(tile[tx][ty+i*8]);
  }
}

// ---------------- V transpose: Vb [h][p][d] -> Vtb [h][d][p] ----------------
__global__ void k_vT(const us* __restrict__ V, us* __restrict__ Vt)
{
  __shared__ us tile[32][33];
  int tx = threadIdx.x&31, ty = threadIdx.x>>5;
  int p0 = blockIdx.x*32;
  int h = blockIdx.y>>1, d0 = (blockIdx.y&1)*32;
#pragma unroll
  for (int i=0;i<4;++i){
    int p = p0+ty+i*8;
    tile[ty+i*8][tx] = V[((size_t)h*NPAD+p)*DHD + d0+tx];
  }
  __syncthreads();
#pragma unroll
  for (int i=0;i<4;++i){
    int d = d0+ty+i*8;
    Vt[((size_t)h*DHD+d)*NPAD + p0+tx] = tile[tx][ty+i*8];
  }
}

// ---------------- MFMA GEMM (64x128 tile), 3-buffer counted-vmcnt pipeline ----------------
// MODE 0: fc1 (A=hb bf16 -> X bf16 relu)   MODE 1: qkv (A=Yb bf16 -> Qb/Kb/Vb)
// MODE 2: wout (A=OHb bf16, X bf16 +=)     MODE 3: qk0 (A=Yb bf16 -> Q0/K0 fp32)
template<int MODE>
__global__ __launch_bounds__(256) void k_gemm(
    const us* __restrict__ Ab, const us* __restrict__ Bt, const float* __restrict__ bias,
    us* __restrict__ Xb, float* __restrict__ Cf, float* __restrict__ C2,
    us* __restrict__ Q_, us* __restrict__ K_, us* __restrict__ V_,
    const us* __restrict__ zpg, int Kd, int mtn)
{
  constexpr int BM = 64;
  constexpr int BUFE = BM*64 + 128*64;    // 12288 us per buffer
  __shared__ us SM[3*BUFE];               // 72 KB
  const int tid = threadIdx.x;
  const int bid = blockIdx.x;
  const int ntile = bid / mtn;            // m-fastest: consecutive blocks share B panel
  const int m0 = (bid % mtn)*BM, n0 = ntile*128;
  const int lane = tid & 63;
  const int wid = tid >> 6;
  const int wm = (wid>>1)*32, wn = (wid&1)*64;
  f32x4 acc[2][4] = {};
  const int NT = Kd >> 6;

  auto stage = [&](int t, int buf){
    us* As = SM + buf*BUFE;
    us* Bs = As + BM*64;
    int k0 = t*64;
#pragma unroll
    for (int i=0;i<2;++i){
      int c = wid*2+i;
      int row = c*8 + (lane>>3);
      int scol8 = ((lane&7) ^ (row&7))*8;
      int gm = m0+row;
      const us* ga;
      if (MODE==0)      ga = (gm<NTOK) ? Ab + (size_t)gm*Kd + k0 + scol8 : zpg + scol8;
      else if (MODE==2) ga = Ab + ((size_t)((gm<N1?gm:0)+PADR))*Kd + k0 + scol8;
      else              ga = (gm>=PADR) ? Ab + (size_t)(gm-PADR)*Kd + k0 + scol8 : zpg + scol8;
      gld16(ga, &As[c*512]);
    }
#pragma unroll
    for (int i=0;i<4;++i){
      int c = wid*4+i;
      int row = c*8 + (lane>>3);
      int scol8 = ((lane&7) ^ (row&7))*8;
      int vn = n0+row;
      if (MODE==3) vn = (vn<64)? vn : vn+448;
      gld16(Bt + (size_t)vn*Kd + k0 + scol8, &Bs[c*512]);
    }
  };

  stage(0, 0);
  stage(1, 1);
  for (int t=0; t<NT; ++t){
    asm volatile("s_waitcnt vmcnt(6)" ::: "memory");   // oldest stage (t) landed in LDS
    __builtin_amdgcn_s_barrier();                      // raw barrier: NO vmcnt drain
    asm volatile("" ::: "memory");
    if (t+2 < NT) stage(t+2, (t+2)%3);                 // buf (t+2)%3: last read at iter t-1
    us* As = SM + (t%3)*BUFE;
    us* Bs = As + BM*64;
#pragma unroll
    for (int ks=0; ks<2; ++ks){
      const int kk = ks*32 + (lane>>4)*8;
      bf16x8 af[2], bfm[4];
#pragma unroll
      for (int tt=0;tt<2;++tt){
        int r = wm + tt*16 + (lane&15);
        af[tt] = *(bf16x8*)(&As[r*64 + (kk ^ ((r&7)<<3))]);
      }
#pragma unroll
      for (int tt=0;tt<4;++tt){
        int c = wn + tt*16 + (lane&15);
        bfm[tt] = *(bf16x8*)(&Bs[c*64 + (kk ^ ((c&7)<<3))]);
      }
#pragma unroll
      for (int mt=0;mt<2;++mt)
#pragma unroll
        for (int nt=0;nt<4;++nt)
          acc[mt][nt] = __builtin_amdgcn_mfma_f32_16x16x32_bf16(af[mt], bfm[nt], acc[mt][nt], 0,0,0);
    }
  }
  __syncthreads();
  const int rbase = (lane>>4)*4;
  const int cl = lane&15;
  if (MODE==3){
#pragma unroll
    for (int mt=0;mt<2;++mt)
#pragma unroll
      for (int r=0;r<4;++r){
        int gm = m0 + wm + mt*16 + rbase + r;
#pragma unroll
        for (int nt=0;nt<4;++nt){
          int gn = n0 + wn + nt*16 + cl;
          float v = acc[mt][nt][r];
          if (gn < 64) Cf[(size_t)gm*DHD + gn] = v*0.125f;
          else         C2[(size_t)gm*DHD + (gn-64)] = v;
        }
      }
    return;
  }
  // LDS relayout epilogues (coalesced 16B bf16 stores)
  const float sc1 = (MODE==1 && (ntile>>2)==0) ? 0.125f : 1.f;
#pragma unroll
  for (int mt=0;mt<2;++mt)
#pragma unroll
    for (int r=0;r<4;++r){
      int row = wm + mt*16 + rbase + r;
#pragma unroll
      for (int nt=0;nt<4;++nt){
        int col = wn + nt*16 + cl;
        float v = acc[mt][nt][r];
        if (MODE==0){ v += bias[n0+col]; v = v>0.f?v:0.f; }
        else if (MODE==2){ v += bias[n0+col]; }
        else v *= sc1;
        SM[row*128 + col] = f2b(v);
      }
    }
  __syncthreads();
  if (MODE==1){
    const int sec = ntile>>2;
    us* dst = sec==0 ? Q_ : (sec==1 ? K_ : V_);
#pragma unroll
    for (int i=0;i<4;++i){
      int v8 = i*256 + tid;
      int row = v8>>4, c8 = (v8&15)*8;
      int gm = m0 + row, gn = n0 + c8;
      int hh = (gn>>6)&7, d = gn&63;
      *(bf16x8*)(dst + ((size_t)hh*NPAD+gm)*DHD + d) = *(bf16x8*)(&SM[row*128 + c8]);
    }
  } else if (MODE==0){
#pragma unroll
    for (int i=0;i<4;++i){
      int v8 = i*256 + tid;
      int row = v8>>4, c8 = (v8&15)*8;
      int gm = m0 + row;
      if (gm < NTOK)
        *(bf16x8*)(Xb + (size_t)(1+gm)*DIM + n0 + c8) = *(bf16x8*)(&SM[row*128 + c8]);
    }
  } else {  // MODE 2: bf16 RMW on X
#pragma unroll
    for (int i=0;i<4;++i){
      int v8 = i*256 + tid;
      int row = v8>>4, c8 = (v8&15)*8;
      int gm = m0 + row;
      if (gm < N1){
        us* p = Xb + (size_t)gm*DIM + n0 + c8;
        U8 xo, ad, o;
        xo.v = *(bf16x8*)p;
        ad.v = *(bf16x8*)(&SM[row*128 + c8]);
#pragma unroll
        for (int j=0;j<8;++j) o.u[j] = f2b(bf2f(xo.u[j]) + bf2f(ad.u[j]));
        *(bf16x8*)p = o.v;
      }
    }
  }
}

__global__ void k_setcls(us* __restrict__ X, const float* __restrict__ cls){
  int i = blockIdx.x*256 + threadIdx.x;
  if (i < DIM) X[i] = f2b(cls[i]);
}
__global__ void k_copyu(us* __restrict__ d, const us* __restrict__ s, size_t n){
  size_t i = (size_t)blockIdx.x*256 + threadIdx.x;
  if (i<n) d[i]=s[i];
}

// ---------------- layernorm: bf16 in -> bf16 out (wave-per-row, 4 rows/block) ----------------
__global__ __launch_bounds__(256) void k_ln(const us* __restrict__ X, us* __restrict__ Y,
                     const float* __restrict__ w, const float* __restrict__ b)
{
  int r = blockIdx.x*4 + (threadIdx.x>>6);
  if (r >= N1) return;
  int lane = threadIdx.x & 63;
  U8 xv; xv.v = *(const bf16x8*)(X + (size_t)r*DIM + lane*8);
  float a[8]; float s=0.f, q=0.f;
#pragma unroll
  for (int j=0;j<8;++j){ a[j]=bf2f(xv.u[j]); s+=a[j]; q+=a[j]*a[j]; }
  s = waveSumX(s); q = waveSumX(q);
  float mean = s*(1.f/512.f);
  float var  = q*(1.f/512.f) - mean*mean;
  float rstd = rsqrtf(var+1e-5f);
  float4 w0 = *(const float4*)(w + lane*8);
  float4 w1 = *(const float4*)(w + lane*8 + 4);
  float4 b0 = *(const float4*)(b + lane*8);
  float4 b1 = *(const float4*)(b + lane*8 + 4);
  float wv[8] = {w0.x,w0.y,w0.z,w0.w,w1.x,w1.y,w1.z,w1.w};
  float bv[8] = {b0.x,b0.y,b0.z,b0.w,b1.x,b1.y,b1.z,b1.w};
  U8 o;
#pragma unroll
  for (int j=0;j<8;++j) o.u[j] = f2b((a[j]-mean)*rstd*wv[j]+bv[j]);
  *(bf16x8*)(Y + (size_t)r*DIM + lane*8) = o.v;
}

// ---------------- landmarks (fused Q+K) ----------------
__global__ void k_landmark2(const us* __restrict__ Q, const us* __restrict__ K,
                            us* __restrict__ QL, us* __restrict__ KL)
{
  int hm = blockIdx.x;
  bool isK = hm >= NH*MM;
  if (isK) hm -= NH*MM;
  int h = hm>>8, m = hm&255; int d = threadIdx.x;
  const us* base = (isK?K:Q) + ((size_t)h*NPAD + (size_t)m*LLM)*DHD + d;
  float s = 0.f;
  for (int j=0;j<LLM;++j) s += bf2f(base[(size_t)j*DHD]);
  (isK?KL:QL)[((size_t)h*MM + m)*DHD + d] = f2b(s * (1.f/(float)LLM));
}
__global__ void k_landmark2f(const float* __restrict__ Q, const float* __restrict__ K,
                             float* __restrict__ QL, float* __restrict__ KL)
{
  int hm = blockIdx.x;
  bool isK = hm >= MM;
  int m = isK ? hm-MM : hm; int d = threadIdx.x;
  const float* base = (isK?K:Q) + (size_t)m*LLM*DHD + d;
  float s = 0.f;
  for (int j=0;j<LLM;++j) s += base[(size_t)j*DHD];
  (isK?KL:QL)[(size_t)m*DHD + d] = s * (1.f/(float)LLM);
}

// ---------------- MFMA NT gemm K=64, fp32 inputs ----------------
__global__ __launch_bounds__(64) void k_nt64(const float* __restrict__ A,
    const float* __restrict__ B, float* __restrict__ C,
    long sA, long sB, long sC, int Nr)
{
  int lane = threadIdx.x;
  int n0 = blockIdx.x*64, m0 = blockIdx.y*64;
  A += (size_t)blockIdx.z*sA; B += (size_t)blockIdx.z*sB; C += (size_t)blockIdx.z*sC;
  f32x4 acc[4][4] = {};
#pragma unroll
  for (int ks=0;ks<2;++ks){
    int kk = ks*32 + (lane>>4)*8;
    bf16x8 af[4], bfr[4];
#pragma unroll
    for (int mt=0;mt<4;++mt){
      const float* p = A + (size_t)(m0+mt*16+(lane&15))*64 + kk;
      af[mt] = cvt8(*(const float4*)p, *(const float4*)(p+4));
    }
#pragma unroll
    for (int nt=0;nt<4;++nt){
      const float* p = B + (size_t)(n0+nt*16+(lane&15))*64 + kk;
      bfr[nt] = cvt8(*(const float4*)p, *(const float4*)(p+4));
    }
#pragma unroll
    for (int mt=0;mt<4;++mt)
#pragma unroll
      for (int nt=0;nt<4;++nt)
        acc[mt][nt] = __builtin_amdgcn_mfma_f32_16x16x32_bf16(af[mt], bfr[nt], acc[mt][nt], 0,0,0);
  }
#pragma unroll
  for (int mt=0;mt<4;++mt)
#pragma unroll
    for (int r=0;r<4;++r){
      int row = m0+mt*16+(lane>>4)*4+r;
#pragma unroll
      for (int nt=0;nt<4;++nt){
        int col = n0+nt*16+(lane&15);
        C[(size_t)row*Nr + col] = acc[mt][nt][r];
      }
    }
}

// ---------------- MFMA NT gemm K=64, bf16 inputs (attn2 logits) ----------------
__global__ __launch_bounds__(64) void k_nt64b(const us* __restrict__ A,
    const us* __restrict__ B, float* __restrict__ C,
    long sA, long sB, long sC, int Nr)
{
  int lane = threadIdx.x;
  int n0 = blockIdx.x*64, m0 = blockIdx.y*64;
  A += (size_t)blockIdx.z*sA; B += (size_t)blockIdx.z*sB; C += (size_t)blockIdx.z*sC;
  f32x4 acc[4][4] = {};
#pragma unroll
  for (int ks=0;ks<2;++ks){
    int kk = ks*32 + (lane>>4)*8;
    bf16x8 af[4], bfr[4];
#pragma unroll
    for (int mt=0;mt<4;++mt)
      af[mt] = *(const bf16x8*)(A + (size_t)(m0+mt*16+(lane&15))*64 + kk);
#pragma unroll
    for (int nt=0;nt<4;++nt)
      bfr[nt] = *(const bf16x8*)(B + (size_t)(n0+nt*16+(lane&15))*64 + kk);
#pragma unroll
    for (int mt=0;mt<4;++mt)
#pragma unroll
      for (int nt=0;nt<4;++nt)
        acc[mt][nt] = __builtin_amdgcn_mfma_f32_16x16x32_bf16(af[mt], bfr[nt], acc[mt][nt], 0,0,0);
  }
#pragma unroll
  for (int mt=0;mt<4;++mt)
#pragma unroll
    for (int r=0;r<4;++r){
      int row = m0+mt*16+(lane>>4)*4+r;
#pragma unroll
      for (int nt=0;nt<4;++nt){
        int col = n0+nt*16+(lane&15);
        C[(size_t)row*Nr + col] = acc[mt][nt][r];
      }
    }
}

// ---------------- pinv MFMA gemm (dispatched, all-bf16, 64x64 tile, coalesced epilogue) ----------------
// PM 0: C=A@B (write C+Ct)   PM 1: C=alpha*(dc*A - A@B) (write Ct, C if writeC)
template<int PM>
__global__ __launch_bounds__(256) void k_pgemm(const us* __restrict__ A,
    const us* __restrict__ Bt, us* __restrict__ C, us* __restrict__ Ct,
    float dc, float alpha, int writeC)
{
  __shared__ us As[64*256];
  __shared__ us Bs[64*256];
  const int tid = threadIdx.x, lane = tid&63, wid = tid>>6;
  const int n0 = blockIdx.x*64, m0 = blockIdx.y*64;
  const us* Ab = A + (size_t)blockIdx.z*65536;
  const us* Bb = Bt + (size_t)blockIdx.z*65536;
  for (int i=tid; i<4096; i+=256){
    int r = i>>6, c4 = (i&63)*4;
    *(ushort4*)(&As[r*256 + (c4 ^ ((r&7)<<3))]) = *(const ushort4*)(Ab + (size_t)(m0+r)*256 + c4);
    *(ushort4*)(&Bs[r*256 + (c4 ^ ((r&7)<<3))]) = *(const ushort4*)(Bb + (size_t)(n0+r)*256 + c4);
  }
  __syncthreads();
  const int wm = (wid>>1)*32, wn = (wid&1)*32;
  f32x4 acc[2][2] = {};
#pragma unroll
  for (int ks=0;ks<8;++ks){
    int kk = ks*32 + (lane>>4)*8;
    bf16x8 af[2], bfr[2];
#pragma unroll
    for (int t=0;t<2;++t){
      int rr = wm + t*16 + (lane&15);
      af[t] = *(const bf16x8*)(&As[rr*256 + (kk ^ ((rr&7)<<3))]);
      int cc = wn + t*16 + (lane&15);
      bfr[t] = *(const bf16x8*)(&Bs[cc*256 + (kk ^ ((cc&7)<<3))]);
    }
#pragma unroll
    for (int mt=0;mt<2;++mt)
#pragma unroll
      for (int nt=0;nt<2;++nt)
        acc[mt][nt] = __builtin_amdgcn_mfma_f32_16x16x32_bf16(af[mt], bfr[nt], acc[mt][nt], 0,0,0);
  }
  // fold PM1 diag term (A read from LDS), keep in regs
  float vv[2][4][2];
#pragma unroll
  for (int mt=0;mt<2;++mt)
#pragma unroll
    for (int q=0;q<4;++q){
      int rl = wm + mt*16 + (lane>>4)*4 + q;
#pragma unroll
      for (int nt=0;nt<2;++nt){
        int clx = wn + nt*16 + (lane&15);
        float v = acc[mt][nt][q];
        if (PM==1) v = alpha*(dc*bf2f(As[rl*256 + (clx ^ ((rl&7)<<3))]) - v);
        vv[mt][q][nt] = v;
      }
    }
  __syncthreads();
  // write 64x64 tile into LDS (swizzled), reuse As
  us* TT = As;
#pragma unroll
  for (int mt=0;mt<2;++mt)
#pragma unroll
    for (int q=0;q<4;++q){
      int rl = wm + mt*16 + (lane>>4)*4 + q;
      int sw = (rl&7)<<3;
#pragma unroll
      for (int nt=0;nt<2;++nt){
        int clx = wn + nt*16 + (lane&15);
        TT[rl*64 + (clx ^ sw)] = f2b(vv[mt][q][nt]);
      }
    }
  __syncthreads();
  // coalesced transposed store
  {
    int c = tid>>2, r0 = (tid&3)*16;
    U8 b0, b1;
#pragma unroll
    for (int i=0;i<8;++i){
      int r = r0+i;       b0.u[i] = TT[r*64 + (c ^ ((r&7)<<3))];
      int r2 = r0+8+i;    b1.u[i] = TT[r2*64 + (c ^ ((r2&7)<<3))];
    }
    us* dst = Ct + (size_t)blockIdx.z*65536 + (size_t)(n0+c)*256 + m0 + r0;
    *(bf16x8*)dst = b0.v;
    *(bf16x8*)(dst+8) = b1.v;
  }
  if (PM==0 || writeC){
    int rr = tid>>2, c0 = (tid&3)*16;
    int sw = (rr&7)<<3;
    bf16x8 x0 = *(const bf16x8*)(&TT[rr*64 + (c0 ^ sw)]);
    bf16x8 x1 = *(const bf16x8*)(&TT[rr*64 + ((c0+8) ^ sw)]);
    us* dc2 = C + (size_t)blockIdx.z*65536 + (size_t)(m0+rr)*256 + n0 + c0;
    *(bf16x8*)dc2 = x0;
    *(bf16x8*)(dc2+8) = x1;
  }
}

// ---------------- WmT gemm (dispatch) ----------------
__global__ __launch_bounds__(256) void k_pgemm2(const us* __restrict__ A,
    const us* __restrict__ Bt, us* __restrict__ Ct)
{
  __shared__ us As[16384];
  __shared__ us Bs[16384];
  const int tid = threadIdx.x, lane = tid&63, wid = tid>>6;
  const int n0 = 0, m0 = blockIdx.y*64;
  const us* Ab = A + (size_t)blockIdx.z*65536;
  const us* Bb = Bt + (size_t)blockIdx.z*16384;
  for (int i=tid; i<4096; i+=256){
    int r = i>>6, c4 = (i&63)*4;
    *(ushort4*)(&As[r*256 + (c4 ^ ((r&7)<<3))]) = *(const ushort4*)(Ab + (size_t)(m0+r)*256 + c4);
    if (r < 64)
      *(ushort4*)(&Bs[r*256 + (c4 ^ ((r&7)<<3))]) = *(const ushort4*)(Bb + (size_t)(n0+r)*256 + c4);
  }
  __syncthreads();
  const int wm = (wid>>1)*32, wn = (wid&1)*32;
  f32x4 acc[2][2] = {};
#pragma unroll
  for (int ks=0;ks<8;++ks){
    int kk = ks*32 + (lane>>4)*8;
    bf16x8 af[2], bfr[2];
#pragma unroll
    for (int t=0;t<2;++t){
      int rr = wm + t*16 + (lane&15);
      af[t] = *(const bf16x8*)(&As[rr*256 + (kk ^ ((rr&7)<<3))]);
      int cc = wn + t*16 + (lane&15);
      bfr[t] = *(const bf16x8*)(&Bs[cc*256 + (kk ^ ((cc&7)<<3))]);
    }
#pragma unroll
    for (int mt=0;mt<2;++mt)
#pragma unroll
      for (int nt=0;nt<2;++nt)
        acc[mt][nt] = __builtin_amdgcn_mfma_f32_16x16x32_bf16(af[mt], bfr[nt], acc[mt][nt], 0,0,0);
  }
#pragma unroll
  for (int mt=0;mt<2;++mt)
#pragma unroll
    for (int r=0;r<4;++r){
      int row = m0 + wm + mt*16 + (lane>>4)*4 + r;
#pragma unroll
      for (int nt=0;nt<2;++nt){
        int col = n0 + wn + nt*16 + (lane&15);
        Ct[(size_t)blockIdx.z*16384 + (size_t)col*256 + row] = f2b(acc[mt][nt][r]);
      }
    }
}

// ---------------- small elementwise ----------------
// softmax over 256-wide rows: one wave per row, 4 rows per block
__global__ __launch_bounds__(256) void k_softmax256(float* __restrict__ S, us* __restrict__ Sb)
{
  int row = blockIdx.x*4 + (threadIdx.x>>6);
  int lane = threadIdx.x & 63;
  float* rp = S + ((size_t)row<<8);
  float4 xv = *(float4*)(rp + lane*4);
  float m = fmaxf(fmaxf(xv.x,xv.y),fmaxf(xv.z,xv.w));
  m = waveMaxX(m);
  float e0=__expf(xv.x-m), e1=__expf(xv.y-m), e2=__expf(xv.z-m), e3=__expf(xv.w-m);
  float s = waveSumX(e0+e1+e2+e3);
  float inv = 1.f/s;
  float4 p; p.x=e0*inv; p.y=e1*inv; p.z=e2*inv; p.w=e3*inv;
  *(float4*)(rp + lane*4) = p;
  ushort4 u; u.x=f2b(p.x); u.y=f2b(p.y); u.z=f2b(p.z); u.w=f2b(p.w);
  *(ushort4*)(Sb + ((size_t)row<<8) + lane*4) = u;
}
// col-sum max per head, then device atomic-max into mslot (positive floats: uint order == float order)
__global__ void k_csmax(const float* __restrict__ A2, unsigned* __restrict__ mslot)
{
  __shared__ float sb[4];
  int b = blockIdx.x, j = threadIdx.x;
  const float* Ab = A2 + ((size_t)b<<16);
  float s = 0.f;
  for (int i=0;i<256;++i) s += Ab[((size_t)i<<8)+j];
  float m = blockMax256(s, sb);
  if (j==0) atomicMax(mslot, __float_as_uint(m));
}
// tiled Z0: Zt = A2*s (row-major), Z = A2^T*s, both coalesced via LDS 32x32
__global__ void k_z0t(const float* __restrict__ A2, us* __restrict__ Z, us* __restrict__ Zt,
                      const unsigned* __restrict__ mslot)
{
  __shared__ us tile[32][33];
  int tx = threadIdx.x&31, ty = threadIdx.x>>5;
  int i0 = blockIdx.x*32;
  int head = blockIdx.y>>3, j0 = (blockIdx.y&7)*32;
  float s = 1.f/__uint_as_float(mslot[0]);
  const float* Ab = A2 + (size_t)head*65536;
  us* Zh  = Z  + (size_t)head*65536;
  us* Zth = Zt + (size_t)head*65536;
#pragma unroll
  for (int ii=0;ii<4;++ii){
    int i = i0+ty+ii*8;
    us bv = f2b(Ab[(size_t)i*256 + j0+tx]*s);
    Zth[(size_t)i*256 + j0+tx] = bv;
    tile[ty+ii*8][tx] = bv;
  }
  __syncthreads();
#pragma unroll
  for (int ii=0;ii<4;++ii){
    int j = j0+ty+ii*8;
    Zh[(size_t)j*256 + i0+tx] = tile[tx][ty+ii*8];
  }
}

// ---------------- attn3: MFMA flash (8 waves x 32 query rows) ----------------
__global__ __launch_bounds__(512) void k_attn3(const us* __restrict__ QLb,
    const us* __restrict__ Kb, const us* __restrict__ Vt,
    float* __restrict__ Pmax, float* __restrict__ Psum, us* __restrict__ Pacc)
{
  __shared__ us Ks[64*64];       // 8 KB
  __shared__ us Vs[64*64];       // 8 KB
  __shared__ us Ps[8*32*64];     // 32 KB (per-wave 32x64 P tile)
  int h = blockIdx.y, cx = blockIdx.x;
  int tid = threadIdx.x, wid = tid>>6, lane = tid&63;   // wid 0..7
  bf16x8 aq[2][2];
#pragma unroll
  for (int mt=0;mt<2;++mt){
    const us* qp = QLb + ((size_t)h*MM + wid*32 + mt*16 + (lane&15))*DHD;
#pragma unroll
    for (int ks=0;ks<2;++ks)
      aq[mt][ks] = *(const bf16x8*)(qp + ks*32 + (lane>>4)*8);
  }
  float m_[2][4], l_[2][4];
  f32x4 acc[2][4] = {};
#pragma unroll
  for (int mt=0;mt<2;++mt)
#pragma unroll
    for (int r=0;r<4;++r){ m_[mt][r] = -1e30f; l_[mt][r] = 0.f; }

  us* Pw = &Ps[wid*2048];
  for (int t=0;t<4;++t){
    int kb0 = cx*CSZ + t*64;
    __syncthreads();
    for (int i=tid;i<1024;i+=512){
      int rr = i>>4, c4 = (i&15)*4;
      ushort4 ku = *(const ushort4*)(Kb + ((size_t)h*NPAD + kb0 + rr)*DHD + c4);
      *(ushort4*)(&Ks[rr*64 + (c4 ^ ((rr&7)<<3))]) = ku;
      ushort4 vu = *(const ushort4*)(Vt + ((size_t)h*DHD + rr)*NPAD + kb0 + c4);
      *(ushort4*)(&Vs[rr*64 + (c4 ^ ((rr&7)<<3))]) = vu;
    }
    __syncthreads();
    f32x4 s[2][4] = {};
    __builtin_amdgcn_s_setprio(1);
#pragma unroll
    for (int ks=0;ks<2;++ks){
      int kk = ks*32 + (lane>>4)*8;
      bf16x8 kbf[4];
#pragma unroll
      for (int nt=0;nt<4;++nt){
        int key = nt*16 + (lane&15);
        kbf[nt] = *(const bf16x8*)(&Ks[key*64 + (kk ^ ((key&7)<<3))]);
      }
#pragma unroll
      for (int mt=0;mt<2;++mt)
#pragma unroll
        for (int nt=0;nt<4;++nt)
          s[mt][nt] = __builtin_amdgcn_mfma_f32_16x16x32_bf16(aq[mt][ks], kbf[nt], s[mt][nt], 0,0,0);
    }
    __builtin_amdgcn_s_setprio(0);
#pragma unroll
    for (int mt=0;mt<2;++mt){
#pragma unroll
      for (int r=0;r<4;++r){
        float mx = fmaxf(fmaxf(s[mt][0][r], s[mt][1][r]), fmaxf(s[mt][2][r], s[mt][3][r]));
#pragma unroll
        for (int off=8;off>=1;off>>=1) mx = fmaxf(mx, __shfl_xor(mx, off));
        float mn = fmaxf(m_[mt][r], mx);
        float f = __expf(m_[mt][r]-mn);
        float la = 0.f;
#pragma unroll
        for (int nt=0;nt<4;++nt){ float p=__expf(s[mt][nt][r]-mn); s[mt][nt][r]=p; la+=p; }
#pragma unroll
        for (int off=8;off>=1;off>>=1) la += __shfl_xor(la, off);
        l_[mt][r] = l_[mt][r]*f + la;
        m_[mt][r] = mn;
#pragma unroll
        for (int dt=0;dt<4;++dt) acc[mt][dt][r] *= f;
      }
    }
#pragma unroll
    for (int mt=0;mt<2;++mt)
#pragma unroll
      for (int r=0;r<4;++r){
        int row = mt*16 + (lane>>4)*4 + r;      // 0..31 within wave
        int sw = (row&7)<<3;
#pragma unroll
        for (int nt=0;nt<4;++nt){
          int col = nt*16 + (lane&15);
          Pw[row*64 + (col ^ sw)] = f2b(s[mt][nt][r]);
        }
      }
    __builtin_amdgcn_s_setprio(1);
#pragma unroll
    for (int ks=0;ks<2;++ks){
      int kk = ks*32 + (lane>>4)*8;
      bf16x8 pa[2], vb[4];
#pragma unroll
      for (int mt=0;mt<2;++mt){
        int arow = mt*16 + (lane&15);
        pa[mt] = *(const bf16x8*)(&Pw[arow*64 + (kk ^ ((arow&7)<<3))]);
      }
#pragma unroll
      for (int dt=0;dt<4;++dt){
        int d = dt*16 + (lane&15);
        vb[dt] = *(const bf16x8*)(&Vs[d*64 + (kk ^ ((d&7)<<3))]);
      }
#pragma unroll
      for (int mt=0;mt<2;++mt)
#pragma unroll
        for (int dt=0;dt<4;++dt)
          acc[mt][dt] = __builtin_amdgcn_mfma_f32_16x16x32_bf16(pa[mt], vb[dt], acc[mt][dt], 0,0,0);
    }
    __builtin_amdgcn_s_setprio(0);
  }
  size_t pbase = ((size_t)h*NCH + cx)*MM;
#pragma unroll
  for (int mt=0;mt<2;++mt)
#pragma unroll
    for (int r=0;r<4;++r){
      int row = wid*32 + mt*16 + (lane>>4)*4 + r;
      if ((lane&15)==0){ Pmax[pbase+row]=m_[mt][r]; Psum[pbase+row]=l_[mt][r]; }
#pragma unroll
      for (int dt=0;dt<4;++dt)
        Pacc[(pbase+row)*DHD + dt*16+(lane&15)] = f2b(acc[mt][dt][r]);
    }
}

__global__ void k_attn3_merge(const float* __restrict__ Pmax, const float* __restrict__ Psum,
    const us* __restrict__ Pacc, us* __restrict__ A3Vtb)
{
  int hm = blockIdx.x; int h = hm>>8, m = hm&255; int d = threadIdx.x;
  float gm = -1e30f;
  for (int c=0;c<NCH;++c) gm = fmaxf(gm, Pmax[((size_t)h*NCH+c)*MM+m]);
  float tot=0.f, acc=0.f;
  for (int c=0;c<NCH;++c){
    size_t pi = ((size_t)h*NCH+c)*MM+m;
    float w = __expf(Pmax[pi]-gm);
    tot += Psum[pi]*w;
    acc += bf2f(Pacc[pi*DHD+d])*w;
  }
  A3Vtb[((size_t)h*DHD + d)*MM + m] = f2b(acc/tot);
}

// ---------------- attn1 ----------------
__global__ __launch_bounds__(256) void k_attn1(const us* __restrict__ Qb,
    const us* __restrict__ KLb, const us* __restrict__ WmT,
    us* __restrict__ OH)
{
  __shared__ us KWs[64*256];
  __shared__ us Ps[64*256];
  int h = blockIdx.y, tid = threadIdx.x;
  int wid = tid>>6, lane = tid&63;
  int q0 = blockIdx.x*64;
  for (int i=tid; i<4096; i+=256){
    int lm = i>>4, k4 = (i&15)*4;
    *(ushort4*)(&KWs[lm*64 + (k4 ^ ((lm&7)<<3))]) =
        *(const ushort4*)(KLb + ((size_t)h*MM + lm)*DHD + k4);
  }
  bf16x8 aq[2];
  const us* qp = Qb + ((size_t)h*NPAD + q0 + wid*16 + (lane&15))*DHD;
#pragma unroll
  for (int ks=0;ks<2;++ks)
    aq[ks] = *(const bf16x8*)(qp + ks*32 + (lane>>4)*8);
  __syncthreads();
  f32x4 s[16];
#pragma unroll
  for (int nt=0;nt<16;++nt) s[nt] = (f32x4){0.f,0.f,0.f,0.f};
  __builtin_amdgcn_s_setprio(1);
#pragma unroll
  for (int ks=0;ks<2;++ks){
    int kk = ks*32 + (lane>>4)*8;
#pragma unroll
    for (int nt=0;nt<16;++nt){
      int col = nt*16 + (lane&15);
      bf16x8 b = *(const bf16x8*)(&KWs[col*64 + (kk ^ ((col&7)<<3))]);
      s[nt] = __builtin_amdgcn_mfma_f32_16x16x32_bf16(aq[ks], b, s[nt], 0,0,0);
    }
  }
  __builtin_amdgcn_s_setprio(0);
  float rcp[4];
#pragma unroll
  for (int r=0;r<4;++r){
    float m = -1e30f;
#pragma unroll
    for (int nt=0;nt<16;++nt) m = fmaxf(m, s[nt][r]);
#pragma unroll
    for (int off=8;off>=1;off>>=1) m = fmaxf(m, __shfl_xor(m, off));
    float l = 0.f;
#pragma unroll
    for (int nt=0;nt<16;++nt){ float p=__expf(s[nt][r]-m); s[nt][r]=p; l+=p; }
#pragma unroll
    for (int off=8;off>=1;off>>=1) l += __shfl_xor(l, off);
    rcp[r] = 1.f/l;
  }
  int prow_base = wid*16 + (lane>>4)*4;
#pragma unroll
  for (int nt=0;nt<16;++nt){
    int col = nt*16 + (lane&15);
#pragma unroll
    for (int r=0;r<4;++r){
      int row = prow_base + r;
      Ps[row*256 + (col ^ ((row&7)<<3))] = f2b(s[nt][r]);
    }
  }
  __syncthreads();
  for (int i=tid; i<4096; i+=256){
    int d = i>>6, k4 = (i&63)*4;
    ushort4 u = *(const ushort4*)(WmT + ((size_t)h*DHD + d)*MM + k4);
    *(ushort4*)(&KWs[d*256 + (k4 ^ ((d&7)<<3))]) = u;
  }
  __syncthreads();
  f32x4 acc[4] = {};
  int arow = wid*16 + (lane&15);
  __builtin_amdgcn_s_setprio(1);
#pragma unroll
  for (int ks=0;ks<8;++ks){
    int kk = ks*32 + (lane>>4)*8;
    bf16x8 a = *(const bf16x8*)(&Ps[arow*256 + (kk ^ ((arow&7)<<3))]);
#pragma unroll
    for (int dt=0;dt<4;++dt){
      int d = dt*16 + (lane&15);
      bf16x8 b = *(const bf16x8*)(&KWs[d*256 + (kk ^ ((d&7)<<3))]);
      acc[dt] = __builtin_amdgcn_mfma_f32_16x16x32_bf16(a, b, acc[dt], 0,0,0);
    }
  }
  __builtin_amdgcn_s_setprio(0);
#pragma unroll
  for (int r=0;r<4;++r){
    int row = q0 + prow_base + r;
    us* op = OH + (size_t)row*DIM + h*DHD;
#pragma unroll
    for (int dt=0;dt<4;++dt)
      op[dt*16 + (lane&15)] = f2b(acc[dt][r]*rcp[r]);
  }
}

// ---------------- depthwise conv along seq, bf16 RMW ----------------
#define SCBLK 32
__global__ __launch_bounds__(256) void k_seqconv(const us* __restrict__ Vb,
    const float* __restrict__ resk, us* __restrict__ OH)
{
  __shared__ us Vs[64*512];
  int tid = threadIdx.x;
  int p0 = blockIdx.x*SCBLK;
  for (int i=tid; i<16384; i+=256){
    int pl = i>>8, c2 = i&255;
    int gp = p0 - 16 + pl;
    int hh = c2>>5, d2 = (c2&31)*2;
    ushort2 v = make_ushort2(0,0);
    if (gp>=0 && gp<NPAD) v = *(const ushort2*)(Vb + ((size_t)hh*NPAD+gp)*DHD + d2);
    *(ushort2*)(&Vs[pl*512 + c2*2]) = v;
  }
  __syncthreads();
  int h = tid>>5;
  float kr[33];
#pragma unroll
  for (int r=0;r<33;++r) kr[r] = resk[h*33+r];
  for (int pl=0; pl<SCBLK; ++pl){
    float s0=0.f, s1=0.f;
#pragma unroll
    for (int r=0;r<33;++r){
      ushort2 v = *(const ushort2*)(&Vs[(pl+r)*512 + tid*2]);
      s0 += bf2f(v.x)*kr[r];
      s1 += bf2f(v.y)*kr[r];
    }
    size_t o = (size_t)(p0+pl)*DIM + tid*2;
    ushort2 cur = *(ushort2*)(OH + o);
    *(ushort2*)(OH + o) = make_ushort2(f2b(bf2f(cur.x)+s0), f2b(bf2f(cur.y)+s1));
  }
}

// ---------------- leff (bf16 planes, bf16 X) ----------------
__global__ void k_tfwd(const us* __restrict__ X, us* __restrict__ T)
{
  __shared__ us tile[32][33];
  int tx = threadIdx.x & 31, ty = threadIdx.x >> 5;
  int s0 = blockIdx.x*32, c0 = blockIdx.y*32;
  for (int yy=0; yy<4; ++yy){
    int s = s0 + ty + yy*8;
    if (s < NTOK) tile[ty+yy*8][tx] = X[(size_t)(1+s)*DIM + c0+tx];
  }
  __syncthreads();
  for (int yy=0; yy<4; ++yy){
    int c = c0 + ty + yy*8;
    int s = s0 + tx;
    if (s < NTOK) T[(size_t)c*NTOK + s] = tile[tx][ty+yy*8];
  }
}
__global__ void k_tbwd(const us* __restrict__ T, us* __restrict__ X)
{
  __shared__ us tile[32][33];
  int tx = threadIdx.x & 31, ty = threadIdx.x >> 5;
  int s0 = blockIdx.x*32, c0 = blockIdx.y*32;
  for (int yy=0; yy<4; ++yy){
    int c = c0 + ty + yy*8, s = s0 + tx;
    if (s < NTOK) tile[ty+yy*8][tx] = T[(size_t)c*NTOK + s];
  }
  __syncthreads();
  for (int yy=0; yy<4; ++yy){
    int s = s0 + ty + yy*8, c = c0 + tx;
    if (s < NTOK) X[(size_t)(1+s)*DIM + c] = tile[tx][ty+yy*8];
  }
}
// scalar depthwise 7/5/3 conv (round-13 variant: high occupancy)
__global__ __launch_bounds__(256) void k_leff(const us* __restrict__ T,
    const float* __restrict__ k7, const float* __restrict__ b7,
    const float* __restrict__ k5, const float* __restrict__ b5,
    const float* __restrict__ k3, const float* __restrict__ b3,
    us* __restrict__ T2)
{
  __shared__ float tile[21*21];
  int c = blockIdx.y;
  int ti = blockIdx.x/10, tj = blockIdx.x%10;
  int i0 = ti*15-3, j0 = tj*15-3;
  const us* img = T + (size_t)c*NTOK;
  for (int idx=threadIdx.x; idx<441; idx+=256){
    int ii = idx/21, jj = idx%21;
    int gi = i0+ii, gj = j0+jj;
    tile[idx] = (gi>=0 && gi<HSZ && gj>=0 && gj<HSZ) ? bf2f(img[gi*HSZ+gj]) : 0.f;
  }
  __syncthreads();
  if (threadIdx.x < 225){
    int li = threadIdx.x/15, lj = threadIdx.x%15;
    int gi = ti*15+li, gj = tj*15+lj;
    float acc = tile[(li+3)*21 + (lj+3)] + b7[c]+b5[c]+b3[c];
    const float* w7 = k7 + c*49;
#pragma unroll
    for (int a=0;a<7;++a)
#pragma unroll
      for (int bb=0;bb<7;++bb) acc += tile[(li+a)*21 + (lj+bb)]*w7[a*7+bb];
    const float* w5 = k5 + c*25;
#pragma unroll
    for (int a=0;a<5;++a)
#pragma unroll
      for (int bb=0;bb<5;++bb) acc += tile[(li+1+a)*21 + (lj+1+bb)]*w5[a*5+bb];
    const float* w3 = k3 + c*9;
#pragma unroll
    for (int a=0;a<3;++a)
#pragma unroll
      for (int bb=0;bb<3;++bb) acc += tile[(li+2+a)*21 + (lj+2+bb)]*w3[a*3+bb];
    T2[(size_t)c*NTOK + gi*HSZ+gj] = f2b(acc);
  }
}

// ---------------- cls-row pieces ----------------
__global__ void k_row1(const float* __restrict__ Q0, const float* __restrict__ KL0,
                       float* __restrict__ row1)
{
  __shared__ float sb[4];
  __shared__ float qv[64];
  int t = threadIdx.x;
  if (t<64) qv[t] = Q0[PADR*DHD + t];
  __syncthreads();
  float l = 0.f;
#pragma unroll
  for (int d=0;d<64;++d) l += qv[d]*KL0[(size_t)t*DHD+d];
  float m = blockMax256(l, sb);
  float e = __expf(l-m);
  float s = blockSum256(e, sb);
  row1[t] = e/s;
}
__global__ void k_rz(const float* __restrict__ row1, const us* __restrict__ Zt,
                     float* __restrict__ rz)
{
  __shared__ float r1[256];
  int t = threadIdx.x;
  r1[t] = row1[t];
  __syncthreads();
  float s = 0.f;
  for (int k2=0;k2<256;++k2) s += r1[k2]*bf2f(Zt[(size_t)t*MM + k2]);
  rz[t] = s;
}
__global__ void k_rowstat(const float* __restrict__ L0, float* __restrict__ mx, float* __restrict__ se)
{
  __shared__ float sb[4];
  const float* row = L0 + (size_t)blockIdx.x*NPAD;
  float m = -1e30f;
  for (int i=threadIdx.x;i<NPAD;i+=256) m = fmaxf(m, row[i]);
  m = blockMax256(m, sb);
  float s = 0.f;
  for (int i=threadIdx.x;i<NPAD;i+=256) s += __expf(row[i]-m);
  s = blockSum256(s, sb);
  if (threadIdx.x==0){ mx[blockIdx.x]=m; se[blockIdx.x]=s; }
}
__global__ void k_aout(const float* __restrict__ L0, const float* __restrict__ rz,
    const float* __restrict__ mx, const float* __restrict__ se, float* __restrict__ out)
{
  __shared__ float wk[256], mk[256];
  int t = threadIdx.x;
  wk[t] = rz[t]/se[t];
  mk[t] = mx[t];
  __syncthreads();
  int p = blockIdx.x*256 + t;
  if (p >= NTOK) return;
  size_t pp = (size_t)(PADR+1+p);
  float a = 0.f;
  for (int k2=0;k2<256;++k2) a += wk[k2]*__expf(L0[(size_t)k2*NPAD+pp]-mk[k2]);
  out[4+p] = a;
}
__global__ void k_final(const us* __restrict__ H2r, const float* __restrict__ nw,
    const float* __restrict__ nbb, const float* __restrict__ w2, const float* __restrict__ b2,
    float* __restrict__ out)
{
  __shared__ float sb[4];
  __shared__ float hf[512];
  int t = threadIdx.x;
  float x0 = bf2f(H2r[t]), x1 = bf2f(H2r[256+t]);
  float s = blockSum256(x0+x1, sb);
  float q = blockSum256(x0*x0+x1*x1, sb);
  float mean = s*(1.f/512.f);
  float var = q*(1.f/512.f) - mean*mean;
  float rstd = rsqrtf(var+1e-5f);
  hf[t]     = (x0-mean)*rstd*nw[t]+nbb[t];
  hf[256+t] = (x1-mean)*rstd*nw[256+t]+nbb[256+t];
  __syncthreads();
  float p0 = hf[t]*w2[t*2]   + hf[256+t]*w2[(256+t)*2];
  float p1 = hf[t]*w2[t*2+1] + hf[256+t]*w2[(256+t)*2+1];
  p0 = blockSum256(p0, sb);
  p1 = blockSum256(p1, sb);
  if (t==0){
    float l0 = p0+b2[0], l1 = p1+b2[1];
    float m = fmaxf(l0,l1);
    float e0 = __expf(l0-m), e1 = __expf(l1-m), si = 1.f/(e0+e1);
    out[0]=l0; out[1]=l1; out[2]=e0*si; out[3]=e1*si;
  }
}

// ---------------- host orchestration ----------------
struct Bufs {
  float *A2,*sums,*scl,*Pmax,*Psum;
  us *Xb,*Yb,*OHb,*Qb,*Kb,*Vb,*Vtb,*QLb,*KLb,*A2b;
  us *Z0b,*Z0tb,*Z1b,*Z1tb,*XZb,*XZtb,*T1tb,*T2tb;
  us *A3Vtb,*WmT,*Pacc,*zpg;
};

static void run_pinv(const us* A2b, Bufs& b, int NB, hipStream_t st)
{
  dim3 g(4,4,NB);
  us *Zc=b.Z0b, *Zct=b.Z0tb, *Zn=b.Z1b, *Znt=b.Z1tb;
  for (int it=0; it<6; ++it){
    k_pgemm<0><<<g,256,0,st>>>(A2b, Zct, b.XZb, b.XZtb, 0.f, 1.f, 1);
    k_pgemm<1><<<g,256,0,st>>>(b.XZb, b.XZtb, nullptr, b.T1tb, 7.f, 1.f, 0);
    k_pgemm<1><<<g,256,0,st>>>(b.XZb, b.T1tb, nullptr, b.T2tb, 15.f, 1.f, 0);
    k_pgemm<1><<<g,256,0,st>>>(Zc, b.T2tb, Zn, Znt, 13.f, 0.25f, 1);
    us* t1=Zc; Zc=Zn; Zn=t1;
    us* t2=Zct; Zct=Znt; Znt=t2;
  }
  // 6 iterations = even number of swaps -> final Z in Z0b/Z0tb
}

static void nystrom_layer(Bufs& b, const float* lnw, const float* lnb,
    const us* wqkvT, const us* woutT,
    const float* bout, const float* resk, int slot, hipStream_t st)
{
  unsigned* mslot = (unsigned*)(b.zpg + 256) + slot;   // zpg bytes 512.. zeroed each replay
  k_ln<<<(N1+3)/4,256,0,st>>>(b.Xb, b.Yb, lnw, lnb);
  k_gemm<1><<<352*12,256,0,st>>>(b.Yb, wqkvT, nullptr,
      nullptr, nullptr, nullptr, b.Qb, b.Kb, b.Vb, b.zpg, DIM, 352);
  k_vT<<<dim3(NPAD/32,16),256,0,st>>>(b.Vb, b.Vtb);
  k_landmark2<<<2*NH*MM,64,0,st>>>(b.Qb, b.Kb, b.QLb, b.KLb);
  k_nt64b<<<dim3(4,4,NH),64,0,st>>>(b.QLb, b.KLb, b.A2,
      (long)MM*DHD,(long)MM*DHD,(long)MM*MM, MM);
  k_softmax256<<<NH*MM/4,256,0,st>>>(b.A2, b.A2b);
  k_csmax<<<NH,256,0,st>>>(b.A2, mslot);
  k_z0t<<<dim3(8,8*NH),256,0,st>>>(b.A2, b.Z0b, b.Z0tb, mslot);
  run_pinv(b.A2b, b, NH, st);
  k_attn3<<<dim3(NCH,NH),512,0,st>>>(b.QLb, b.Kb, b.Vtb, b.Pmax, b.Psum, b.Pacc);
  k_attn3_merge<<<NH*MM,64,0,st>>>(b.Pmax, b.Psum, b.Pacc, b.A3Vtb);
  k_pgemm2<<<dim3(1,4,NH),256,0,st>>>(b.Z0b, b.A3Vtb, b.WmT);
  k_attn1<<<dim3(NPAD/64,NH),256,0,st>>>(b.Qb, b.KLb, b.WmT, b.OHb);
  k_seqconv<<<NPAD/SCBLK,256,0,st>>>(b.Vb, resk, b.OHb);
  k_gemm<2><<<352*4,256,0,st>>>(b.OHb, woutT, bout,
      b.Xb, nullptr, nullptr, nullptr, nullptr, nullptr, b.zpg, DIM, 352);
}

extern "C" void kernel_launch(void* const* d_in, const int* in_sizes, int n_in,
                              void* d_out, int out_size, void* d_ws, size_t ws_size,
                              hipStream_t stream)
{
  (void)n_in; (void)out_size;
  bool sig_order = (in_sizes[10] == 25088);
  int iL2 = sig_order ? 16 : 10;
  int iLf = sig_order ? 10 : 16;

  const float* h       = (const float*)d_in[0];
  const float* fc1_w   = (const float*)d_in[1];
  const float* fc1_b   = (const float*)d_in[2];
  const float* cls_tok = (const float*)d_in[3];
  const float* l1_lnw  = (const float*)d_in[4];
  const float* l1_lnb  = (const float*)d_in[5];
  const float* l1_wqkv = (const float*)d_in[6];
  const float* l1_wout = (const float*)d_in[7];
  const float* l1_bout = (const float*)d_in[8];
  const float* l1_resk = (const float*)d_in[9];
  const float* l2_lnw  = (const float*)d_in[iL2+0];
  const float* l2_lnb  = (const float*)d_in[iL2+1];
  const float* l2_wqkv = (const float*)d_in[iL2+2];
  const float* l2_wout = (const float*)d_in[iL2+3];
  const float* l2_bout = (const float*)d_in[iL2+4];
  const float* l2_resk = (const float*)d_in[iL2+5];
  const float* k7 = (const float*)d_in[iLf+0];
  const float* b7 = (const float*)d_in[iLf+1];
  const float* k5 = (const float*)d_in[iLf+2];
  const float* b5 = (const float*)d_in[iLf+3];
  const float* k3 = (const float*)d_in[iLf+4];
  const float* b3 = (const float*)d_in[iLf+5];
  const float* nw = (const float*)d_in[22];
  const float* nbb= (const float*)d_in[23];
  const float* w2 = (const float*)d_in[24];
  const float* b2 = (const float*)d_in[25];
  float* out = (float*)d_out;

  char* base = (char*)d_ws;
  auto allocF = [&](size_t n)->float*{
    float* p=(float*)base; base += ((n*sizeof(float)+255)&~(size_t)255); return p; };
  auto allocU = [&](size_t n)->us*{
    us* p=(us*)base; base += ((n*sizeof(us)+255)&~(size_t)255); return p; };

  const size_t S = (size_t)NPAD*DIM;
  const size_t SQ = (size_t)MM*MM;
  Bufs b;
  b.Xb  = allocU(S);
  b.Yb  = allocU(S);
  b.OHb = allocU(S);
  b.Qb  = allocU(S);
  b.Kb  = allocU(S);
  b.Vb  = allocU(S);
  b.Vtb = allocU(S);
  b.QLb = allocU((size_t)NH*MM*DHD);
  b.KLb = allocU((size_t)NH*MM*DHD);
  b.A2  = allocF((size_t)NH*SQ);
  b.A2b = allocU((size_t)NH*SQ);
  b.Z0b = allocU((size_t)NH*SQ);  b.Z0tb = allocU((size_t)NH*SQ);
  b.Z1b = allocU((size_t)NH*SQ);  b.Z1tb = allocU((size_t)NH*SQ);
  b.XZb = allocU((size_t)NH*SQ);  b.XZtb = allocU((size_t)NH*SQ);
  b.T1tb= allocU((size_t)NH*SQ);
  b.T2tb= allocU((size_t)NH*SQ);
  b.A3Vtb = allocU((size_t)NH*MM*DHD);
  b.WmT   = allocU((size_t)NH*MM*DHD);
  b.sums  = allocF(2*(size_t)NH*MM);
  b.scl   = allocF(16);
  b.Pmax  = allocF((size_t)NH*NCH*MM);
  b.Psum  = allocF((size_t)NH*NCH*MM);
  b.Pacc  = allocU((size_t)NH*NCH*MM*DHD);
  b.zpg   = allocU(512);
  us* hb     = allocU((size_t)NTOK*1024);
  us* fc1T   = allocU((size_t)DIM*1024);
  us* wqkvT1 = allocU((size_t)1536*DIM);
  us* wqkvT2 = allocU((size_t)1536*DIM);
  us* woutT1 = allocU((size_t)DIM*DIM);
  us* woutT2 = allocU((size_t)DIM*DIM);
  float* Q0   = allocF((size_t)NPAD*DHD);
  float* K0   = allocF((size_t)NPAD*DHD);
  float* QL0f = allocF((size_t)MM*DHD);
  float* KL0f = allocF((size_t)MM*DHD);
  float* row1 = allocF(256);
  float* rzv  = allocF(256);
  float* mxv  = allocF(256);
  float* sev  = allocF(256);
  us* h2row = allocU(512);
  if ((size_t)(base - (char*)d_ws) > ws_size) return;

  hipMemsetAsync((void*)b.zpg, 0, 1024, stream);

  // input + weight conversions (fp32 -> bf16)
  k_cvt<<<((size_t)NTOK*1024/4 + 255)/256,256,0,stream>>>(h, hb, (size_t)NTOK*1024/4);
  k_wT<<<dim3(32,16),256,0,stream>>>(fc1_w, fc1T, 1024, DIM);
  k_wT<<<dim3(16,48),256,0,stream>>>(l1_wqkv, wqkvT1, DIM, 1536);
  k_wT<<<dim3(16,48),256,0,stream>>>(l2_wqkv, wqkvT2, DIM, 1536);
  k_wT<<<dim3(16,16),256,0,stream>>>(l1_wout, woutT1, DIM, DIM);
  k_wT<<<dim3(16,16),256,0,stream>>>(l2_wout, woutT2, DIM, DIM);

  // stage 0: fc1 + cls token
  k_gemm<0><<<352*4,256,0,stream>>>(hb, fc1T, fc1_b,
      b.Xb, nullptr, nullptr, nullptr, nullptr, nullptr, b.zpg, 1024, 352);
  k_setcls<<<2,256,0,stream>>>(b.Xb, cls_tok);

  // layer 1 + LeFF
  nystrom_layer(b, l1_lnw, l1_lnb, wqkvT1, woutT1, l1_bout, l1_resk, 0, stream);
  k_tfwd<<<dim3(704,16),256,0,stream>>>(b.Xb, b.OHb);
  k_leff<<<dim3(100,512),256,0,stream>>>(b.OHb, k7,b7,k5,b5,k3,b3, b.Qb);
  k_tbwd<<<dim3(704,16),256,0,stream>>>(b.Qb, b.Xb);

  // layer 2 (save h2 row 0)
  nystrom_layer(b, l2_lnw, l2_lnb, wqkvT2, woutT2, l2_bout, l2_resk, 1, stream);
  k_copyu<<<2,256,0,stream>>>(h2row, b.Xb, 512);

  // layer 3 -> h3
  nystrom_layer(b, l2_lnw, l2_lnb, wqkvT2, woutT2, l2_bout, l2_resk, 2, stream);

  // cls-row stage (head 0, l2 weights, LN(h3))
  unsigned* mslot3 = (unsigned*)(b.zpg + 256) + 3;
  k_ln<<<(N1+3)/4,256,0,stream>>>(b.Xb, b.Yb, l2_lnw, l2_lnb);
  k_gemm<3><<<352,256,0,stream>>>(b.Yb, wqkvT2, nullptr,
      nullptr, Q0, K0, nullptr, nullptr, nullptr, b.zpg, DIM, 352);
  k_landmark2f<<<2*MM,64,0,stream>>>(Q0, K0, QL0f, KL0f);
  k_nt64<<<dim3(4,4,1),64,0,stream>>>(QL0f, KL0f, b.A2, 0,0,0, MM);
  k_softmax256<<<MM/4,256,0,stream>>>(b.A2, b.A2b);
  k_csmax<<<1,256,0,stream>>>(b.A2, mslot3);
  k_z0t<<<dim3(8,8),256,0,stream>>>(b.A2, b.Z0b, b.Z0tb, mslot3);
  run_pinv(b.A2b, b, 1, stream);
  k_row1<<<1,256,0,stream>>>(Q0, KL0f, row1);
  k_rz<<<1,256,0,stream>>>(row1, b.Z0tb, rzv);
  // L0 = QL0 @ K0^T (256 x NPAD), into Yb's storage (NPAD*256 floats)
  float* L0 = (float*)b.Yb;
  k_nt64<<<dim3(NPAD/64,4,1),64,0,stream>>>(QL0f, K0, L0, 0,0,0, NPAD);
  k_rowstat<<<MM,256,0,stream>>>(L0, mxv, sev);
  k_aout<<<88,256,0,stream>>>(L0, rzv, mxv, sev, out);
  k_final<<<1,256,0,stream>>>(h2row, nw, nbb, w2, b2, out);
}